// Round 2
// baseline (355139.233 us; speedup 1.0000x reference)
//
#include <hip/hip_runtime.h>
#include <math.h>
#include <stdint.h>

#define Dd 32
#define DS 33
#define TT 8192
#define NN 8191
#define KK 16
#define LOG2PI_ 1.8378770664093453

// ---------------- ws layout ----------------
// doubles at byte 0:
#define WSD_LOGC0  0
#define WSD_LOGZQ  1
#define WSD_MIXC   3
#define WSD_LDLAM  4
#define WSD_BTLAMB 5
#define WSD_PR     8
#define WSD_PT     1032
#define WSD_PM     2056
// float area begins at byte 32768:
#define F_TAU      0
#define F_TAUMU    1024
#define F_LAM      1056
#define F_A        2080
#define F_B        3104
#define F_ATLAM    3136
#define F_ATLAMA   4160
#define F_LAMA     5184
#define F_LAMB     6208
#define F_ATLAMB   6240
#define F_SC       6272
#define F_LAMAK    6304
#define F_ATLAMAK  22688
#define F_LAMBK    39072
#define F_ATLAMBK  39584
#define F_BTLAMBK  40096
#define F_LOGDETK  40112
#define F_TPM      40128
#define F_J0       40160
#define F_H0       41184
#define F_MLAST    41216
#define F_COVT     41248
#define F_XT       42272
#define F_ALPHA    42304
#define F_BETA     173360
#define F_EPS      304416
#define F_EZ       566560
#define F_GSM      599328
#define F_LG       861440
#define F_GG       9249024

// out offsets (floats)
#define O_Z     ((size_t)0)
#define O_EX    ((size_t)262144)
#define O_EXXT  ((size_t)524288)
#define O_CROSS ((size_t)8912896)
#define O_CAT   ((size_t)17300480)
#define O_KL    ((size_t)17431536)

// ---------------- threefry ----------------
__device__ __forceinline__ uint32_t rotl32(uint32_t v, int d){ return (v<<d)|(v>>(32-d)); }

__device__ __forceinline__ void threefry2x32(uint32_t k0, uint32_t k1, uint32_t x0, uint32_t x1,
                                             uint32_t& o0, uint32_t& o1){
  uint32_t ks2 = k0 ^ k1 ^ 0x1BD11BDAu;
  x0 += k0; x1 += k1;
  x0+=x1; x1=rotl32(x1,13); x1^=x0;
  x0+=x1; x1=rotl32(x1,15); x1^=x0;
  x0+=x1; x1=rotl32(x1,26); x1^=x0;
  x0+=x1; x1=rotl32(x1, 6); x1^=x0;
  x0+=k1; x1+=ks2+1u;
  x0+=x1; x1=rotl32(x1,17); x1^=x0;
  x0+=x1; x1=rotl32(x1,29); x1^=x0;
  x0+=x1; x1=rotl32(x1,16); x1^=x0;
  x0+=x1; x1=rotl32(x1,24); x1^=x0;
  x0+=ks2; x1+=k0+2u;
  x0+=x1; x1=rotl32(x1,13); x1^=x0;
  x0+=x1; x1=rotl32(x1,15); x1^=x0;
  x0+=x1; x1=rotl32(x1,26); x1^=x0;
  x0+=x1; x1=rotl32(x1, 6); x1^=x0;
  x0+=k0; x1+=k1+3u;
  x0+=x1; x1=rotl32(x1,17); x1^=x0;
  x0+=x1; x1=rotl32(x1,29); x1^=x0;
  x0+=x1; x1=rotl32(x1,16); x1^=x0;
  x0+=x1; x1=rotl32(x1,24); x1^=x0;
  x0+=k1; x1+=ks2+4u;
  x0+=x1; x1=rotl32(x1,13); x1^=x0;
  x0+=x1; x1=rotl32(x1,15); x1^=x0;
  x0+=x1; x1=rotl32(x1,26); x1^=x0;
  x0+=x1; x1=rotl32(x1, 6); x1^=x0;
  x0+=ks2; x1+=k0+5u;
  o0=x0; o1=x1;
}

// XLA f32 erfinv (Giles), matching jax.random.normal
__device__ __forceinline__ float tf_normal(uint32_t bits){
  float fl = __uint_as_float((bits>>9) | 0x3F800000u) - 1.0f;
  const float lo = -0.99999994f;
  float u = fmaxf(lo, fl*2.0f + lo);
  float w = -log1pf(-u*u);
  float p;
  if (w < 5.0f){
    w -= 2.5f;
    p = 2.81022636e-08f;
    p = fmaf(p,w,3.43273939e-07f);
    p = fmaf(p,w,-3.5233877e-06f);
    p = fmaf(p,w,-4.39150654e-06f);
    p = fmaf(p,w,0.00021858087f);
    p = fmaf(p,w,-0.00125372503f);
    p = fmaf(p,w,-0.00417768164f);
    p = fmaf(p,w,0.246640727f);
    p = fmaf(p,w,1.50140941f);
  } else {
    w = sqrtf(w) - 3.0f;
    p = -0.000200214257f;
    p = fmaf(p,w,0.000100950558f);
    p = fmaf(p,w,0.00134934322f);
    p = fmaf(p,w,-0.00367342844f);
    p = fmaf(p,w,0.00573950773f);
    p = fmaf(p,w,-0.0076224613f);
    p = fmaf(p,w,0.00943887047f);
    p = fmaf(p,w,1.00167406f);
    p = fmaf(p,w,2.83297682f);
  }
  return 1.4142135381698608f * (p*u);
}

// ---------------- block helpers ----------------
// destroys Ms (stride DS); returns sum_j log(d_j) = logdet
__device__ double blk_logdet(float* Ms, int tid){
  double sl = 0.0;
  for (int j=0;j<Dd;++j){
    float dd = Ms[j*DS+j];
    sl += log((double)dd);
    float invd = 1.0f/dd;
    #pragma unroll
    for(int p=0;p<4;p++){
      int cell = tid + (p<<8); int r=cell>>5, c=cell&31;
      if(r>j && c>j && c<=r) Ms[r*DS+c] -= Ms[r*DS+j]*(Ms[c*DS+j]*invd);
    }
    __syncthreads();
  }
  return sl;
}

// in-place cholesky of Ms -> L into Lb (lower), rdg[j]=1/L_jj ; returns sum log L_jj
__device__ float chol_ds(float* Ms, float* Lb, float* rdg, int tid){
  float sumlog = 0.f;
  for(int j=0;j<Dd;++j){
    float dd = Ms[j*DS+j];
    float sq = sqrtf(dd);
    float rd = 1.0f/sq;
    float invd = rd*rd;
    sumlog += __logf(sq);
    if(tid==0) rdg[j]=rd;
    #pragma unroll
    for(int p=0;p<4;p++){
      int cell=tid+(p<<8); int r=cell>>5, c=cell&31;
      if(c==j){ if(r>=j) Lb[r*DS+j] = (r==j)? sq : Ms[r*DS+j]*rd; }
      else if(r>j && c>j && c<=r) Ms[r*DS+c] -= Ms[r*DS+j]*(Ms[c*DS+j]*invd);
    }
    __syncthreads();
  }
  return sumlog;
}

// solve (L L^T) X = B for 32x33 RHS in Bs (stride DS), deferred-scale substitutions
__device__ void solve33(float* Bs, const float* Lb, const float* rdg,
                        const int* kk5, const int* rr5, const int* ok5, int tid){
  for(int ii=0;ii<Dd;++ii){
    float rdi = rdg[ii];
    #pragma unroll
    for(int p=0;p<5;p++) if(ok5[p]){
      int k=kk5[p], r=rr5[p];
      if(k>ii) Bs[k*DS+r] -= Lb[k*DS+ii]*(Bs[ii*DS+r]*rdi);
    }
    __syncthreads();
  }
  #pragma unroll
  for(int p=0;p<5;p++) if(ok5[p]) Bs[kk5[p]*DS+rr5[p]] *= rdg[kk5[p]];
  __syncthreads();
  for(int ii=Dd-1;ii>=0;--ii){
    float rdi = rdg[ii];
    #pragma unroll
    for(int p=0;p<5;p++) if(ok5[p]){
      int k=kk5[p], r=rr5[p];
      if(k<ii) Bs[k*DS+r] -= Lb[ii*DS+k]*(Bs[ii*DS+r]*rdi);
    }
    __syncthreads();
  }
  #pragma unroll
  for(int p=0;p<5;p++) if(ok5[p]) Bs[kk5[p]*DS+rr5[p]] *= rdg[kk5[p]];
  __syncthreads();
}

__device__ __forceinline__ double blk_red(double v, double* sd, int tid){
  sd[tid]=v; __syncthreads();
  for(int s=128;s>0;s>>=1){ if(tid<s) sd[tid]+=sd[tid+s]; __syncthreads(); }
  double r=sd[0]; __syncthreads(); return r;
}

// ---------------- kernels ----------------
__global__ __launch_bounds__(256) void k_setup(const float* rJ, const float* rh, const float* loc,
    const float* Tp, const float* Lp, const float* X, const float* plam, const float* pX,
    const float* ptau, const float* pmu, float* wsf, double* wsd){
  __shared__ float s1[1056], s2[1056], s3[1056];
  __shared__ float sv[32], sv2[32];
  int tid=threadIdx.x;
  // ---- tau ----
  for(int p=0;p<4;p++){int cell=tid+(p<<8);int r=cell>>5,c=cell&31; s1[r*DS+c]=Tp[cell];}
  if(tid<32) sv[tid]=loc[tid];
  __syncthreads();
  for(int p=0;p<4;p++){int cell=tid+(p<<8);int r=cell>>5,c=cell&31;
    float a=0.f;
    #pragma unroll
    for(int m=0;m<Dd;++m) a=fmaf(s1[r*DS+m], s1[c*DS+m], a);
    if(r==c) a+=1e-8f;
    s2[r*DS+c]=a; wsf[F_TAU+cell]=a; wsf[F_J0+cell]=a+rJ[cell];
  }
  __syncthreads();
  if(tid<32){ float tm=0.f;
    #pragma unroll
    for(int m=0;m<Dd;++m) tm=fmaf(s2[tid*DS+m], sv[m], tm);
    sv2[tid]=tm; wsf[F_TAUMU+tid]=tm; wsf[F_H0+tid]=tm+rh[tid];
  }
  __syncthreads();
  {
    double ldt = blk_logdet(s2, tid);
    if(tid==0){ double dd=0; for(int m=0;m<Dd;++m) dd += (double)sv[m]*(double)sv2[m];
      wsd[WSD_LOGC0] = -0.5*dd + 0.5*ldt - 0.5*Dd*LOG2PI_; }
  }
  __syncthreads();
  // ---- lam ----
  for(int p=0;p<4;p++){int cell=tid+(p<<8);int r=cell>>5,c=cell&31; s1[r*DS+c]=Lp[cell];}
  __syncthreads();
  for(int p=0;p<4;p++){int cell=tid+(p<<8);int r=cell>>5,c=cell&31;
    float a=0.f;
    #pragma unroll
    for(int m=0;m<Dd;++m) a=fmaf(s1[r*DS+m], s1[c*DS+m], a);
    if(r==c) a+=1e-8f;
    s2[r*DS+c]=a; wsf[F_LAM+cell]=a;
  }
  __syncthreads();
  // ---- A, b ----
  for(int p=0;p<4;p++){int cell=tid+(p<<8);int r=cell>>5,c=cell&31;
    float a=X[r*33+c]; s3[r*DS+c]=a; wsf[F_A+cell]=a; }
  if(tid<32){ sv[tid]=X[tid*33+32]; wsf[F_B+tid]=sv[tid]; }
  __syncthreads();
  // ---- lamA (s1), ATlam, lamb ----
  for(int p=0;p<4;p++){int cell=tid+(p<<8);int r=cell>>5,c=cell&31;
    float a=0.f,b2=0.f;
    #pragma unroll
    for(int m=0;m<Dd;++m){ a=fmaf(s2[r*DS+m], s3[m*DS+c], a); b2=fmaf(s3[m*DS+r], s2[m*DS+c], b2); }
    s1[r*DS+c]=a; wsf[F_LAMA+cell]=a; wsf[F_ATLAM+cell]=b2;
  }
  if(tid<32){ float lb=0.f;
    #pragma unroll
    for(int m=0;m<Dd;++m) lb=fmaf(s2[tid*DS+m], sv[m], lb);
    sv2[tid]=lb; wsf[F_LAMB+tid]=lb;
  }
  __syncthreads();
  // ---- ATlamA, ATlamb, bTlamb ----
  for(int p=0;p<4;p++){int cell=tid+(p<<8);int r=cell>>5,c=cell&31;
    float a=0.f;
    #pragma unroll
    for(int m=0;m<Dd;++m) a=fmaf(s3[m*DS+r], s1[m*DS+c], a);
    wsf[F_ATLAMA+cell]=a;
  }
  if(tid<32){ float ab=0.f;
    #pragma unroll
    for(int m=0;m<Dd;++m) ab=fmaf(s3[m*DS+tid], sv2[m], ab);
    wsf[F_ATLAMB+tid]=ab;
  }
  if(tid==0){ double bb=0; for(int m=0;m<Dd;++m) bb += (double)sv[m]*(double)sv2[m];
    wsd[WSD_BTLAMB]=bb; }
  __syncthreads();
  {
    double ldl = blk_logdet(s2, tid);   // destroys s2 (lam copy)
    if(tid==0) wsd[WSD_LDLAM]=ldl;
  }
  // ---- prior_tau ----
  for(int p=0;p<4;p++){int cell=tid+(p<<8);int r=cell>>5,c=cell&31; s1[r*DS+c]=ptau[cell];}
  if(tid<32) sv[tid]=pmu[tid];
  __syncthreads();
  if(tid<32){ float tm=0.f;
    #pragma unroll
    for(int m=0;m<Dd;++m) tm=fmaf(s1[tid*DS+m], sv[m], tm);
    sv2[tid]=tm; wsf[F_TPM+tid]=tm;
  }
  __syncthreads();
  {
    double ldp = blk_logdet(s1, tid);
    if(tid==0){ double dd=0; for(int m=0;m<Dd;++m) dd += (double)sv[m]*(double)sv2[m];
      wsd[WSD_MIXC] = -0.5*dd + 0.5*ldp - 0.5*Dd*LOG2PI_; }
  }
  __syncthreads();
  // ---- prior per-k ----
  for(int k2=0;k2<KK;++k2){
    for(int p=0;p<4;p++){int cell=tid+(p<<8);int r=cell>>5,c=cell&31;
      s2[r*DS+c]=plam[k2*1024+cell]; s3[r*DS+c]=pX[k2*1056 + r*33 + c];}
    if(tid<32) sv[tid]=pX[k2*1056 + tid*33 + 32];
    __syncthreads();
    for(int p=0;p<4;p++){int cell=tid+(p<<8);int r=cell>>5,c=cell&31;
      float a=0.f;
      #pragma unroll
      for(int m=0;m<Dd;++m) a=fmaf(s2[r*DS+m], s3[m*DS+c], a);
      s1[r*DS+c]=a; wsf[F_LAMAK + (size_t)k2*1024 + cell]=a;
    }
    if(tid<32){ float lb=0.f;
      #pragma unroll
      for(int m=0;m<Dd;++m) lb=fmaf(s2[tid*DS+m], sv[m], lb);
      sv2[tid]=lb; wsf[F_LAMBK + k2*32 + tid]=lb;
    }
    __syncthreads();
    for(int p=0;p<4;p++){int cell=tid+(p<<8);int r=cell>>5,c=cell&31;
      float a=0.f;
      #pragma unroll
      for(int m=0;m<Dd;++m) a=fmaf(s3[m*DS+r], s1[m*DS+c], a);
      wsf[F_ATLAMAK + (size_t)k2*1024 + cell]=a;
    }
    if(tid<32){ float ab=0.f;
      #pragma unroll
      for(int m=0;m<Dd;++m) ab=fmaf(s3[m*DS+tid], sv2[m], ab);
      wsf[F_ATLAMBK + k2*32 + tid]=ab;
    }
    if(tid==0){ float bb=0.f; for(int m=0;m<Dd;++m) bb=fmaf(sv[m],sv2[m],bb);
      wsf[F_BTLAMBK + k2]=bb; }
    __syncthreads();
    double dk = blk_logdet(s2, tid);
    if(tid==0) wsf[F_LOGDETK + k2]=(float)dk;
  }
}

__global__ __launch_bounds__(256) void k_eps(const int* seedp, float* wsf){
  uint32_t seed = (uint32_t)seedp[0];
  uint32_t K0,K1;
  threefry2x32(0u, seed, 0u, 1u, K0, K1);         // fold_in(key(seed), 1)
  uint32_t i = blockIdx.x*256u + threadIdx.x;      // element index (partitionable counter)
  uint32_t o0,o1;
  threefry2x32(K0, K1, 0u, i, o0, o1);
  wsf[F_EPS + i] = tf_normal(o0 ^ o1);
}

__global__ __launch_bounds__(256) void k_mainseq(const float* rJ, const float* rh,
    const float* il, const float* tl, float* wsf, double* wsd, float* out){
  __shared__ float sm[8704];
  int tid=threadIdx.x;
  if(blockIdx.x==0){
    // ======= Kalman information filter (sequential) =======
    float* Ms   = sm;        float* Lb  = sm+1056;  float* Bs   = sm+2112;
    float* Jc   = sm+3168;   float* cATA= sm+4224;  float* cATl = sm+5280;
    float* clam = sm+6336;   float* clamA=sm+7392;
    float* hc   = sm+8448;   float* ub  = sm+8480;  float* rdg  = sm+8512;
    float* clmb = sm+8544;   float* cAlb= sm+8576;  float* scr  = sm+8608;
    int i8=tid>>3, c4=(tid&7)*4;
    int kk5[5], rr5[5], ok5[5];
    #pragma unroll
    for(int p=0;p<5;p++){int cell=tid+(p<<8); ok5[p]=(cell<1056)?1:0;
      int k=cell/33; kk5[p]=k; rr5[p]=cell-k*33;}
    for(int p=0;p<4;p++){int cell=tid+(p<<8);int r=cell>>5,c=cell&31;
      cATA[r*DS+c]=wsf[F_ATLAMA+cell]; cATl[r*DS+c]=wsf[F_ATLAM+cell];
      clam[r*DS+c]=wsf[F_LAM+cell];    clamA[r*DS+c]=wsf[F_LAMA+cell];
      Jc[r*DS+c]=wsf[F_J0+cell];}
    if(tid<32){hc[tid]=wsf[F_H0+tid]; clmb[tid]=wsf[F_LAMB+tid]; cAlb[tid]=wsf[F_ATLAMB+tid];}
    double lc = wsd[WSD_LOGC0];
    double c_bt = wsd[WSD_BTLAMB], c_ldl = wsd[WSD_LDLAM];
    __syncthreads();
    for(int t=0;t<NN;++t){
      float4 jr = *(const float4*)(rJ + ((size_t)(t+1)<<10) + (tid<<2));
      float hr = (tid<32)? rh[(size_t)(t+1)*Dd + tid] : 0.f;
      for(int p=0;p<4;p++){int cell=tid+(p<<8);int r=cell>>5,c=cell&31;
        Ms[r*DS+c]=Jc[r*DS+c]+cATA[r*DS+c]+((r==c)?1e-6f:0.f);
        Bs[r*DS+c]=cATl[r*DS+c];}
      if(tid<32){float u=hc[tid]-cAlb[tid]; Bs[tid*DS+32]=u; ub[tid]=u;}
      __syncthreads();
      float sumlog = chol_ds(Ms, Lb, rdg, tid);
      solve33(Bs, Lb, rdg, kk5, rr5, ok5, tid);   // Bs = [G | v]
      { // stores: L, G, g
        size_t ob=(size_t)t*1024 + ((size_t)i8<<5) + c4;
        float4 lv = make_float4(Lb[i8*DS+c4],Lb[i8*DS+c4+1],Lb[i8*DS+c4+2],Lb[i8*DS+c4+3]);
        *(float4*)(wsf+F_LG+ob)=lv;
        float4 gvv= make_float4(Bs[i8*DS+c4],Bs[i8*DS+c4+1],Bs[i8*DS+c4+2],Bs[i8*DS+c4+3]);
        *(float4*)(wsf+F_GG+ob)=gvv;
        if(tid<32) wsf[F_GSM+(size_t)t*32+tid]=Bs[tid*DS+32];
      }
      float acc0=0,acc1=0,acc2=0,acc3=0;
      #pragma unroll
      for(int m=0;m<Dd;++m){ float a=clamA[i8*DS+m];
        acc0=fmaf(a,Bs[m*DS+c4],acc0);   acc1=fmaf(a,Bs[m*DS+c4+1],acc1);
        acc2=fmaf(a,Bs[m*DS+c4+2],acc2); acc3=fmaf(a,Bs[m*DS+c4+3],acc3);}
      float jn0=clam[i8*DS+c4]  +jr.x-acc0;
      float jn1=clam[i8*DS+c4+1]+jr.y-acc1;
      float jn2=clam[i8*DS+c4+2]+jr.z-acc2;
      float jn3=clam[i8*DS+c4+3]+jr.w-acc3;
      float hn=0.f;
      if(tid<32){ float s2=0.f;
        #pragma unroll
        for(int m=0;m<Dd;++m) s2=fmaf(clamA[tid*DS+m],Bs[m*DS+32],s2);
        hn=clmb[tid]+hr+s2;
        scr[tid]=ub[tid]*Bs[tid*DS+32];
      }
      __syncthreads();
      if(tid==0){ float uv=0.f; for(int q=0;q<Dd;q++) uv+=scr[q];
        lc += -0.5*c_bt + 0.5*c_ldl + 0.5*(double)uv - (double)sumlog; }
      Jc[i8*DS+c4]=jn0; Jc[i8*DS+c4+1]=jn1; Jc[i8*DS+c4+2]=jn2; Jc[i8*DS+c4+3]=jn3;
      if(tid<32) hc[tid]=hn;
      __syncthreads();
    }
    // ======= final step: Cl, mlast, CovT, logZq, xT =======
    for(int p=0;p<4;p++){int cell=tid+(p<<8);int r=cell>>5,c=cell&31;
      Ms[r*DS+c]=Jc[r*DS+c]+((r==c)?1e-6f:0.f);
      Bs[r*DS+c]=(r==c)?1.f:0.f;}
    if(tid<32) Bs[tid*DS+32]=hc[tid];
    __syncthreads();
    float sumlogCl = chol_ds(Ms, Lb, rdg, tid);
    solve33(Bs, Lb, rdg, kk5, rr5, ok5, tid);     // Bs = [CovT | mlast]
    for(int p=0;p<4;p++){int cell=tid+(p<<8);int r=cell>>5,c=cell&31;
      wsf[F_COVT+cell]=Bs[r*DS+c];}
    if(tid<32){ float ml=Bs[tid*DS+32];
      wsf[F_MLAST+tid]=ml; out[O_EX+(size_t)(TT-1)*32+tid]=ml;
      scr[tid]=hc[tid]*ml; }
    __syncthreads();
    if(tid==0){ double hm=0; for(int q=0;q<Dd;q++) hm+=(double)scr[q];
      wsd[WSD_LOGZQ] = lc + 0.5*hm + 0.5*Dd*LOG2PI_ - (double)sumlogCl; }
    {
      float mi=Bs[i8*DS+32];
      float4 ex=make_float4(Bs[i8*DS+c4]  +mi*Bs[(c4  )*DS+32],
                            Bs[i8*DS+c4+1]+mi*Bs[(c4+1)*DS+32],
                            Bs[i8*DS+c4+2]+mi*Bs[(c4+2)*DS+32],
                            Bs[i8*DS+c4+3]+mi*Bs[(c4+3)*DS+32]);
      *(float4*)(out+O_EXXT+(size_t)(TT-1)*1024+((size_t)i8<<5)+c4)=ex;
    }
    __syncthreads();
    if(tid<32) scr[tid]=wsf[F_EPS+(size_t)(TT-1)*32+tid];
    __syncthreads();
    for(int ii=Dd-1;ii>=0;--ii){
      if(tid<ii) scr[tid] -= Lb[ii*DS+tid]*(scr[ii]*rdg[ii]);
      __syncthreads();
    }
    if(tid<32) scr[tid]*=rdg[tid];
    __syncthreads();
    if(tid<32){ float xt=Bs[tid*DS+32]+scr[tid];
      wsf[F_XT+tid]=xt; out[O_Z+(size_t)(TT-1)*32+tid]=xt; }
  }
  else if(blockIdx.x==1){
    // ======= HMM forward (emit == 0) =======
    float* a_s=sm; float* tmp=sm+16; float* T_s=sm+32;
    T_s[tid]=tl[tid];
    if(tid<16) a_s[tid]=il[tid];
    __syncthreads();
    if(tid<16) wsf[F_ALPHA+tid]=a_s[tid];
    for(int n=1;n<NN;++n){
      if(tid<16){ int j=tid; float m=-3.0e38f;
        #pragma unroll
        for(int i2=0;i2<16;++i2) m=fmaxf(m, a_s[i2]+T_s[i2*16+j]);
        float s=0.f;
        #pragma unroll
        for(int i2=0;i2<16;++i2) s+=__expf(a_s[i2]+T_s[i2*16+j]-m);
        tmp[j]=m+__logf(s); }
      __syncthreads();
      if(tid<16){ a_s[tid]=tmp[tid]; wsf[F_ALPHA+(size_t)n*16+tid]=tmp[tid]; }
      __syncthreads();
    }
    if(tid==0){ float m=-3.0e38f;
      for(int i2=0;i2<16;++i2) m=fmaxf(m,a_s[i2]);
      float s=0.f;
      for(int i2=0;i2<16;++i2) s+=__expf(a_s[i2]-m);
      wsf[F_SC+0]=m+__logf(s); }
  }
  else {
    // ======= HMM backward =======
    float* b_s=sm; float* tmp=sm+16; float* T_s=sm+32;
    T_s[tid]=tl[tid];
    if(tid<16){ b_s[tid]=0.f; wsf[F_BETA+(size_t)(NN-1)*16+tid]=0.f; }
    __syncthreads();
    for(int n=NN-2;n>=0;--n){
      if(tid<16){ int i2=tid; float m=-3.0e38f;
        #pragma unroll
        for(int j=0;j<16;++j) m=fmaxf(m, T_s[i2*16+j]+b_s[j]);
        float s=0.f;
        #pragma unroll
        for(int j=0;j<16;++j) s+=__expf(T_s[i2*16+j]+b_s[j]-m);
        tmp[i2]=m+__logf(s); }
      __syncthreads();
      if(tid<16){ b_s[tid]=tmp[tid]; wsf[F_BETA+(size_t)n*16+tid]=tmp[tid]; }
      __syncthreads();
    }
  }
}

__global__ __launch_bounds__(256) void k_cat(const float* tl, float* wsf, float* out){
  __shared__ float Ts[256]; __shared__ float ar[16]; __shared__ float br[16];
  int tid=threadIdx.x;
  Ts[tid]=tl[tid];
  float logZ = wsf[F_SC+0];
  int i=tid>>4, j=tid&15;
  float acc=0.f;
  int n0=blockIdx.x*64;
  __syncthreads();
  for(int nn=0;nn<64;++nn){
    int n=n0+nn;
    if(n<NN-1){
      if(tid<16) ar[tid]=wsf[F_ALPHA+(size_t)n*16+tid];
      else if(tid<32) br[tid-16]=wsf[F_BETA+(size_t)(n+1)*16+(tid-16)];
      __syncthreads();
      acc += __expf(ar[i]+Ts[i*16+j]+br[j]-logZ);
      __syncthreads();
    }
    if(n<NN && tid<16)
      out[O_CAT+(size_t)n*16+tid]=__expf(wsf[F_ALPHA+(size_t)n*16+tid]+wsf[F_BETA+(size_t)n*16+tid]-logZ);
  }
  wsf[F_EZ + blockIdx.x*256 + tid]=acc;
}

__global__ __launch_bounds__(256) void k_pinv(float* wsf, float* out){
  __shared__ float Lb[1056]; __shared__ float Xs[1056]; __shared__ float rdg[32];
  int t=blockIdx.x; int tid=threadIdx.x; int i8=tid>>3, c4=(tid&7)*4;
  size_t ob=(size_t)t*1024;
  for(int p=0;p<4;p++){int cell=tid+(p<<8);int r=cell>>5,c=cell&31;
    Lb[r*DS+c]=wsf[F_LG+ob+cell];
    Xs[r*DS+c]=(r==c)?1.f:0.f;}
  __syncthreads();
  if(tid<32) rdg[tid]=1.0f/Lb[tid*DS+tid];
  __syncthreads();
  for(int ii=0;ii<Dd;++ii){
    float rdi=rdg[ii];
    #pragma unroll
    for(int p=0;p<4;p++){int cell=tid+(p<<8);int r=cell>>5,c=cell&31;
      if(r>ii) Xs[r*DS+c] -= Lb[r*DS+ii]*(Xs[ii*DS+c]*rdi);}
    __syncthreads();
  }
  for(int p=0;p<4;p++){int cell=tid+(p<<8);int r=cell>>5,c=cell&31; Xs[r*DS+c]*=rdg[r];}
  __syncthreads();
  float a0=0,a1=0,a2=0,a3=0;
  #pragma unroll
  for(int m=0;m<Dd;++m){ float xr=Xs[m*DS+i8];
    a0=fmaf(xr,Xs[m*DS+c4],a0);   a1=fmaf(xr,Xs[m*DS+c4+1],a1);
    a2=fmaf(xr,Xs[m*DS+c4+2],a2); a3=fmaf(xr,Xs[m*DS+c4+3],a3);}
  *(float4*)(out+O_CROSS+ob+((size_t)i8<<5)+c4)=make_float4(a0,a1,a2,a3);  // Pinv staged in Cross slot
  float4 lv=make_float4(Xs[i8*DS+c4],Xs[i8*DS+c4+1],Xs[i8*DS+c4+2],Xs[i8*DS+c4+3]);
  *(float4*)(wsf+F_LG+ob+((size_t)i8<<5)+c4)=lv;                           // Linv over L
}

__global__ __launch_bounds__(256) void k_backward(float* wsf, float* out){
  __shared__ float sm[6720];
  int tid=threadIdx.x; int i8=tid>>3, c4=(tid&7)*4;
  if(blockIdx.x==0){
    // ======= RTS smoother =======
    float* Cov=sm;       float* Gs=sm+1056;  float* Ps=sm+2112;
    float* T1=sm+3168;   float* Us=sm+4224;  float* CR=sm+5280;
    float* msv=sm+6336;  float* gsv=sm+6368; float* scr=sm+6400;
    for(int p=0;p<4;p++){int cell=tid+(p<<8);int r=cell>>5,c=cell&31; Cov[r*DS+c]=wsf[F_COVT+cell];}
    if(tid<32) msv[tid]=wsf[F_MLAST+tid];
    int t=NN-1;
    size_t ob=(size_t)t*1024+((size_t)i8<<5)+c4;
    float4 gv=*(const float4*)(wsf+F_GG+ob);
    float4 pv=*(const float4*)(out+O_CROSS+ob);
    float gsc=(tid<32)? wsf[F_GSM+(size_t)t*32+tid]:0.f;
    __syncthreads();
    for(t=NN-1;t>=0;--t){
      Gs[i8*DS+c4]=gv.x; Gs[i8*DS+c4+1]=gv.y; Gs[i8*DS+c4+2]=gv.z; Gs[i8*DS+c4+3]=gv.w;
      Ps[i8*DS+c4]=pv.x; Ps[i8*DS+c4+1]=pv.y; Ps[i8*DS+c4+2]=pv.z; Ps[i8*DS+c4+3]=pv.w;
      if(tid<32) gsv[tid]=gsc;
      for(int p=0;p<4;p++){int cell=tid+(p<<8);int r=cell>>5,c=cell&31;
        T1[r*DS+c]=Cov[r*DS+c]+msv[r]*msv[c];}
      __syncthreads();                                   // B1
      if(t>0){ size_t ob2=(size_t)(t-1)*1024+((size_t)i8<<5)+c4;
        gv=*(const float4*)(wsf+F_GG+ob2);
        pv=*(const float4*)(out+O_CROSS+ob2);
        gsc=(tid<32)? wsf[F_GSM+(size_t)(t-1)*32+tid]:0.f; }
      float ac0=0,ac1=0,ac2=0,ac3=0, au0=0,au1=0,au2=0,au3=0;
      #pragma unroll
      for(int m=0;m<Dd;++m){ float g_=Gs[i8*DS+m];
        ac0=fmaf(g_,T1[m*DS+c4],ac0);   ac1=fmaf(g_,T1[m*DS+c4+1],ac1);
        ac2=fmaf(g_,T1[m*DS+c4+2],ac2); ac3=fmaf(g_,T1[m*DS+c4+3],ac3);
        au0=fmaf(g_,Cov[m*DS+c4],au0);   au1=fmaf(g_,Cov[m*DS+c4+1],au1);
        au2=fmaf(g_,Cov[m*DS+c4+2],au2); au3=fmaf(g_,Cov[m*DS+c4+3],au3);}
      CR[i8*DS+c4]  =ac0+gsv[i8]*msv[c4];
      CR[i8*DS+c4+1]=ac1+gsv[i8]*msv[c4+1];
      CR[i8*DS+c4+2]=ac2+gsv[i8]*msv[c4+2];
      CR[i8*DS+c4+3]=ac3+gsv[i8]*msv[c4+3];
      Us[i8*DS+c4]=au0; Us[i8*DS+c4+1]=au1; Us[i8*DS+c4+2]=au2; Us[i8*DS+c4+3]=au3;
      { int s=tid>>5, ii=tid&31; float pp=0.f;
        #pragma unroll
        for(int m=0;m<4;++m) pp=fmaf(Gs[ii*DS+s*4+m], msv[s*4+m], pp);
        scr[(s<<5)+ii]=pp; }
      __syncthreads();                                   // B2
      float cn0=0,cn1=0,cn2=0,cn3=0;
      #pragma unroll
      for(int m=0;m<Dd;++m){ float u_=Us[i8*DS+m];
        cn0=fmaf(u_,Gs[(c4  )*DS+m],cn0); cn1=fmaf(u_,Gs[(c4+1)*DS+m],cn1);
        cn2=fmaf(u_,Gs[(c4+2)*DS+m],cn2); cn3=fmaf(u_,Gs[(c4+3)*DS+m],cn3);}
      cn0+=Ps[i8*DS+c4]; cn1+=Ps[i8*DS+c4+1]; cn2+=Ps[i8*DS+c4+2]; cn3+=Ps[i8*DS+c4+3];
      float mn=0.f;
      if(tid<32){ mn=gsv[tid];
        #pragma unroll
        for(int s=0;s<8;++s) mn+=scr[(s<<5)+tid];
        out[O_EX+(size_t)t*32+tid]=mn; }
      __syncthreads();                                   // B2b (scr/gsv/msv reads done)
      if(tid<32) msv[tid]=mn;
      Cov[i8*DS+c4]=cn0; Cov[i8*DS+c4+1]=cn1; Cov[i8*DS+c4+2]=cn2; Cov[i8*DS+c4+3]=cn3;
      __syncthreads();                                   // B3
      { float mi=msv[i8];
        float4 ex=make_float4(cn0+mi*msv[c4],cn1+mi*msv[c4+1],cn2+mi*msv[c4+2],cn3+mi*msv[c4+3]);
        *(float4*)(out+O_EXXT+(size_t)t*1024+((size_t)i8<<5)+c4)=ex;
        float4 cro=make_float4(CR[(c4)*DS+i8],CR[(c4+1)*DS+i8],CR[(c4+2)*DS+i8],CR[(c4+3)*DS+i8]);
        *(float4*)(out+O_CROSS+(size_t)t*1024+((size_t)i8<<5)+c4)=cro;
      }
    }
  } else {
    // ======= backward sampler =======
    float* Gs=sm; float* Ls=sm+1056; float* xsv=sm+2112;
    float* gsv=sm+2144; float* ev=sm+2176; float* scr=sm+2208;
    if(tid<32) xsv[tid]=wsf[F_XT+tid];
    int t=NN-1;
    size_t ob=(size_t)t*1024+((size_t)i8<<5)+c4;
    float4 gv=*(const float4*)(wsf+F_GG+ob);
    float4 lv=*(const float4*)(wsf+F_LG+ob);      // Linv (written by k_pinv)
    float gsc=(tid<32)? wsf[F_GSM+(size_t)t*32+tid]:0.f;
    float ee =(tid<32)? wsf[F_EPS+(size_t)t*32+tid]:0.f;
    __syncthreads();
    for(t=NN-1;t>=0;--t){
      Gs[i8*DS+c4]=gv.x; Gs[i8*DS+c4+1]=gv.y; Gs[i8*DS+c4+2]=gv.z; Gs[i8*DS+c4+3]=gv.w;
      Ls[i8*DS+c4]=lv.x; Ls[i8*DS+c4+1]=lv.y; Ls[i8*DS+c4+2]=lv.z; Ls[i8*DS+c4+3]=lv.w;
      if(tid<32){ gsv[tid]=gsc; ev[tid]=ee; }
      __syncthreads();
      if(t>0){ size_t ob2=(size_t)(t-1)*1024+((size_t)i8<<5)+c4;
        gv=*(const float4*)(wsf+F_GG+ob2);
        lv=*(const float4*)(wsf+F_LG+ob2);
        gsc=(tid<32)? wsf[F_GSM+(size_t)(t-1)*32+tid]:0.f;
        ee =(tid<32)? wsf[F_EPS+(size_t)(t-1)*32+tid]:0.f; }
      { int s=tid>>5, ii=tid&31; float pp=0.f;
        #pragma unroll
        for(int m=0;m<4;++m){ int mm=s*4+m;
          pp=fmaf(Gs[ii*DS+mm], xsv[mm], pp);
          pp=fmaf(Ls[mm*DS+ii], ev[mm], pp); }
        scr[(s<<5)+ii]=pp; }
      __syncthreads();
      if(tid<32){ float nx=gsv[tid];
        #pragma unroll
        for(int s=0;s<8;++s) nx+=scr[(s<<5)+tid];
        out[O_Z+(size_t)t*32+tid]=nx; xsv[tid]=nx; }
      __syncthreads();
    }
  }
}

__global__ __launch_bounds__(256) void k_terms(const float* rJ, const float* rh,
    const float* plam, float* wsf, double* wsd, float* out){
  __shared__ float slam[1056], slamA[1056], sata[1056];
  __shared__ float slamb[32], satlb[32], cst[16], sw[16];
  __shared__ double sd[256];
  int tid=threadIdx.x; int i8=tid>>3, c4=(tid&7)*4;
  for(int p=0;p<4;p++){int cell=tid+(p<<8);int r=cell>>5,c=cell&31;
    slam[r*DS+c]=wsf[F_LAM+cell]; slamA[r*DS+c]=wsf[F_LAMA+cell]; sata[r*DS+c]=wsf[F_ATLAMA+cell];}
  if(tid<32){slamb[tid]=wsf[F_LAMB+tid]; satlb[tid]=wsf[F_ATLAMB+tid];}
  if(tid<16) cst[tid] = -0.5f*wsf[F_BTLAMBK+tid] + 0.5f*wsf[F_LOGDETK+tid];
  __syncthreads();
  double dr=0.0, dt=0.0, dm=0.0;
  int t0=blockIdx.x*8;
  for(int tt=0;tt<8;++tt){
    int t=t0+tt;
    if(t<NN){ if(tid<16) sw[tid]=out[O_CAT+(size_t)t*16+tid]; }
    __syncthreads();
    size_t cb=(size_t)t*1024+((size_t)i8<<5)+c4;
    float4 exT=*(const float4*)(out+O_EXXT+cb);
    float4 rj =*(const float4*)(rJ+cb);
    dr += -0.5*(double)(rj.x*exT.x+rj.y*exT.y+rj.z*exT.z+rj.w*exT.w);
    if(tid<32) dr += (double)(rh[(size_t)t*32+tid]*out[O_EX+(size_t)t*32+tid]);
    if(t>=1){
      dt += -0.5*(double)(slam[i8*DS+c4]*exT.x + slam[i8*DS+c4+1]*exT.y
                        + slam[i8*DS+c4+2]*exT.z + slam[i8*DS+c4+3]*exT.w);
      if(tid<32) dt += (double)(slamb[tid]*out[O_EX+(size_t)t*32+tid]);
    }
    if(t<NN){
      float4 crT =*(const float4*)(out+O_CROSS+cb);
      float4 exT1=*(const float4*)(out+O_EXXT+cb+1024);
      dt += (double)(slamA[i8*DS+c4]*crT.x + slamA[i8*DS+c4+1]*crT.y
                   + slamA[i8*DS+c4+2]*crT.z + slamA[i8*DS+c4+3]*crT.w)
          -0.5*(double)(sata[i8*DS+c4]*exT.x + sata[i8*DS+c4+1]*exT.y
                      + sata[i8*DS+c4+2]*exT.z + sata[i8*DS+c4+3]*exT.w);
      if(tid<32) dt -= (double)(satlb[tid]*out[O_EX+(size_t)t*32+tid]);
      const float* pe1=(const float*)&exT1; const float* pcr=(const float*)&crT; const float* pe0=(const float*)&exT;
      #pragma unroll
      for(int q=0;q<4;q++){
        int cc=(i8<<5)+c4+q;
        float wl=0.f, wa=0.f, wt2=0.f;
        #pragma unroll
        for(int k2=0;k2<KK;k2++){ float wv=sw[k2];
          wl =fmaf(wv, plam[(size_t)k2*1024+cc], wl);
          wa =fmaf(wv, wsf[F_LAMAK+(size_t)k2*1024+cc], wa);
          wt2=fmaf(wv, wsf[F_ATLAMAK+(size_t)k2*1024+cc], wt2);}
        dm += (double)(-0.5f*wl*pe1[q] + wa*pcr[q] - 0.5f*wt2*pe0[q]);
      }
      if(tid<32){
        float wlb=0.f, wtb=0.f;
        #pragma unroll
        for(int k2=0;k2<KK;k2++){ wlb=fmaf(sw[k2], wsf[F_LAMBK+k2*32+tid], wlb);
                                  wtb=fmaf(sw[k2], wsf[F_ATLAMBK+k2*32+tid], wtb);}
        dm += (double)(wlb*out[O_EX+(size_t)(t+1)*32+tid] - wtb*out[O_EX+(size_t)t*32+tid]);
      }
      if(tid<16) dm += (double)(sw[tid]*cst[tid]);
    }
    __syncthreads();
  }
  double r1=blk_red(dr,sd,tid);
  double r2=blk_red(dt,sd,tid);
  double r3=blk_red(dm,sd,tid);
  if(tid==0){ wsd[WSD_PR+blockIdx.x]=r1; wsd[WSD_PT+blockIdx.x]=r2; wsd[WSD_PM+blockIdx.x]=r3; }
}

__global__ __launch_bounds__(256) void k_final(const float* il, const float* tl,
    const float* ilp, const float* tlp, const float* ptau, float* wsf, double* wsd, float* out){
  __shared__ double sd[256];
  int tid=threadIdx.x;
  // hmm_kl
  double ez=0.0;
  for(int b=0;b<128;++b) ez += (double)wsf[F_EZ + b*256 + tid];
  double v = ez * (double)(tl[tid]-tlp[tid]);
  if(tid<16) v += (double)out[O_CAT+tid] * (double)(il[tid]-ilp[tid]);
  double hmmkl = blk_red(v, sd, tid) - (double)wsf[F_SC+0];
  // partial sums from k_terms
  double a=0,b2=0,c=0;
  for(int q=0;q<4;q++){int b3=tid+q*256; a+=wsd[WSD_PR+b3]; b2+=wsd[WSD_PT+b3]; c+=wsd[WSD_PM+b3];}
  double recog=blk_red(a,sd,tid), trns=blk_red(b2,sd,tid), mixt=blk_red(c,sd,tid);
  // init dots
  double ia=0, ib=0, va=0, vb=0;
  for(int p=0;p<4;p++){int cell=tid+(p<<8);
    float e0=out[O_EXXT+cell];
    ia += (double)(wsf[F_TAU+cell]*e0);
    ib += (double)(ptau[cell]*e0);
  }
  if(tid<32){ float ex0=out[O_EX+tid];
    va=(double)(ex0*wsf[F_TAUMU+tid]); vb=(double)(ex0*wsf[F_TPM+tid]); }
  double s_ia=blk_red(ia,sd,tid), s_ib=blk_red(ib,sd,tid);
  double s_va=blk_red(va,sd,tid), s_vb=blk_red(vb,sd,tid);
  if(tid==0){
    double init_term = -0.5*s_ia + s_va + wsd[WSD_LOGC0];
    double mix_init  = -0.5*s_ib + s_vb + wsd[WSD_MIXC];
    double trans_term = trns + (double)NN*(-0.5*wsd[WSD_BTLAMB] + 0.5*wsd[WSD_LDLAM] - 0.5*Dd*LOG2PI_);
    double mix_trans  = mixt - 0.5*(double)NN*(double)Dd*LOG2PI_;
    double lds_kl = (init_term+trans_term) + recog - wsd[WSD_LOGZQ] - (mix_init+mix_trans);
    out[O_KL] = (float)(lds_kl + hmmkl);
  }
}

// ---------------- launch ----------------
extern "C" void kernel_launch(void* const* d_in, const int* in_sizes, int n_in,
                              void* d_out, int out_size, void* d_ws, size_t ws_size,
                              hipStream_t stream){
  const float* rJ  =(const float*)d_in[0];
  const float* rh  =(const float*)d_in[1];
  const float* loc =(const float*)d_in[2];
  const float* Tp  =(const float*)d_in[3];
  const float* Lp  =(const float*)d_in[4];
  const float* X   =(const float*)d_in[5];
  const float* il  =(const float*)d_in[6];
  const float* tl  =(const float*)d_in[7];
  const float* plam=(const float*)d_in[8];
  const float* pX  =(const float*)d_in[9];
  const float* ptau=(const float*)d_in[10];
  const float* pmu =(const float*)d_in[11];
  const float* ilp =(const float*)d_in[12];
  const float* tlp =(const float*)d_in[13];
  const int*   seed=(const int*)d_in[14];
  float* out=(float*)d_out;
  double* wsd=(double*)d_ws;
  float* wsf=(float*)((char*)d_ws + 32768);

  k_setup<<<1,256,0,stream>>>(rJ,rh,loc,Tp,Lp,X,plam,pX,ptau,pmu,wsf,wsd);
  k_eps<<<1024,256,0,stream>>>(seed,wsf);
  k_mainseq<<<3,256,0,stream>>>(rJ,rh,il,tl,wsf,wsd,out);
  k_cat<<<128,256,0,stream>>>(tl,wsf,out);
  k_pinv<<<NN,256,0,stream>>>(wsf,out);
  k_backward<<<2,256,0,stream>>>(wsf,out);
  k_terms<<<1024,256,0,stream>>>(rJ,rh,plam,wsf,wsd,out);
  k_final<<<1,256,0,stream>>>(il,tl,ilp,tlp,ptau,wsf,wsd,out);
}

// Round 3
// 11000.363 us; speedup vs baseline: 32.2843x; 32.2843x over previous
//
#include <hip/hip_runtime.h>
#include <math.h>
#include <stdint.h>

#define Dd 32
#define TT 8192
#define NN 8191
#define KK 16
#define LOG2PI_ 1.8378770664093453

// ---------------- ws doubles ----------------
#define WSD_LOGC0  0
#define WSD_LOGZQ  1
#define WSD_MIXC   3
#define WSD_LDLAM  4
#define WSD_BTLAMB 5
#define WSD_PR     8
#define WSD_PT     1032
#define WSD_PM     2056
// ---------------- ws floats (base = byte 32768) ----------------
#define F_TAU      0
#define F_TAUMU    1024
#define F_LAM      1056
#define F_A        2080
#define F_B        3104
#define F_ATLAM    3136
#define F_ATLAMA   4160
#define F_LAMA     5184
#define F_LAMB     6208
#define F_ATLAMB   6240
#define F_SC       6272
#define F_LAMAK    6304
#define F_ATLAMAK  22688
#define F_LAMBK    39072
#define F_ATLAMBK  39584
#define F_BTLAMBK  40096
#define F_LOGDETK  40112
#define F_TPM      40128
#define F_J0       40160
#define F_H0       41184
#define F_MLAST    41216
#define F_COVT     41248
#define F_XT       42272
#define F_TPOW     42304
#define F_ALPHA    45632
#define F_BETA     176704
#define F_EZ       307776
#define F_SCAN     340544

// scan slot layout (stride 2148 floats)
#define SSTR   2148
#define POFF   0
#define QOFF   528
#define ROFF   1056
#define PPOFF  2080
#define QQOFF  2112
#define GAMOFF 2144
#define FLGOFF 2146
// affine (B) slot layout (within same slots)
#define BG     0
#define BCZ    1024
#define BCM    1056
#define BP     1088

// out offsets (floats)
#define O_Z     ((size_t)0)
#define O_EX    ((size_t)262144)
#define O_EXXT  ((size_t)524288)
#define O_CROSS ((size_t)8912896)
#define O_CAT   ((size_t)17300480)
#define O_KL    ((size_t)17431536)

// ---------------- threefry ----------------
__device__ __forceinline__ uint32_t rotl32(uint32_t v, int d){ return (v<<d)|(v>>(32-d)); }
__device__ __forceinline__ void threefry2x32(uint32_t k0, uint32_t k1, uint32_t x0, uint32_t x1,
                                             uint32_t& o0, uint32_t& o1){
  uint32_t ks2 = k0 ^ k1 ^ 0x1BD11BDAu;
  x0 += k0; x1 += k1;
  x0+=x1; x1=rotl32(x1,13); x1^=x0;  x0+=x1; x1=rotl32(x1,15); x1^=x0;
  x0+=x1; x1=rotl32(x1,26); x1^=x0;  x0+=x1; x1=rotl32(x1, 6); x1^=x0;
  x0+=k1; x1+=ks2+1u;
  x0+=x1; x1=rotl32(x1,17); x1^=x0;  x0+=x1; x1=rotl32(x1,29); x1^=x0;
  x0+=x1; x1=rotl32(x1,16); x1^=x0;  x0+=x1; x1=rotl32(x1,24); x1^=x0;
  x0+=ks2; x1+=k0+2u;
  x0+=x1; x1=rotl32(x1,13); x1^=x0;  x0+=x1; x1=rotl32(x1,15); x1^=x0;
  x0+=x1; x1=rotl32(x1,26); x1^=x0;  x0+=x1; x1=rotl32(x1, 6); x1^=x0;
  x0+=k0; x1+=k1+3u;
  x0+=x1; x1=rotl32(x1,17); x1^=x0;  x0+=x1; x1=rotl32(x1,29); x1^=x0;
  x0+=x1; x1=rotl32(x1,16); x1^=x0;  x0+=x1; x1=rotl32(x1,24); x1^=x0;
  x0+=k1; x1+=ks2+4u;
  x0+=x1; x1=rotl32(x1,13); x1^=x0;  x0+=x1; x1=rotl32(x1,15); x1^=x0;
  x0+=x1; x1=rotl32(x1,26); x1^=x0;  x0+=x1; x1=rotl32(x1, 6); x1^=x0;
  x0+=ks2; x1+=k0+5u;
  o0=x0; o1=x1;
}
__device__ __forceinline__ float tf_normal(uint32_t bits){
  float fl = __uint_as_float((bits>>9) | 0x3F800000u) - 1.0f;
  const float lo = -0.99999994f;
  float u = fmaxf(lo, fl*2.0f + lo);
  float w = -log1pf(-u*u);
  float p;
  if (w < 5.0f){
    w -= 2.5f;
    p = 2.81022636e-08f;
    p = fmaf(p,w,3.43273939e-07f); p = fmaf(p,w,-3.5233877e-06f);
    p = fmaf(p,w,-4.39150654e-06f); p = fmaf(p,w,0.00021858087f);
    p = fmaf(p,w,-0.00125372503f); p = fmaf(p,w,-0.00417768164f);
    p = fmaf(p,w,0.246640727f); p = fmaf(p,w,1.50140941f);
  } else {
    w = sqrtf(w) - 3.0f;
    p = -0.000200214257f;
    p = fmaf(p,w,0.000100950558f); p = fmaf(p,w,0.00134934322f);
    p = fmaf(p,w,-0.00367342844f); p = fmaf(p,w,0.00573950773f);
    p = fmaf(p,w,-0.0076224613f); p = fmaf(p,w,0.00943887047f);
    p = fmaf(p,w,1.00167406f); p = fmaf(p,w,2.83297682f);
  }
  return 1.4142135381698608f * (p*u);
}

// ---------------- helpers ----------------
__device__ __forceinline__ void tri_rc(int i, int& r, int& c){
  int rr = (int)((sqrtf(8.f*(float)i+1.f)-1.f)*0.5f);
  while((rr+1)*(rr+2)/2 <= i) ++rr;
  while(rr*(rr+1)/2 > i) --rr;
  r = rr; c = i - rr*(rr+1)/2;
}

// cholesky of 32x32 (full stride-33 in Ms, lower used) -> Lb (stride 33), rdg; returns sum log diag
template<int NT>
__device__ double tchol(float* Ms, float* Lb, float* rdg, int tid){
  double slog = 0.0;
  for(int j=0;j<Dd;++j){
    float dd = Ms[j*33+j];
    float sq = sqrtf(dd); float rd = 1.0f/sq; float invd = rd*rd;
    slog += log((double)sq);
    if(tid==0) rdg[j]=rd;
    for(int q=tid;q<1056;q+=NT){
      int r=q/33, c=q-33*r;
      if(c==j){ if(r>=j) Lb[r*33+j] = (r==j)? sq : Ms[r*33+j]*rd; }
      else if(r>j && c>j && c<=r) Ms[r*33+c] -= Ms[r*33+j]*(Ms[c*33+j]*invd);
    }
    __syncthreads();
  }
  return slog;
}

// solve (L L^T) X = B ; RHS layout [col*33 + row]; cols < nfwd get fwd+bwd, cols in [nfwd,ncols) bwd only (L^-T b)
template<int NT>
__device__ void tsolve(float* RHS, const float* Lb, const float* rdg, int tid, int ncols, int nfwd){
  int cells = ncols*32;
  for(int ii=0;ii<Dd;++ii){
    float rdi = rdg[ii];
    for(int q=tid;q<cells;q+=NT){
      int c=q>>5, r=q&31;
      if(c<nfwd && r>ii) RHS[c*33+r] -= Lb[r*33+ii]*(RHS[c*33+ii]*rdi);
    }
    __syncthreads();
  }
  for(int q=tid;q<cells;q+=NT){ int c=q>>5, r=q&31; if(c<nfwd) RHS[c*33+r] *= rdg[r]; }
  __syncthreads();
  for(int ii=Dd-1;ii>=0;--ii){
    float rdi = rdg[ii];
    for(int q=tid;q<cells;q+=NT){
      int c=q>>5, r=q&31;
      if(r<ii) RHS[c*33+r] -= Lb[ii*33+r]*(RHS[c*33+ii]*rdi);
    }
    __syncthreads();
  }
  for(int q=tid;q<cells;q+=NT){ int c=q>>5, r=q&31; RHS[c*33+r] *= rdg[r]; }
  __syncthreads();
}

__device__ __forceinline__ double blk_red(double v, double* sd, int tid){
  sd[tid]=v; __syncthreads();
  for(int s=128;s>0;s>>=1){ if(tid<s) sd[tid]+=sd[tid+s]; __syncthreads(); }
  double r=sd[0]; __syncthreads(); return r;
}
__device__ double blk_logdet(float* Ms, int tid){
  double sl = 0.0;
  for (int j=0;j<Dd;++j){
    float dd = Ms[j*33+j];
    sl += log((double)dd);
    float invd = 1.0f/dd;
    #pragma unroll
    for(int p=0;p<4;p++){
      int cell = tid + (p<<8); int r=cell>>5, c=cell&31;
      if(r>j && c>j && c<=r) Ms[r*33+c] -= Ms[r*33+j]*(Ms[c*33+j]*invd);
    }
    __syncthreads();
  }
  return sl;
}

// ---------------- setup ----------------
__global__ __launch_bounds__(256) void k_setup(const float* rJ, const float* rh, const float* loc,
    const float* Tp, const float* Lp, const float* X, const float* plam, const float* pX,
    const float* ptau, const float* pmu, float* wsf, double* wsd){
  __shared__ float s1[1056], s2[1056], s3[1056];
  __shared__ float sv[32], sv2[32];
  int tid=threadIdx.x;
  for(int p=0;p<4;p++){int cell=tid+(p<<8);int r=cell>>5,c=cell&31; s1[r*33+c]=Tp[cell];}
  if(tid<32) sv[tid]=loc[tid];
  __syncthreads();
  for(int p=0;p<4;p++){int cell=tid+(p<<8);int r=cell>>5,c=cell&31;
    float a=0.f;
    #pragma unroll
    for(int m=0;m<Dd;++m) a=fmaf(s1[r*33+m], s1[c*33+m], a);
    if(r==c) a+=1e-8f;
    s2[r*33+c]=a; wsf[F_TAU+cell]=a; wsf[F_J0+cell]=a+rJ[cell];
  }
  __syncthreads();
  if(tid<32){ float tm=0.f;
    #pragma unroll
    for(int m=0;m<Dd;++m) tm=fmaf(s2[tid*33+m], sv[m], tm);
    sv2[tid]=tm; wsf[F_TAUMU+tid]=tm; wsf[F_H0+tid]=tm+rh[tid];
  }
  __syncthreads();
  {
    double ldt = blk_logdet(s2, tid);
    if(tid==0){ double dd=0; for(int m=0;m<Dd;++m) dd += (double)sv[m]*(double)sv2[m];
      wsd[WSD_LOGC0] = -0.5*dd + 0.5*ldt - 0.5*Dd*LOG2PI_; }
  }
  __syncthreads();
  for(int p=0;p<4;p++){int cell=tid+(p<<8);int r=cell>>5,c=cell&31; s1[r*33+c]=Lp[cell];}
  __syncthreads();
  for(int p=0;p<4;p++){int cell=tid+(p<<8);int r=cell>>5,c=cell&31;
    float a=0.f;
    #pragma unroll
    for(int m=0;m<Dd;++m) a=fmaf(s1[r*33+m], s1[c*33+m], a);
    if(r==c) a+=1e-8f;
    s2[r*33+c]=a; wsf[F_LAM+cell]=a;
  }
  __syncthreads();
  for(int p=0;p<4;p++){int cell=tid+(p<<8);int r=cell>>5,c=cell&31;
    float a=X[r*33+c]; s3[r*33+c]=a; wsf[F_A+cell]=a; }
  if(tid<32){ sv[tid]=X[tid*33+32]; wsf[F_B+tid]=sv[tid]; }
  __syncthreads();
  for(int p=0;p<4;p++){int cell=tid+(p<<8);int r=cell>>5,c=cell&31;
    float a=0.f,b2=0.f;
    #pragma unroll
    for(int m=0;m<Dd;++m){ a=fmaf(s2[r*33+m], s3[m*33+c], a); b2=fmaf(s3[m*33+r], s2[m*33+c], b2); }
    s1[r*33+c]=a; wsf[F_LAMA+cell]=a; wsf[F_ATLAM+cell]=b2;
  }
  if(tid<32){ float lb=0.f;
    #pragma unroll
    for(int m=0;m<Dd;++m) lb=fmaf(s2[tid*33+m], sv[m], lb);
    sv2[tid]=lb; wsf[F_LAMB+tid]=lb;
  }
  __syncthreads();
  for(int p=0;p<4;p++){int cell=tid+(p<<8);int r=cell>>5,c=cell&31;
    float a=0.f;
    #pragma unroll
    for(int m=0;m<Dd;++m) a=fmaf(s3[m*33+r], s1[m*33+c], a);
    wsf[F_ATLAMA+cell]=a;
  }
  if(tid<32){ float ab=0.f;
    #pragma unroll
    for(int m=0;m<Dd;++m) ab=fmaf(s3[m*33+tid], sv2[m], ab);
    wsf[F_ATLAMB+tid]=ab;
  }
  if(tid==0){ double bb=0; for(int m=0;m<Dd;++m) bb += (double)sv[m]*(double)sv2[m];
    wsd[WSD_BTLAMB]=bb; }
  __syncthreads();
  {
    double ldl = blk_logdet(s2, tid);
    if(tid==0) wsd[WSD_LDLAM]=ldl;
  }
  for(int p=0;p<4;p++){int cell=tid+(p<<8);int r=cell>>5,c=cell&31; s1[r*33+c]=ptau[cell];}
  if(tid<32) sv[tid]=pmu[tid];
  __syncthreads();
  if(tid<32){ float tm=0.f;
    #pragma unroll
    for(int m=0;m<Dd;++m) tm=fmaf(s1[tid*33+m], sv[m], tm);
    sv2[tid]=tm; wsf[F_TPM+tid]=tm;
  }
  __syncthreads();
  {
    double ldp = blk_logdet(s1, tid);
    if(tid==0){ double dd=0; for(int m=0;m<Dd;++m) dd += (double)sv[m]*(double)sv2[m];
      wsd[WSD_MIXC] = -0.5*dd + 0.5*ldp - 0.5*Dd*LOG2PI_; }
  }
  __syncthreads();
  for(int k2=0;k2<KK;++k2){
    for(int p=0;p<4;p++){int cell=tid+(p<<8);int r=cell>>5,c=cell&31;
      s2[r*33+c]=plam[k2*1024+cell]; s3[r*33+c]=pX[k2*1056 + r*33 + c];}
    if(tid<32) sv[tid]=pX[k2*1056 + tid*33 + 32];
    __syncthreads();
    for(int p=0;p<4;p++){int cell=tid+(p<<8);int r=cell>>5,c=cell&31;
      float a=0.f;
      #pragma unroll
      for(int m=0;m<Dd;++m) a=fmaf(s2[r*33+m], s3[m*33+c], a);
      s1[r*33+c]=a; wsf[F_LAMAK + (size_t)k2*1024 + cell]=a;
    }
    if(tid<32){ float lb=0.f;
      #pragma unroll
      for(int m=0;m<Dd;++m) lb=fmaf(s2[tid*33+m], sv[m], lb);
      sv2[tid]=lb; wsf[F_LAMBK + k2*32 + tid]=lb;
    }
    __syncthreads();
    for(int p=0;p<4;p++){int cell=tid+(p<<8);int r=cell>>5,c=cell&31;
      float a=0.f;
      #pragma unroll
      for(int m=0;m<Dd;++m) a=fmaf(s3[m*33+r], s1[m*33+c], a);
      wsf[F_ATLAMAK + (size_t)k2*1024 + cell]=a;
    }
    if(tid<32){ float ab=0.f;
      #pragma unroll
      for(int m=0;m<Dd;++m) ab=fmaf(s3[m*33+tid], sv2[m], ab);
      wsf[F_ATLAMBK + k2*32 + tid]=ab;
    }
    if(tid==0){ float bb=0.f; for(int m=0;m<Dd;++m) bb=fmaf(sv[m],sv2[m],bb);
      wsf[F_BTLAMBK + k2]=bb; }
    __syncthreads();
    double dk = blk_logdet(s2, tid);
    if(tid==0) wsf[F_LOGDETK + k2]=(float)dk;
  }
}

// ---------------- eps (threefry) -> out O_Z region (staged) ----------------
__global__ __launch_bounds__(256) void k_eps(const int* seedp, float* outz){
  uint32_t seed = (uint32_t)seedp[0];
  uint32_t K0,K1;
  threefry2x32(0u, seed, 0u, 1u, K0, K1);
  uint32_t i = blockIdx.x*256u + threadIdx.x;
  uint32_t o0,o1;
  threefry2x32(K0, K1, 0u, i, o0, o1);
  outz[i] = tf_normal(o0 ^ o1);
}

// ---------------- HMM: log-powers of T ----------------
__global__ __launch_bounds__(256) void k_hmmpow(const float* tl, float* wsf){
  __shared__ float A0[256], A1[256];
  int tid=threadIdx.x;
  A0[tid]=tl[tid];
  wsf[F_TPOW+tid]=A0[tid];
  __syncthreads();
  float* cur=A0; float* nxt=A1;
  for(int k=1;k<13;++k){
    int i=tid>>4, j=tid&15;
    float mx=-3.0e38f;
    #pragma unroll
    for(int m=0;m<16;++m) mx=fmaxf(mx, cur[i*16+m]+cur[m*16+j]);
    float s=0.f;
    #pragma unroll
    for(int m=0;m<16;++m) s+=__expf(cur[i*16+m]+cur[m*16+j]-mx);
    float v=mx+__logf(s);
    nxt[tid]=v; wsf[F_TPOW+k*256+tid]=v;
    __syncthreads();
    float* t2=cur; cur=nxt; nxt=t2;
  }
}

// ---------------- HMM: alphas/betas via bit-decomposed powers ----------------
__global__ __launch_bounds__(256) void k_hmmab(const float* il, float* wsf){
  __shared__ float S[3328];
  int tid=threadIdx.x;
  for(int p=0;p<13;++p) S[p*256+tid]=wsf[F_TPOW+p*256+tid];
  __syncthreads();
  int n = blockIdx.x*256 + tid;
  if(n>NN-1) return;
  float v[16], w[16];
  #pragma unroll
  for(int j=0;j<16;++j) v[j]=il[j];
  for(int k=0;k<13;++k){
    if((n>>k)&1){
      #pragma unroll
      for(int j=0;j<16;++j){
        float mx=-3.0e38f;
        #pragma unroll
        for(int i2=0;i2<16;++i2) mx=fmaxf(mx, v[i2]+S[k*256+i2*16+j]);
        float s=0.f;
        #pragma unroll
        for(int i2=0;i2<16;++i2) s+=__expf(v[i2]+S[k*256+i2*16+j]-mx);
        w[j]=mx+__logf(s);
      }
      #pragma unroll
      for(int j=0;j<16;++j) v[j]=w[j];
    }
  }
  #pragma unroll
  for(int j=0;j<16;++j) wsf[F_ALPHA+(size_t)n*16+j]=v[j];
  if(n==NN-1){
    float mx=-3.0e38f;
    #pragma unroll
    for(int j=0;j<16;++j) mx=fmaxf(mx,v[j]);
    float s=0.f;
    #pragma unroll
    for(int j=0;j<16;++j) s+=__expf(v[j]-mx);
    wsf[F_SC+0]=mx+__logf(s);
  }
  // beta_n = log(T^(NN-1-n) * 1)
  int m = NN-1-n;
  float b[16];
  #pragma unroll
  for(int i2=0;i2<16;++i2) b[i2]=0.f;
  for(int k=0;k<13;++k){
    if((m>>k)&1){
      #pragma unroll
      for(int i2=0;i2<16;++i2){
        float mx=-3.0e38f;
        #pragma unroll
        for(int j=0;j<16;++j) mx=fmaxf(mx, S[k*256+i2*16+j]+b[j]);
        float s=0.f;
        #pragma unroll
        for(int j=0;j<16;++j) s+=__expf(S[k*256+i2*16+j]+b[j]-mx);
        w[i2]=mx+__logf(s);
      }
      #pragma unroll
      for(int i2=0;i2<16;++i2) b[i2]=w[i2];
    }
  }
  #pragma unroll
  for(int i2=0;i2<16;++i2) wsf[F_BETA+(size_t)n*16+i2]=b[i2];
}

// ---------------- cat_es + EZZNT partials ----------------
__global__ __launch_bounds__(256) void k_cat(const float* tl, float* wsf, float* out){
  __shared__ float Ts[256]; __shared__ float ar[16]; __shared__ float br[16];
  int tid=threadIdx.x;
  Ts[tid]=tl[tid];
  float logZ = wsf[F_SC+0];
  int i=tid>>4, j=tid&15;
  float acc=0.f;
  int n0=blockIdx.x*64;
  __syncthreads();
  for(int nn=0;nn<64;++nn){
    int n=n0+nn;
    if(n<NN-1){
      if(tid<16) ar[tid]=wsf[F_ALPHA+(size_t)n*16+tid];
      else if(tid<32) br[tid-16]=wsf[F_BETA+(size_t)(n+1)*16+(tid-16)];
      __syncthreads();
      acc += __expf(ar[i]+Ts[i*16+j]+br[j]-logZ);
      __syncthreads();
    }
    if(n<NN && tid<16)
      out[O_CAT+(size_t)n*16+tid]=__expf(wsf[F_ALPHA+(size_t)n*16+tid]+wsf[F_BETA+(size_t)n*16+tid]-logZ);
  }
  wsf[F_EZ + blockIdx.x*256 + tid]=acc;
}

// ---------------- build filter-scan leaves ----------------
__global__ __launch_bounds__(256) void k_leaf(const float* rJ, const float* rh, float* wsf, double* wsd){
  int k = blockIdx.x; int tid=threadIdx.x;
  float* pe = wsf + F_SCAN + (size_t)k*SSTR;
  if(k==NN){ if(tid==0) pe[FLGOFF]=0.f; return; }
  int t = k+1;
  for(int q=tid;q<528;q+=256){
    int r,c; tri_rc(q,r,c);
    pe[POFF+q] = wsf[F_ATLAMA + r*32+c] + ((r==c)?1e-6f:0.f);
    pe[QOFF+q] = wsf[F_LAM + r*32+c] + rJ[(size_t)t*1024 + r*32+c];
  }
  for(int q=tid;q<1024;q+=256) pe[ROFF+q] = -wsf[F_ATLAM+q];
  if(tid<32){
    pe[PPOFF+tid] = -wsf[F_ATLAMB+tid];
    pe[QQOFF+tid] = wsf[F_LAMB+tid] + rh[(size_t)t*32+tid];
  }
  if(tid==0){
    double g = -0.5*wsd[WSD_BTLAMB] + 0.5*wsd[WSD_LDLAM];
    *(double*)(pe+GAMOFF) = g;
    pe[FLGOFF]=1.f;
  }
}

// ---------------- filter-scan combine (Blelloch phase) ----------------
__global__ __launch_bounds__(64) void k_cf(float* wsf, int d, int mode){
  __shared__ float SA[2148], SB[2148];
  __shared__ float Ms[1089], Lb[1089], RHS[2178], rdg[32], sv[32];
  int tid = threadIdx.x;
  int i = blockIdx.x;
  int iA = (i<<(d+1)) + (1<<d) - 1;
  int iB = iA + (1<<d);
  float* base = wsf + F_SCAN;
  float* pa = base + (size_t)iA*SSTR;
  float* pb = base + (size_t)iB*SSTR;
  for(int p=0;p<9;p++){
    int q=tid+(p<<6);
    if(q<537){ ((float4*)SA)[q]=((const float4*)pa)[q]; ((float4*)SB)[q]=((const float4*)pb)[q]; }
  }
  __syncthreads();
  int fa = (SA[FLGOFF]!=0.f), fb = (SB[FLGOFF]!=0.f);
  if(mode==1){
    for(int p=0;p<9;p++){ int q=tid+(p<<6); if(q<537) ((float4*)pb)[q]=((float4*)SA)[q]; }
    if(tid==0) pa[FLGOFF]=0.f;
    return;
  }
  if(mode==2){
    for(int p=0;p<9;p++){ int q=tid+(p<<6); if(q<537) ((float4*)pa)[q]=((float4*)SB)[q]; }
  }
  float* X = (mode==2)? SB : SA;  int fx = (mode==2)? fb : fa;
  float* Y = (mode==2)? SA : SB;  int fy = (mode==2)? fa : fb;
  if(!fx && !fy){ if(tid==0) pb[FLGOFF]=0.f; return; }
  if(!fx){ for(int p=0;p<9;p++){ int q=tid+(p<<6); if(q<537) ((float4*)pb)[q]=((float4*)Y)[q]; } return; }
  if(!fy){ for(int p=0;p<9;p++){ int q=tid+(p<<6); if(q<537) ((float4*)pb)[q]=((float4*)X)[q]; } return; }
  // W = Q_x + P_y
  for(int q=tid;q<528;q+=64){
    int r,c; tri_rc(q,r,c);
    float w = X[QOFF+q] + Y[POFF+q];
    Ms[r*33+c]=w; Ms[c*33+r]=w;
  }
  __syncthreads();
  double slog = tchol<64>(Ms, Lb, rdg, tid);
  // RHS: cols 0..31 = rows of R_x ; 32..63 = cols of R_y ; 64 = s
  for(int q=tid;q<2080;q+=64){
    int c=q>>5, r=q&31;
    float v;
    if(c<32)      v = X[ROFF + c*32 + r];
    else if(c<64) v = Y[ROFF + r*32 + (c-32)];
    else        { v = X[QQOFF+r] + Y[PPOFF+r]; sv[r]=v; }
    RHS[c*33+r]=v;
  }
  __syncthreads();
  tsolve<64>(RHS, Lb, rdg, tid, 65, 65);
  // outputs
  for(int q=tid;q<528;q+=64){
    int r,c; tri_rc(q,r,c);
    float accP=0.f, accQ=0.f;
    #pragma unroll
    for(int m=0;m<32;++m){
      accP = fmaf(X[ROFF + r*32 + m], RHS[c*33+m], accP);
      accQ = fmaf(Y[ROFF + m*32 + r], RHS[(32+c)*33+m], accQ);
    }
    pb[POFF+q] = X[POFF+q] - accP;
    pb[QOFF+q] = Y[QOFF+q] - accQ;
  }
  for(int q=tid;q<1024;q+=64){
    int r=q>>5, c=q&31;
    float acc=0.f;
    #pragma unroll
    for(int m=0;m<32;++m) acc = fmaf(X[ROFF + r*32 + m], RHS[(32+c)*33+m], acc);
    pb[ROFF+q] = -acc;
  }
  if(tid<32){
    float accp=0.f, accq=0.f;
    #pragma unroll
    for(int m=0;m<32;++m){
      accp = fmaf(X[ROFF + tid*32 + m], RHS[64*33+m], accp);
      accq = fmaf(Y[ROFF + m*32 + tid], RHS[64*33+m], accq);
    }
    pb[PPOFF+tid] = X[PPOFF+tid] - accp;
    pb[QQOFF+tid] = Y[QQOFF+tid] - accq;
  }
  if(tid==0){
    double g = *(double*)(X+GAMOFF) + *(double*)(Y+GAMOFF);
    double dot=0.0;
    for(int m=0;m<32;++m) dot += (double)sv[m]*(double)RHS[64*33+m];
    g += 0.5*dot - slog;
    *(double*)(pb+GAMOFF) = g;
    pb[FLGOFF]=1.f;
  }
}

// ---------------- per-t pointwise: Jf/hf -> G,g,Pinv,Linv^T eps ; special last ----------------
__global__ __launch_bounds__(256) void k_point(float* wsf, double* wsd, float* out){
  __shared__ float SE[2148];
  __shared__ float Ms[1089], Lb[1089], RHS[2178], JfF[1089];
  __shared__ float rdg[32], hfv[32], vst[32], mlv[32];
  int tid=threadIdx.x;
  int b = blockIdx.x;
  float* base = wsf + F_SCAN;
  float* pe = base + (size_t)b*SSTR;
  float* outz = out + O_Z;
  for(int p=0;p<3;p++){ int q=tid+(p<<8); if(q<537) ((float4*)SE)[q]=((const float4*)pe)[q]; }
  __syncthreads();
  int flag = (SE[FLGOFF]!=0.f);
  double slog1=0.0;
  if(flag){
    for(int q=tid;q<528;q+=256){
      int r,c; tri_rc(q,r,c);
      float w = wsf[F_J0 + r*32+c] + SE[POFF+q];
      Ms[r*33+c]=w; Ms[c*33+r]=w;
    }
    __syncthreads();
    slog1 = tchol<256>(Ms, Lb, rdg, tid);
    for(int q=tid;q<1056;q+=256){
      int c=q>>5, r=q&31;
      float v;
      if(c<32) v = SE[ROFF + r*32 + c];
      else   { v = wsf[F_H0+r] + SE[PPOFF+r]; vst[r]=v; }
      RHS[c*33+r]=v;
    }
    __syncthreads();
    tsolve<256>(RHS, Lb, rdg, tid, 33, 33);
    for(int q=tid;q<528;q+=256){
      int r,c; tri_rc(q,r,c);
      float acc=0.f;
      #pragma unroll
      for(int m=0;m<32;++m) acc = fmaf(SE[ROFF + m*32 + r], RHS[c*33+m], acc);
      float v = SE[QOFF+q] - acc;
      JfF[r*33+c]=v; JfF[c*33+r]=v;
    }
    if(tid<32){
      float acc=0.f;
      #pragma unroll
      for(int m=0;m<32;++m) acc = fmaf(SE[ROFF + m*32 + tid], RHS[32*33+m], acc);
      hfv[tid] = SE[QQOFF+tid] - acc;
    }
    __syncthreads();
  } else {
    for(int q=tid;q<1024;q+=256){ int r=q>>5,c=q&31; JfF[r*33+c]=wsf[F_J0+q]; }
    if(tid<32) hfv[tid]=wsf[F_H0+tid];
    __syncthreads();
  }
  if(b < NN){
    // P_t = Jf + ATlamA + jitter
    for(int q=tid;q<528;q+=256){
      int r,c; tri_rc(q,r,c);
      float w = JfF[r*33+c] + wsf[F_ATLAMA + r*32+c] + ((r==c)?1e-6f:0.f);
      Ms[r*33+c]=w; Ms[c*33+r]=w;
    }
    __syncthreads();
    tchol<256>(Ms, Lb, rdg, tid);
    for(int q=tid;q<2112;q+=256){
      int c=q>>5, r=q&31;
      float v;
      if(c<32)      v = wsf[F_ATLAM + r*32 + c];
      else if(c<64) v = (r==(c-32))? 1.f : 0.f;
      else if(c==64) v = hfv[r] - wsf[F_ATLAMB+r];
      else           v = outz[(size_t)b*32 + r];
      RHS[c*33+r]=v;
    }
    __syncthreads();
    tsolve<256>(RHS, Lb, rdg, tid, 66, 65);
    // write affine leaf over own slot + stage Pinv|g into out Cross slot
    float* outc = out + O_CROSS + (size_t)b*1024;
    for(int q=tid;q<1024;q+=256){ int c=q>>5, r=q&31; pe[BG + c*32 + r] = RHS[c*33+r]; } // G row-major: G[c][r]? no:
    __syncthreads();
    // fix: G[r][c] = RHS[c*33+r]; rewrite properly
    for(int q=tid;q<1024;q+=256){ int r=q>>5, c=q&31; pe[BG + q] = RHS[c*33+r]; }
    for(int q=tid;q<528;q+=256){
      int r,c; tri_rc(q,r,c);
      float pv = RHS[(32+c)*33 + r];
      pe[BP+q]=pv; outc[q]=pv;
    }
    if(tid<32){
      float g = RHS[64*33+tid];
      float y = RHS[65*33+tid];
      pe[BCM+tid]=g; pe[BCZ+tid]=g+y; outc[528+tid]=g;
    }
    if(tid==0) pe[FLGOFF]=1.f;
  } else {
    // special: b == NN (t = 8191): final-state outputs
    double gam=0.0, dot=0.0, lcl=0.0;
    if(tid==0){
      gam = *(double*)(SE+GAMOFF);
      for(int m=0;m<32;++m) dot += (double)vst[m]*(double)RHS[32*33+m];
      lcl = wsd[WSD_LOGC0] + gam + 0.5*dot - slog1;
    }
    // Cl = chol(Jlast + jitter)
    for(int q=tid;q<528;q+=256){
      int r,c; tri_rc(q,r,c);
      float w = JfF[r*33+c] + ((r==c)?1e-6f:0.f);
      Ms[r*33+c]=w; Ms[c*33+r]=w;
    }
    __syncthreads();
    double slog2 = tchol<256>(Ms, Lb, rdg, tid);
    for(int q=tid;q<1088;q+=256){
      int c=q>>5, r=q&31;
      float v;
      if(c<32) v = (r==c)?1.f:0.f;
      else if(c==32) v = hfv[r];
      else v = outz[(size_t)NN*32 + r];
      RHS[c*33+r]=v;
    }
    __syncthreads();
    tsolve<256>(RHS, Lb, rdg, tid, 34, 33);
    for(int q=tid;q<1024;q+=256){ int r=q>>5,c=q&31; wsf[F_COVT+q] = RHS[c*33+r]; }
    if(tid<32){
      float ml = RHS[32*33+tid];
      float y  = RHS[33*33+tid];
      wsf[F_MLAST+tid]=ml; out[O_EX+(size_t)NN*32+tid]=ml;
      float xt = ml+y;
      wsf[F_XT+tid]=xt; out[O_Z+(size_t)NN*32+tid]=xt;
      mlv[tid]=ml;
    }
    __syncthreads();
    if(tid==0){
      double hm=0.0;
      for(int m=0;m<32;++m) hm += (double)hfv[m]*(double)mlv[m];
      wsd[WSD_LOGZQ] = lcl + 0.5*hm + 0.5*Dd*LOG2PI_ - slog2;
      pe[FLGOFF]=0.f;  // pad for affine scan
    }
    for(int q=tid;q<1024;q+=256){
      int r=q>>5, c=q&31;
      out[O_EXXT+(size_t)NN*1024+q] = RHS[c*33+r] + mlv[r]*mlv[c];
    }
  }
}

// ---------------- affine-scan combine (smoother+sampler), mirrored indexing ----------------
__device__ __forceinline__ int amap(int j){ return (j<NN)? (NN-1-j) : NN; }

__global__ __launch_bounds__(64) void k_ca(float* wsf, int d, int mode){
  __shared__ float SA[2148], SB[2148];
  __shared__ float PXF[1089], Tm[1024];
  int tid = threadIdx.x;
  int i = blockIdx.x;
  int iA = (i<<(d+1)) + (1<<d) - 1;
  int iB = iA + (1<<d);
  float* base = wsf + F_SCAN;
  float* pa = base + (size_t)amap(iA)*SSTR;
  float* pb = base + (size_t)amap(iB)*SSTR;
  for(int p=0;p<9;p++){
    int q=tid+(p<<6);
    if(q<537){ ((float4*)SA)[q]=((const float4*)pa)[q]; ((float4*)SB)[q]=((const float4*)pb)[q]; }
  }
  __syncthreads();
  int fa = (SA[FLGOFF]!=0.f), fb = (SB[FLGOFF]!=0.f);
  if(mode==1){
    for(int p=0;p<9;p++){ int q=tid+(p<<6); if(q<537) ((float4*)pb)[q]=((float4*)SA)[q]; }
    if(tid==0) pa[FLGOFF]=0.f;
    return;
  }
  if(mode==2){
    for(int p=0;p<9;p++){ int q=tid+(p<<6); if(q<537) ((float4*)pa)[q]=((float4*)SB)[q]; }
  }
  float* X = (mode==2)? SB : SA;  int fx = (mode==2)? fb : fa;
  float* Y = (mode==2)? SA : SB;  int fy = (mode==2)? fa : fb;
  if(!fx && !fy){ if(tid==0) pb[FLGOFF]=0.f; return; }
  if(!fx){ for(int p=0;p<9;p++){ int q=tid+(p<<6); if(q<537) ((float4*)pb)[q]=((float4*)Y)[q]; } return; }
  if(!fy){ for(int p=0;p<9;p++){ int q=tid+(p<<6); if(q<537) ((float4*)pb)[q]=((float4*)X)[q]; } return; }
  // result = Y ∘ X   (X applied first):  G=GY*GX, P=GY*PX*GY^T+PY, c=GY*cX+cY
  for(int q=tid;q<528;q+=64){
    int r,c; tri_rc(q,r,c);
    float v = X[BP+q]; PXF[r*33+c]=v; PXF[c*33+r]=v;
  }
  __syncthreads();
  for(int q=tid;q<1024;q+=64){
    int r=q>>5,c=q&31;
    float acc=0.f;
    #pragma unroll
    for(int m=0;m<32;++m) acc=fmaf(Y[BG+r*32+m], PXF[m*33+c], acc);
    Tm[q]=acc;
  }
  __syncthreads();
  for(int q=tid;q<528;q+=64){
    int r,c; tri_rc(q,r,c);
    float acc=0.f;
    #pragma unroll
    for(int m=0;m<32;++m) acc=fmaf(Tm[r*32+m], Y[BG+c*32+m], acc);
    pb[BP+q] = acc + Y[BP+q];
  }
  for(int q=tid;q<1024;q+=64){
    int r=q>>5,c=q&31;
    float acc=0.f;
    #pragma unroll
    for(int m=0;m<32;++m) acc=fmaf(Y[BG+r*32+m], X[BG+m*32+c], acc);
    pb[BG+q]=acc;
  }
  if(tid<32){
    float az=0.f, am=0.f;
    #pragma unroll
    for(int m=0;m<32;++m){
      az=fmaf(Y[BG+tid*32+m], X[BCZ+m], az);
      am=fmaf(Y[BG+tid*32+m], X[BCM+m], am);
    }
    pb[BCZ+tid]=az+Y[BCZ+tid];
    pb[BCM+tid]=am+Y[BCM+tid];
  }
  if(tid==0) pb[FLGOFF]=1.f;
}

// ---------------- apply composites: m_t, Cov_t->ExxT_t, z_t ----------------
__global__ __launch_bounds__(256) void k_smz(float* wsf, float* out){
  __shared__ float CP[1620];
  __shared__ float CVF[1024], Tm[1024];
  __shared__ float mlv[32], xtv[32], mv[32], zv[32];
  int tid=threadIdx.x;
  int t = blockIdx.x;           // 0..NN-1
  int slot = (t>=1)? (t-1) : NN;
  const float* pe = wsf + F_SCAN + (size_t)slot*SSTR;
  for(int p=0;p<2;p++){ int q=tid+(p<<8); if(q<405) ((float4*)CP)[q]=((const float4*)pe)[q]; }
  for(int q=tid;q<1024;q+=256) CVF[q]=wsf[F_COVT+q];
  if(tid<32){ mlv[tid]=wsf[F_MLAST+tid]; xtv[tid]=wsf[F_XT+tid]; }
  __syncthreads();
  if(tid<32){
    float am=0.f, az=0.f;
    #pragma unroll
    for(int m=0;m<32;++m){
      am=fmaf(CP[BG+tid*32+m], mlv[m], am);
      az=fmaf(CP[BG+tid*32+m], xtv[m], az);
    }
    mv[tid]=am+CP[BCM+tid];
    zv[tid]=az+CP[BCZ+tid];
    out[O_EX+(size_t)t*32+tid]=mv[tid];
    out[O_Z +(size_t)t*32+tid]=zv[tid];
  }
  for(int q=tid;q<1024;q+=256){
    int r=q>>5,c=q&31;
    float acc=0.f;
    #pragma unroll
    for(int m=0;m<32;++m) acc=fmaf(CP[BG+r*32+m], CVF[m*32+c], acc);
    Tm[q]=acc;
  }
  __syncthreads();
  for(int q=tid;q<528;q+=256){
    int r,c; tri_rc(q,r,c);
    float acc=0.f;
    #pragma unroll
    for(int m=0;m<32;++m) acc=fmaf(Tm[r*32+m], CP[BG+c*32+m], acc);
    float cov = acc + CP[BP+q];
    float e = cov + mv[r]*mv[c];
    out[O_EXXT+(size_t)t*1024 + r*32+c]=e;
    if(r!=c) out[O_EXXT+(size_t)t*1024 + c*32+r]=e;
  }
}

// ---------------- Cross_t = transpose(G_t ExxT_{t+1} + g_t m_{t+1}^T) ----------------
__global__ __launch_bounds__(256) void k_cross(float* wsf, float* out){
  __shared__ float PV[1089], GF[1024], E1[1024];
  __shared__ float gv[32], m1[32];
  int tid=threadIdx.x;
  int t = blockIdx.x;           // 0..NN-1
  float* outc = out + O_CROSS + (size_t)t*1024;
  for(int q=tid;q<528;q+=256){
    int r,c; tri_rc(q,r,c);
    float v=outc[q]; PV[r*33+c]=v; PV[c*33+r]=v;
  }
  if(tid<32) gv[tid]=outc[528+tid];
  for(int q=tid;q<1024;q+=256) E1[q]=out[O_EXXT+(size_t)(t+1)*1024+q];
  if(tid<32) m1[tid]=out[O_EX+(size_t)(t+1)*32+tid];
  __syncthreads();
  for(int q=tid;q<1024;q+=256){
    int r=q>>5,c=q&31;
    float acc=0.f;
    #pragma unroll
    for(int m=0;m<32;++m) acc=fmaf(PV[r*33+m], wsf[F_ATLAM+m*32+c], acc);
    GF[q]=acc;
  }
  __syncthreads();
  for(int q=tid;q<1024;q+=256){
    int i2=q>>5, j=q&31;
    float acc=0.f;
    #pragma unroll
    for(int m=0;m<32;++m) acc=fmaf(GF[j*32+m], E1[m*32+i2], acc);
    outc[q] = acc + gv[j]*m1[i2];
  }
}

// ---------------- big reduction over t ----------------
__global__ __launch_bounds__(256) void k_terms(const float* rJ, const float* rh,
    const float* plam, float* wsf, double* wsd, float* out){
  __shared__ float slam[1056], slamA[1056], sata[1056];
  __shared__ float slamb[32], satlb[32], cst[16], sw[16];
  __shared__ double sd[256];
  int tid=threadIdx.x; int i8=tid>>3, c4=(tid&7)*4;
  for(int p=0;p<4;p++){int cell=tid+(p<<8);int r=cell>>5,c=cell&31;
    slam[r*33+c]=wsf[F_LAM+cell]; slamA[r*33+c]=wsf[F_LAMA+cell]; sata[r*33+c]=wsf[F_ATLAMA+cell];}
  if(tid<32){slamb[tid]=wsf[F_LAMB+tid]; satlb[tid]=wsf[F_ATLAMB+tid];}
  if(tid<16) cst[tid] = -0.5f*wsf[F_BTLAMBK+tid] + 0.5f*wsf[F_LOGDETK+tid];
  __syncthreads();
  double dr=0.0, dt=0.0, dm=0.0;
  int t0=blockIdx.x*8;
  for(int tt=0;tt<8;++tt){
    int t=t0+tt;
    if(t<NN){ if(tid<16) sw[tid]=out[O_CAT+(size_t)t*16+tid]; }
    __syncthreads();
    size_t cb=(size_t)t*1024+((size_t)i8<<5)+c4;
    float4 exT=*(const float4*)(out+O_EXXT+cb);
    float4 rj =*(const float4*)(rJ+cb);
    dr += -0.5*(double)(rj.x*exT.x+rj.y*exT.y+rj.z*exT.z+rj.w*exT.w);
    if(tid<32) dr += (double)(rh[(size_t)t*32+tid]*out[O_EX+(size_t)t*32+tid]);
    if(t>=1){
      dt += -0.5*(double)(slam[i8*33+c4]*exT.x + slam[i8*33+c4+1]*exT.y
                        + slam[i8*33+c4+2]*exT.z + slam[i8*33+c4+3]*exT.w);
      if(tid<32) dt += (double)(slamb[tid]*out[O_EX+(size_t)t*32+tid]);
    }
    if(t<NN){
      float4 crT =*(const float4*)(out+O_CROSS+cb);
      float4 exT1=*(const float4*)(out+O_EXXT+cb+1024);
      dt += (double)(slamA[i8*33+c4]*crT.x + slamA[i8*33+c4+1]*crT.y
                   + slamA[i8*33+c4+2]*crT.z + slamA[i8*33+c4+3]*crT.w)
          -0.5*(double)(sata[i8*33+c4]*exT.x + sata[i8*33+c4+1]*exT.y
                      + sata[i8*33+c4+2]*exT.z + sata[i8*33+c4+3]*exT.w);
      if(tid<32) dt -= (double)(satlb[tid]*out[O_EX+(size_t)t*32+tid]);
      const float* pe1=(const float*)&exT1; const float* pcr=(const float*)&crT; const float* pe0=(const float*)&exT;
      #pragma unroll
      for(int q=0;q<4;q++){
        int cc=(i8<<5)+c4+q;
        float wl=0.f, wa=0.f, wt2=0.f;
        #pragma unroll
        for(int k2=0;k2<KK;k2++){ float wv=sw[k2];
          wl =fmaf(wv, plam[(size_t)k2*1024+cc], wl);
          wa =fmaf(wv, wsf[F_LAMAK+(size_t)k2*1024+cc], wa);
          wt2=fmaf(wv, wsf[F_ATLAMAK+(size_t)k2*1024+cc], wt2);}
        dm += (double)(-0.5f*wl*pe1[q] + wa*pcr[q] - 0.5f*wt2*pe0[q]);
      }
      if(tid<32){
        float wlb=0.f, wtb=0.f;
        #pragma unroll
        for(int k2=0;k2<KK;k2++){ wlb=fmaf(sw[k2], wsf[F_LAMBK+k2*32+tid], wlb);
                                  wtb=fmaf(sw[k2], wsf[F_ATLAMBK+k2*32+tid], wtb);}
        dm += (double)(wlb*out[O_EX+(size_t)(t+1)*32+tid] - wtb*out[O_EX+(size_t)t*32+tid]);
      }
      if(tid<16) dm += (double)(sw[tid]*cst[tid]);
    }
    __syncthreads();
  }
  double r1=blk_red(dr,sd,tid);
  double r2=blk_red(dt,sd,tid);
  double r3=blk_red(dm,sd,tid);
  if(tid==0){ wsd[WSD_PR+blockIdx.x]=r1; wsd[WSD_PT+blockIdx.x]=r2; wsd[WSD_PM+blockIdx.x]=r3; }
}

__global__ __launch_bounds__(256) void k_final(const float* il, const float* tl,
    const float* ilp, const float* tlp, const float* ptau, float* wsf, double* wsd, float* out){
  __shared__ double sd[256];
  int tid=threadIdx.x;
  double ez=0.0;
  for(int b=0;b<128;++b) ez += (double)wsf[F_EZ + b*256 + tid];
  double v = ez * (double)(tl[tid]-tlp[tid]);
  if(tid<16) v += (double)out[O_CAT+tid] * (double)(il[tid]-ilp[tid]);
  double hmmkl = blk_red(v, sd, tid) - (double)wsf[F_SC+0];
  double a=0,b2=0,c=0;
  for(int q=0;q<4;q++){int b3=tid+q*256; a+=wsd[WSD_PR+b3]; b2+=wsd[WSD_PT+b3]; c+=wsd[WSD_PM+b3];}
  double recog=blk_red(a,sd,tid), trns=blk_red(b2,sd,tid), mixt=blk_red(c,sd,tid);
  double ia=0, ib=0, va=0, vb=0;
  for(int p=0;p<4;p++){int cell=tid+(p<<8);
    float e0=out[O_EXXT+cell];
    ia += (double)(wsf[F_TAU+cell]*e0);
    ib += (double)(ptau[cell]*e0);
  }
  if(tid<32){ float ex0=out[O_EX+tid];
    va=(double)(ex0*wsf[F_TAUMU+tid]); vb=(double)(ex0*wsf[F_TPM+tid]); }
  double s_ia=blk_red(ia,sd,tid), s_ib=blk_red(ib,sd,tid);
  double s_va=blk_red(va,sd,tid), s_vb=blk_red(vb,sd,tid);
  if(tid==0){
    double init_term = -0.5*s_ia + s_va + wsd[WSD_LOGC0];
    double mix_init  = -0.5*s_ib + s_vb + wsd[WSD_MIXC];
    double trans_term = trns + (double)NN*(-0.5*wsd[WSD_BTLAMB] + 0.5*wsd[WSD_LDLAM] - 0.5*Dd*LOG2PI_);
    double mix_trans  = mixt - 0.5*(double)NN*(double)Dd*LOG2PI_;
    double lds_kl = (init_term+trans_term) + recog - wsd[WSD_LOGZQ] - (mix_init+mix_trans);
    out[O_KL] = (float)(lds_kl + hmmkl);
  }
}

// ---------------- launch ----------------
extern "C" void kernel_launch(void* const* d_in, const int* in_sizes, int n_in,
                              void* d_out, int out_size, void* d_ws, size_t ws_size,
                              hipStream_t stream){
  const float* rJ  =(const float*)d_in[0];
  const float* rh  =(const float*)d_in[1];
  const float* loc =(const float*)d_in[2];
  const float* Tp  =(const float*)d_in[3];
  const float* Lp  =(const float*)d_in[4];
  const float* X   =(const float*)d_in[5];
  const float* il  =(const float*)d_in[6];
  const float* tl  =(const float*)d_in[7];
  const float* plam=(const float*)d_in[8];
  const float* pX  =(const float*)d_in[9];
  const float* ptau=(const float*)d_in[10];
  const float* pmu =(const float*)d_in[11];
  const float* ilp =(const float*)d_in[12];
  const float* tlp =(const float*)d_in[13];
  const int*   seed=(const int*)d_in[14];
  float* out=(float*)d_out;
  double* wsd=(double*)d_ws;
  float* wsf=(float*)((char*)d_ws + 32768);

  k_setup<<<1,256,0,stream>>>(rJ,rh,loc,Tp,Lp,X,plam,pX,ptau,pmu,wsf,wsd);
  k_eps<<<1024,256,0,stream>>>(seed, out + O_Z);
  k_hmmpow<<<1,256,0,stream>>>(tl, wsf);
  k_hmmab<<<32,256,0,stream>>>(il, wsf);
  k_cat<<<128,256,0,stream>>>(tl, wsf, out);
  k_leaf<<<8192,256,0,stream>>>(rJ, rh, wsf, wsd);
  for(int d=0; d<13; ++d) k_cf<<<(8192>>(d+1)),64,0,stream>>>(wsf, d, 0);
  k_cf<<<1,64,0,stream>>>(wsf, 12, 1);
  for(int d=11; d>=0; --d) k_cf<<<(8192>>(d+1)),64,0,stream>>>(wsf, d, 2);
  k_point<<<8192,256,0,stream>>>(wsf, wsd, out);
  for(int d=0; d<13; ++d) k_ca<<<(8192>>(d+1)),64,0,stream>>>(wsf, d, 0);
  k_ca<<<1,64,0,stream>>>(wsf, 12, 1);
  for(int d=11; d>=0; --d) k_ca<<<(8192>>(d+1)),64,0,stream>>>(wsf, d, 2);
  k_smz<<<NN,256,0,stream>>>(wsf, out);
  k_cross<<<NN,256,0,stream>>>(wsf, out);
  k_terms<<<1024,256,0,stream>>>(rJ, rh, plam, wsf, wsd, out);
  k_final<<<1,256,0,stream>>>(il, tl, ilp, tlp, ptau, wsf, wsd, out);
}

// Round 4
// 2581.842 us; speedup vs baseline: 137.5526x; 4.2607x over previous
//
#include <hip/hip_runtime.h>
#include <math.h>
#include <stdint.h>

#define Dd 32
#define TT 8192
#define NN 8191
#define KK 16
#define LOG2PI_ 1.8378770664093453

// ---------------- ws doubles ----------------
#define WSD_LOGC0  0
#define WSD_LOGZQ  1
#define WSD_MIXC   3
#define WSD_LDLAM  4
#define WSD_BTLAMB 5
#define WSD_PR     8
#define WSD_PT     1032
#define WSD_PM     2056
// ---------------- ws floats (base = byte 32768) ----------------
#define F_TAU      0
#define F_TAUMU    1024
#define F_LAM      1056
#define F_A        2080
#define F_B        3104
#define F_ATLAM    3136
#define F_ATLAMA   4160
#define F_LAMA     5184
#define F_LAMB     6208
#define F_ATLAMB   6240
#define F_SC       6272
#define F_LAMAK    6304
#define F_ATLAMAK  22688
#define F_LAMBK    39072
#define F_ATLAMBK  39584
#define F_BTLAMBK  40096
#define F_LOGDETK  40112
#define F_TPM      40128
#define F_J0       40160
#define F_H0       41184
#define F_MLAST    41216
#define F_COVT     41248
#define F_XT       42272
#define F_TPOW     42304
#define F_ALPHA    45632
#define F_BETA     176704
#define F_EZ       307776
#define F_SCAN     340544

// scan slot layout (stride 2148 floats)
#define SSTR   2148
#define POFF   0
#define QOFF   528
#define ROFF   1056
#define PPOFF  2080
#define QQOFF  2112
#define GAMOFF 2144
#define FLGOFF 2146
// affine (B) slot layout (same slots, reused after k_point)
#define BG     0
#define BCZ    1024
#define BCM    1056
#define BP     1088

// out offsets (floats)
#define O_Z     ((size_t)0)
#define O_EX    ((size_t)262144)
#define O_EXXT  ((size_t)524288)
#define O_CROSS ((size_t)8912896)
#define O_CAT   ((size_t)17300480)
#define O_KL    ((size_t)17431536)

// ---------------- threefry ----------------
__device__ __forceinline__ uint32_t rotl32(uint32_t v, int d){ return (v<<d)|(v>>(32-d)); }
__device__ __forceinline__ void threefry2x32(uint32_t k0, uint32_t k1, uint32_t x0, uint32_t x1,
                                             uint32_t& o0, uint32_t& o1){
  uint32_t ks2 = k0 ^ k1 ^ 0x1BD11BDAu;
  x0 += k0; x1 += k1;
  x0+=x1; x1=rotl32(x1,13); x1^=x0;  x0+=x1; x1=rotl32(x1,15); x1^=x0;
  x0+=x1; x1=rotl32(x1,26); x1^=x0;  x0+=x1; x1=rotl32(x1, 6); x1^=x0;
  x0+=k1; x1+=ks2+1u;
  x0+=x1; x1=rotl32(x1,17); x1^=x0;  x0+=x1; x1=rotl32(x1,29); x1^=x0;
  x0+=x1; x1=rotl32(x1,16); x1^=x0;  x0+=x1; x1=rotl32(x1,24); x1^=x0;
  x0+=ks2; x1+=k0+2u;
  x0+=x1; x1=rotl32(x1,13); x1^=x0;  x0+=x1; x1=rotl32(x1,15); x1^=x0;
  x0+=x1; x1=rotl32(x1,26); x1^=x0;  x0+=x1; x1=rotl32(x1, 6); x1^=x0;
  x0+=k0; x1+=k1+3u;
  x0+=x1; x1=rotl32(x1,17); x1^=x0;  x0+=x1; x1=rotl32(x1,29); x1^=x0;
  x0+=x1; x1=rotl32(x1,16); x1^=x0;  x0+=x1; x1=rotl32(x1,24); x1^=x0;
  x0+=k1; x1+=ks2+4u;
  x0+=x1; x1=rotl32(x1,13); x1^=x0;  x0+=x1; x1=rotl32(x1,15); x1^=x0;
  x0+=x1; x1=rotl32(x1,26); x1^=x0;  x0+=x1; x1=rotl32(x1, 6); x1^=x0;
  x0+=ks2; x1+=k0+5u;
  o0=x0; o1=x1;
}
__device__ __forceinline__ float tf_normal(uint32_t bits){
  float fl = __uint_as_float((bits>>9) | 0x3F800000u) - 1.0f;
  const float lo = -0.99999994f;
  float u = fmaxf(lo, fl*2.0f + lo);
  float w = -log1pf(-u*u);
  float p;
  if (w < 5.0f){
    w -= 2.5f;
    p = 2.81022636e-08f;
    p = fmaf(p,w,3.43273939e-07f); p = fmaf(p,w,-3.5233877e-06f);
    p = fmaf(p,w,-4.39150654e-06f); p = fmaf(p,w,0.00021858087f);
    p = fmaf(p,w,-0.00125372503f); p = fmaf(p,w,-0.00417768164f);
    p = fmaf(p,w,0.246640727f); p = fmaf(p,w,1.50140941f);
  } else {
    w = sqrtf(w) - 3.0f;
    p = -0.000200214257f;
    p = fmaf(p,w,0.000100950558f); p = fmaf(p,w,0.00134934322f);
    p = fmaf(p,w,-0.00367342844f); p = fmaf(p,w,0.00573950773f);
    p = fmaf(p,w,-0.0076224613f); p = fmaf(p,w,0.00943887047f);
    p = fmaf(p,w,1.00167406f); p = fmaf(p,w,2.83297682f);
  }
  return 1.4142135381698608f * (p*u);
}

// ---------------- helpers ----------------
__device__ __forceinline__ void tri_rc(int i, int& r, int& c){
  int rr = (int)((sqrtf(8.f*(float)i+1.f)-1.f)*0.5f);
  while((rr+1)*(rr+2)/2 <= i) ++rr;
  while(rr*(rr+1)/2 > i) --rr;
  r = rr; c = i - rr*(rr+1)/2;
}

// In-place cholesky of full-symmetric W (stride 33). After: subdiag cols of W hold
// TRUE (scaled) L, diag holds dd, rdg[j]=1/L_jj. Returns sum log L_jj.
template<int NT>
__device__ double chol_sym(float* W, float* rdg, int tid){
  double slog=0.0;
  for(int j=0;j<32;++j){
    float dd = W[j*33+j];
    float rd = 1.0f/sqrtf(dd);
    float invd = rd*rd;
    slog += (double)(0.5f*__logf(dd));
    if(tid==0) rdg[j]=rd;
    #pragma unroll
    for(int p=0;p<1024/NT;++p){
      int q=tid+p*NT; int r=q>>5, c=q&31;
      if(r>j){
        if(c>j)       W[r*33+c] -= W[j*33+r]*(W[j*33+c]*invd);   // read row j (untouched this step)
        else if(c==j) W[r*33+j] *= rd;                           // scale column j in-pass
      }
    }
    __syncthreads();
  }
  return slog;
}

// X = L^-1 (lower, stride 33). W holds scaled L in subdiag, rdg diag inverses.
template<int NT>
__device__ void linv_sym(const float* W, const float* rdg, float* X, int tid){
  #pragma unroll
  for(int p=0;p<1024/NT;++p){ int q=tid+p*NT; int r=q>>5,c=q&31; X[r*33+c]=(r==c)?1.f:0.f; }
  __syncthreads();
  for(int ii=0;ii<32;++ii){
    float rdi=rdg[ii];
    #pragma unroll
    for(int p=0;p<1024/NT;++p){
      int q=tid+p*NT; int r=q>>5,c=q&31;
      if(r>ii && c<=ii) X[r*33+c] -= W[r*33+ii]*(X[ii*33+c]*rdi);
    }
    __syncthreads();
  }
  #pragma unroll
  for(int p=0;p<1024/NT;++p){ int q=tid+p*NT; int r=q>>5,c=q&31; if(c<=r) X[r*33+c]*=rdg[r]; }
  __syncthreads();
}

__device__ __forceinline__ double blk_red(double v, double* sd, int tid){
  sd[tid]=v; __syncthreads();
  for(int s=128;s>0;s>>=1){ if(tid<s) sd[tid]+=sd[tid+s]; __syncthreads(); }
  double r=sd[0]; __syncthreads(); return r;
}
__device__ double blk_logdet(float* Ms, int tid){
  double sl = 0.0;
  for (int j=0;j<Dd;++j){
    float dd = Ms[j*33+j];
    sl += log((double)dd);
    float invd = 1.0f/dd;
    #pragma unroll
    for(int p=0;p<4;p++){
      int cell = tid + (p<<8); int r=cell>>5, c=cell&31;
      if(r>j && c>j && c<=r) Ms[r*33+c] -= Ms[r*33+j]*(Ms[c*33+j]*invd);
    }
    __syncthreads();
  }
  return sl;
}

// ---------------- setup ----------------
__global__ __launch_bounds__(256) void k_setup(const float* rJ, const float* rh, const float* loc,
    const float* Tp, const float* Lp, const float* X, const float* plam, const float* pX,
    const float* ptau, const float* pmu, float* wsf, double* wsd){
  __shared__ float s1[1056], s2[1056], s3[1056];
  __shared__ float sv[32], sv2[32];
  int tid=threadIdx.x;
  for(int p=0;p<4;p++){int cell=tid+(p<<8);int r=cell>>5,c=cell&31; s1[r*33+c]=Tp[cell];}
  if(tid<32) sv[tid]=loc[tid];
  __syncthreads();
  for(int p=0;p<4;p++){int cell=tid+(p<<8);int r=cell>>5,c=cell&31;
    float a=0.f;
    #pragma unroll
    for(int m=0;m<Dd;++m) a=fmaf(s1[r*33+m], s1[c*33+m], a);
    if(r==c) a+=1e-8f;
    s2[r*33+c]=a; wsf[F_TAU+cell]=a; wsf[F_J0+cell]=a+rJ[cell];
  }
  __syncthreads();
  if(tid<32){ float tm=0.f;
    #pragma unroll
    for(int m=0;m<Dd;++m) tm=fmaf(s2[tid*33+m], sv[m], tm);
    sv2[tid]=tm; wsf[F_TAUMU+tid]=tm; wsf[F_H0+tid]=tm+rh[tid];
  }
  __syncthreads();
  {
    double ldt = blk_logdet(s2, tid);
    if(tid==0){ double dd=0; for(int m=0;m<Dd;++m) dd += (double)sv[m]*(double)sv2[m];
      wsd[WSD_LOGC0] = -0.5*dd + 0.5*ldt - 0.5*Dd*LOG2PI_; }
  }
  __syncthreads();
  for(int p=0;p<4;p++){int cell=tid+(p<<8);int r=cell>>5,c=cell&31; s1[r*33+c]=Lp[cell];}
  __syncthreads();
  for(int p=0;p<4;p++){int cell=tid+(p<<8);int r=cell>>5,c=cell&31;
    float a=0.f;
    #pragma unroll
    for(int m=0;m<Dd;++m) a=fmaf(s1[r*33+m], s1[c*33+m], a);
    if(r==c) a+=1e-8f;
    s2[r*33+c]=a; wsf[F_LAM+cell]=a;
  }
  __syncthreads();
  for(int p=0;p<4;p++){int cell=tid+(p<<8);int r=cell>>5,c=cell&31;
    float a=X[r*33+c]; s3[r*33+c]=a; wsf[F_A+cell]=a; }
  if(tid<32){ sv[tid]=X[tid*33+32]; wsf[F_B+tid]=sv[tid]; }
  __syncthreads();
  for(int p=0;p<4;p++){int cell=tid+(p<<8);int r=cell>>5,c=cell&31;
    float a=0.f,b2=0.f;
    #pragma unroll
    for(int m=0;m<Dd;++m){ a=fmaf(s2[r*33+m], s3[m*33+c], a); b2=fmaf(s3[m*33+r], s2[m*33+c], b2); }
    s1[r*33+c]=a; wsf[F_LAMA+cell]=a; wsf[F_ATLAM+cell]=b2;
  }
  if(tid<32){ float lb=0.f;
    #pragma unroll
    for(int m=0;m<Dd;++m) lb=fmaf(s2[tid*33+m], sv[m], lb);
    sv2[tid]=lb; wsf[F_LAMB+tid]=lb;
  }
  __syncthreads();
  for(int p=0;p<4;p++){int cell=tid+(p<<8);int r=cell>>5,c=cell&31;
    float a=0.f;
    #pragma unroll
    for(int m=0;m<Dd;++m) a=fmaf(s3[m*33+r], s1[m*33+c], a);
    wsf[F_ATLAMA+cell]=a;
  }
  if(tid<32){ float ab=0.f;
    #pragma unroll
    for(int m=0;m<Dd;++m) ab=fmaf(s3[m*33+tid], sv2[m], ab);
    wsf[F_ATLAMB+tid]=ab;
  }
  if(tid==0){ double bb=0; for(int m=0;m<Dd;++m) bb += (double)sv[m]*(double)sv2[m];
    wsd[WSD_BTLAMB]=bb; }
  __syncthreads();
  {
    double ldl = blk_logdet(s2, tid);
    if(tid==0) wsd[WSD_LDLAM]=ldl;
  }
  for(int p=0;p<4;p++){int cell=tid+(p<<8);int r=cell>>5,c=cell&31; s1[r*33+c]=ptau[cell];}
  if(tid<32) sv[tid]=pmu[tid];
  __syncthreads();
  if(tid<32){ float tm=0.f;
    #pragma unroll
    for(int m=0;m<Dd;++m) tm=fmaf(s1[tid*33+m], sv[m], tm);
    sv2[tid]=tm; wsf[F_TPM+tid]=tm;
  }
  __syncthreads();
  {
    double ldp = blk_logdet(s1, tid);
    if(tid==0){ double dd=0; for(int m=0;m<Dd;++m) dd += (double)sv[m]*(double)sv2[m];
      wsd[WSD_MIXC] = -0.5*dd + 0.5*ldp - 0.5*Dd*LOG2PI_; }
  }
  __syncthreads();
  for(int k2=0;k2<KK;++k2){
    for(int p=0;p<4;p++){int cell=tid+(p<<8);int r=cell>>5,c=cell&31;
      s2[r*33+c]=plam[k2*1024+cell]; s3[r*33+c]=pX[k2*1056 + r*33 + c];}
    if(tid<32) sv[tid]=pX[k2*1056 + tid*33 + 32];
    __syncthreads();
    for(int p=0;p<4;p++){int cell=tid+(p<<8);int r=cell>>5,c=cell&31;
      float a=0.f;
      #pragma unroll
      for(int m=0;m<Dd;++m) a=fmaf(s2[r*33+m], s3[m*33+c], a);
      s1[r*33+c]=a; wsf[F_LAMAK + (size_t)k2*1024 + cell]=a;
    }
    if(tid<32){ float lb=0.f;
      #pragma unroll
      for(int m=0;m<Dd;++m) lb=fmaf(s2[tid*33+m], sv[m], lb);
      sv2[tid]=lb; wsf[F_LAMBK + k2*32 + tid]=lb;
    }
    __syncthreads();
    for(int p=0;p<4;p++){int cell=tid+(p<<8);int r=cell>>5,c=cell&31;
      float a=0.f;
      #pragma unroll
      for(int m=0;m<Dd;++m) a=fmaf(s3[m*33+r], s1[m*33+c], a);
      wsf[F_ATLAMAK + (size_t)k2*1024 + cell]=a;
    }
    if(tid<32){ float ab=0.f;
      #pragma unroll
      for(int m=0;m<Dd;++m) ab=fmaf(s3[m*33+tid], sv2[m], ab);
      wsf[F_ATLAMBK + k2*32 + tid]=ab;
    }
    if(tid==0){ float bb=0.f; for(int m=0;m<Dd;++m) bb=fmaf(sv[m],sv2[m],bb);
      wsf[F_BTLAMBK + k2]=bb; }
    __syncthreads();
    double dk = blk_logdet(s2, tid);
    if(tid==0) wsf[F_LOGDETK + k2]=(float)dk;
  }
}

// ---------------- eps -> out O_Z (staged; overwritten by sampler later) ----------------
__global__ __launch_bounds__(256) void k_eps(const int* seedp, float* outz){
  uint32_t seed = (uint32_t)seedp[0];
  uint32_t K0,K1;
  threefry2x32(0u, seed, 0u, 1u, K0, K1);
  uint32_t i = blockIdx.x*256u + threadIdx.x;
  uint32_t o0,o1;
  threefry2x32(K0, K1, 0u, i, o0, o1);
  outz[i] = tf_normal(o0 ^ o1);
}

// ---------------- HMM ----------------
__global__ __launch_bounds__(256) void k_hmmpow(const float* tl, float* wsf){
  __shared__ float A0[256], A1[256];
  int tid=threadIdx.x;
  A0[tid]=tl[tid];
  wsf[F_TPOW+tid]=A0[tid];
  __syncthreads();
  float* cur=A0; float* nxt=A1;
  for(int k=1;k<13;++k){
    int i=tid>>4, j=tid&15;
    float mx=-3.0e38f;
    #pragma unroll
    for(int m=0;m<16;++m) mx=fmaxf(mx, cur[i*16+m]+cur[m*16+j]);
    float s=0.f;
    #pragma unroll
    for(int m=0;m<16;++m) s+=__expf(cur[i*16+m]+cur[m*16+j]-mx);
    float v=mx+__logf(s);
    nxt[tid]=v; wsf[F_TPOW+k*256+tid]=v;
    __syncthreads();
    float* t2=cur; cur=nxt; nxt=t2;
  }
}

__global__ __launch_bounds__(256) void k_hmmab(const float* il, float* wsf){
  __shared__ float S[3328];
  int tid=threadIdx.x;
  for(int p=0;p<13;++p) S[p*256+tid]=wsf[F_TPOW+p*256+tid];
  __syncthreads();
  int n = blockIdx.x*256 + tid;
  if(n>NN-1) return;
  float v[16], w[16];
  #pragma unroll
  for(int j=0;j<16;++j) v[j]=il[j];
  for(int k=0;k<13;++k){
    if((n>>k)&1){
      #pragma unroll
      for(int j=0;j<16;++j){
        float mx=-3.0e38f;
        #pragma unroll
        for(int i2=0;i2<16;++i2) mx=fmaxf(mx, v[i2]+S[k*256+i2*16+j]);
        float s=0.f;
        #pragma unroll
        for(int i2=0;i2<16;++i2) s+=__expf(v[i2]+S[k*256+i2*16+j]-mx);
        w[j]=mx+__logf(s);
      }
      #pragma unroll
      for(int j=0;j<16;++j) v[j]=w[j];
    }
  }
  #pragma unroll
  for(int j=0;j<16;++j) wsf[F_ALPHA+(size_t)n*16+j]=v[j];
  if(n==NN-1){
    float mx=-3.0e38f;
    #pragma unroll
    for(int j=0;j<16;++j) mx=fmaxf(mx,v[j]);
    float s=0.f;
    #pragma unroll
    for(int j=0;j<16;++j) s+=__expf(v[j]-mx);
    wsf[F_SC+0]=mx+__logf(s);
  }
  int m = NN-1-n;
  float b[16];
  #pragma unroll
  for(int i2=0;i2<16;++i2) b[i2]=0.f;
  for(int k=0;k<13;++k){
    if((m>>k)&1){
      #pragma unroll
      for(int i2=0;i2<16;++i2){
        float mx=-3.0e38f;
        #pragma unroll
        for(int j=0;j<16;++j) mx=fmaxf(mx, S[k*256+i2*16+j]+b[j]);
        float s=0.f;
        #pragma unroll
        for(int j=0;j<16;++j) s+=__expf(S[k*256+i2*16+j]+b[j]-mx);
        w[i2]=mx+__logf(s);
      }
      #pragma unroll
      for(int i2=0;i2<16;++i2) b[i2]=w[i2];
    }
  }
  #pragma unroll
  for(int i2=0;i2<16;++i2) wsf[F_BETA+(size_t)n*16+i2]=b[i2];
}

__global__ __launch_bounds__(256) void k_cat(const float* tl, float* wsf, float* out){
  __shared__ float Ts[256]; __shared__ float ar[16]; __shared__ float br[16];
  int tid=threadIdx.x;
  Ts[tid]=tl[tid];
  float logZ = wsf[F_SC+0];
  int i=tid>>4, j=tid&15;
  float acc=0.f;
  int n0=blockIdx.x*64;
  __syncthreads();
  for(int nn=0;nn<64;++nn){
    int n=n0+nn;
    if(n<NN-1){
      if(tid<16) ar[tid]=wsf[F_ALPHA+(size_t)n*16+tid];
      else if(tid<32) br[tid-16]=wsf[F_BETA+(size_t)(n+1)*16+(tid-16)];
      __syncthreads();
      acc += __expf(ar[i]+Ts[i*16+j]+br[j]-logZ);
      __syncthreads();
    }
    if(n<NN && tid<16)
      out[O_CAT+(size_t)n*16+tid]=__expf(wsf[F_ALPHA+(size_t)n*16+tid]+wsf[F_BETA+(size_t)n*16+tid]-logZ);
  }
  wsf[F_EZ + blockIdx.x*256 + tid]=acc;
}

// ---------------- leaves: slot 0 = unary(J0,h0,logc0), slots t=1..NN = pair_t ----------------
__global__ __launch_bounds__(256) void k_leaf(const float* rJ, const float* rh, float* wsf, double* wsd){
  int b = blockIdx.x; int tid=threadIdx.x;
  float* pe = wsf + F_SCAN + (size_t)b*SSTR;
  if(b==0){
    for(int q=tid;q<528;q+=256){
      int r,c; tri_rc(q,r,c);
      pe[POFF+q]=0.f;
      pe[QOFF+q]=wsf[F_J0 + r*32+c];
    }
    for(int q=tid;q<1024;q+=256) pe[ROFF+q]=0.f;
    if(tid<32){ pe[PPOFF+tid]=0.f; pe[QQOFF+tid]=wsf[F_H0+tid]; }
    if(tid==0){ *(double*)(pe+GAMOFF)=wsd[WSD_LOGC0]; pe[FLGOFF]=1.f; }
  } else {
    int t = b;
    for(int q=tid;q<528;q+=256){
      int r,c; tri_rc(q,r,c);
      pe[POFF+q] = wsf[F_ATLAMA + r*32+c] + ((r==c)?1e-6f:0.f);
      pe[QOFF+q] = wsf[F_LAM + r*32+c] + rJ[(size_t)t*1024 + r*32+c];
    }
    for(int q=tid;q<1024;q+=256) pe[ROFF+q] = -wsf[F_ATLAM+q];
    if(tid<32){
      pe[PPOFF+tid] = -wsf[F_ATLAMB+tid];
      pe[QQOFF+tid] = wsf[F_LAMB+tid] + rh[(size_t)t*32+tid];
    }
    if(tid==0){
      *(double*)(pe+GAMOFF) = -0.5*wsd[WSD_BTLAMB] + 0.5*wsd[WSD_LDLAM];
      pe[FLGOFF]=1.f;
    }
  }
}

// ---------------- filter-scan combine ----------------
__global__ __launch_bounds__(256) void k_cf(float* wsf, float* out, int d, int mode){
  __shared__ float SA[2148], SB[2148];
  __shared__ float W[1089], Li[1089], T1[1056], T2[1056];
  __shared__ float rdg[32], Ls[32];
  int tid = threadIdx.x;
  int i = blockIdx.x;
  int iA = (i<<(d+1)) + (1<<d) - 1;
  int iB = iA + (1<<d);
  float* base = wsf + F_SCAN;
  float* pa = base + (size_t)iA*SSTR;
  float* pb = base + (size_t)iB*SSTR;
  for(int q=tid;q<537;q+=256){ ((float4*)SA)[q]=((const float4*)pa)[q]; ((float4*)SB)[q]=((const float4*)pb)[q]; }
  __syncthreads();
  int fa=(SA[FLGOFF]!=0.f), fb=(SB[FLGOFF]!=0.f);
  if(mode==1){
    float* st = out + O_EXXT;    // stage up-sweep total (Jlast,hlast,lc); k_smz overwrites later
    for(int q=tid;q<537;q+=256){ ((float4*)st)[q]=((float4*)SB)[q]; ((float4*)pb)[q]=((float4*)SA)[q]; }
    if(tid==0) pa[FLGOFF]=0.f;
    return;
  }
  if(mode==2){ for(int q=tid;q<537;q+=256) ((float4*)pa)[q]=((float4*)SB)[q]; }
  float* X = (mode==2)? SB : SA;  int fx=(mode==2)?fb:fa;
  float* Y = (mode==2)? SA : SB;  int fy=(mode==2)?fa:fb;
  if(!fx && !fy){ if(tid==0) pb[FLGOFF]=0.f; return; }
  if(!fx){ for(int q=tid;q<537;q+=256) ((float4*)pb)[q]=((float4*)Y)[q]; return; }
  if(!fy){ for(int q=tid;q<537;q+=256) ((float4*)pb)[q]=((float4*)X)[q]; return; }
  // W = Q_x + P_y
  for(int q=tid;q<528;q+=256){
    int r,c; tri_rc(q,r,c);
    float w = X[QOFF+q] + Y[POFF+q];
    W[r*33+c]=w; W[c*33+r]=w;
  }
  __syncthreads();
  double slog = chol_sym<256>(W, rdg, tid);
  linv_sym<256>(W, rdg, Li, tid);
  // Ls = Li * s,  s = q_x + p_y
  if(tid<32){
    float acc=0.f;
    for(int m=0;m<=tid;++m) acc = fmaf(Li[tid*33+m], X[QQOFF+m]+Y[PPOFF+m], acc);
    Ls[tid]=acc;
  }
  // T1 = Li * R_x^T ; T2 = Li * R_y
  for(int q=tid;q<1024;q+=256){
    int i2=q&31, j=q>>5;
    float a1=0.f,a2=0.f;
    #pragma unroll
    for(int m=0;m<32;++m){
      float lv = Li[i2*33+m];
      a1 = fmaf(lv, X[ROFF + j*32 + m], a1);
      a2 = fmaf(lv, Y[ROFF + m*32 + j], a2);
    }
    T1[i2*33+j]=a1; T2[i2*33+j]=a2;
  }
  __syncthreads();
  for(int q=tid;q<528;q+=256){
    int r,c; tri_rc(q,r,c);
    float aP=0.f,aQ=0.f;
    #pragma unroll
    for(int m=0;m<32;++m){
      aP = fmaf(T1[m*33+r], T1[m*33+c], aP);
      aQ = fmaf(T2[m*33+r], T2[m*33+c], aQ);
    }
    pb[POFF+q] = X[POFF+q] - aP;
    pb[QOFF+q] = Y[QOFF+q] - aQ;
  }
  for(int q=tid;q<1024;q+=256){
    int r=q>>5, c=q&31;
    float a=0.f;
    #pragma unroll
    for(int m=0;m<32;++m) a = fmaf(T1[m*33+r], T2[m*33+c], a);
    pb[ROFF+q] = -a;
  }
  if(tid<32){
    float ap=0.f,aq=0.f;
    #pragma unroll
    for(int m=0;m<32;++m){ ap=fmaf(T1[m*33+tid],Ls[m],ap); aq=fmaf(T2[m*33+tid],Ls[m],aq); }
    pb[PPOFF+tid] = X[PPOFF+tid] - ap;
    pb[QQOFF+tid] = Y[QQOFF+tid] - aq;
  }
  if(tid==0){
    double g = *(double*)(X+GAMOFF) + *(double*)(Y+GAMOFF);
    double dot=0.0;
    for(int m=0;m<32;++m) dot += (double)Ls[m]*(double)Ls[m];
    *(double*)(pb+GAMOFF) = g + 0.5*dot - slog;
    pb[FLGOFF]=1.f;
  }
}

// ---------------- per-t pointwise ----------------
// block 0: final state (reads staged total). blocks b=1..NN: time t=b-1 -> affine leaf into slot b.
__global__ __launch_bounds__(256) void k_point(float* wsf, double* wsd, float* out){
  __shared__ float SE[2148];
  __shared__ float W[1089], Li[1089], T1[1056], SAT[1024];
  __shared__ float rdg[32], uv[32], Lu[32], ev[32], gv[32], yv[32];
  int tid=threadIdx.x; int b=blockIdx.x;
  float* base = wsf + F_SCAN;
  float* outz = out + O_Z;
  if(b>0){
    int t = b-1;
    float* pe = base + (size_t)b*SSTR;
    for(int q=tid;q<537;q+=256) ((float4*)SE)[q]=((const float4*)pe)[q];
    if(tid<32) ev[tid]=outz[(size_t)t*32+tid];
    for(int q=tid;q<1024;q+=256) SAT[q]=wsf[F_ATLAM+q];
    __syncthreads();
    // M = Jf_{t-1} + ATlamA + jitter ; prefix is unary: Q holds Jf
    for(int q=tid;q<528;q+=256){
      int r,c; tri_rc(q,r,c);
      float w = SE[QOFF+q] + wsf[F_ATLAMA + r*32+c] + ((r==c)?1e-6f:0.f);
      W[r*33+c]=w; W[c*33+r]=w;
    }
    if(tid<32) uv[tid]=SE[QQOFF+tid]-wsf[F_ATLAMB+tid];
    __syncthreads();
    chol_sym<256>(W, rdg, tid);
    linv_sym<256>(W, rdg, Li, tid);
    if(tid<32){
      float acc=0.f;
      for(int m=0;m<=tid;++m) acc=fmaf(Li[tid*33+m],uv[m],acc);
      Lu[tid]=acc;
    }
    for(int q=tid;q<1024;q+=256){
      int i2=q&31, j=q>>5;
      float a=0.f;
      #pragma unroll
      for(int m=0;m<32;++m) a=fmaf(Li[i2*33+m], SAT[m*32+j], a);
      T1[i2*33+j]=a;
    }
    __syncthreads();
    if(tid<32){
      float ag=0.f, ay=0.f;
      for(int m2=tid;m2<32;++m2){ float lv=Li[m2*33+tid]; ag=fmaf(lv,Lu[m2],ag); ay=fmaf(lv,ev[m2],ay); }
      gv[tid]=ag; yv[tid]=ay;
    }
    __syncthreads();
    // G = Li^T T1 = M^-1 ATlam
    for(int q=tid;q<1024;q+=256){
      int r=q>>5,c=q&31;
      float a=0.f;
      #pragma unroll
      for(int m=0;m<32;++m) a=fmaf(Li[m*33+r],T1[m*33+c],a);
      pe[BG+q]=a;
    }
    float* outc = out + O_CROSS + (size_t)t*1024;
    for(int q=tid;q<528;q+=256){
      int r,c; tri_rc(q,r,c);
      float a=0.f;
      #pragma unroll
      for(int m=0;m<32;++m) a=fmaf(Li[m*33+r],Li[m*33+c],a);
      pe[BP+q]=a; outc[q]=a;
    }
    if(tid<32){
      pe[BCM+tid]=gv[tid]; pe[BCZ+tid]=gv[tid]+yv[tid]; outc[528+tid]=gv[tid];
    }
    if(tid==0) pe[FLGOFF]=1.f;
  } else {
    const float* st = out + O_EXXT;
    for(int q=tid;q<537;q+=256) ((float4*)SE)[q]=((const float4*)st)[q];
    if(tid<32) ev[tid]=outz[(size_t)NN*32+tid];
    __syncthreads();
    for(int q=tid;q<528;q+=256){
      int r,c; tri_rc(q,r,c);
      float w = SE[QOFF+q] + ((r==c)?1e-6f:0.f);
      W[r*33+c]=w; W[c*33+r]=w;
    }
    if(tid<32) uv[tid]=SE[QQOFF+tid];
    __syncthreads();
    double slog2 = chol_sym<256>(W, rdg, tid);
    linv_sym<256>(W, rdg, Li, tid);
    if(tid<32){
      float acc=0.f;
      for(int m=0;m<=tid;++m) acc=fmaf(Li[tid*33+m],uv[m],acc);
      Lu[tid]=acc;
    }
    __syncthreads();
    if(tid<32){
      float am=0.f, ay=0.f;
      for(int m2=tid;m2<32;++m2){ float lv=Li[m2*33+tid]; am=fmaf(lv,Lu[m2],am); ay=fmaf(lv,ev[m2],ay); }
      gv[tid]=am; yv[tid]=ay;
      wsf[F_MLAST+tid]=am; out[O_EX+(size_t)NN*32+tid]=am;
      float xt=am+ay;
      wsf[F_XT+tid]=xt; out[O_Z+(size_t)NN*32+tid]=xt;
    }
    __syncthreads();
    for(int q=tid;q<1024;q+=256){
      int r=q>>5,c=q&31;
      float a=0.f;
      #pragma unroll
      for(int m=0;m<32;++m) a=fmaf(Li[m*33+r],Li[m*33+c],a);
      wsf[F_COVT+q]=a;
      out[O_EXXT+(size_t)NN*1024+q]=a+gv[r]*gv[c];
    }
    if(tid==0){
      double gam=*(const double*)(SE+GAMOFF);
      double hm=0.0;
      for(int m=0;m<32;++m) hm += (double)uv[m]*(double)gv[m];
      wsd[WSD_LOGZQ] = gam + 0.5*hm + 0.5*Dd*LOG2PI_ - slog2;
    }
  }
}

// ---------------- affine-scan combine (leaf for time t at slot t+1; pad -> slot 0) ----------------
__device__ __forceinline__ int amap(int j){ return (j<NN)? (NN-j) : 0; }

__global__ __launch_bounds__(256) void k_ca(float* wsf, int d, int mode){
  __shared__ float SA[2148], SB[2148];
  __shared__ float PXF[1089], Tm[1056], GYT[1056];
  int tid = threadIdx.x;
  int i = blockIdx.x;
  int iA = (i<<(d+1)) + (1<<d) - 1;
  int iB = iA + (1<<d);
  float* base = wsf + F_SCAN;
  float* pa = base + (size_t)amap(iA)*SSTR;
  float* pb = base + (size_t)amap(iB)*SSTR;
  for(int q=tid;q<537;q+=256){ ((float4*)SA)[q]=((const float4*)pa)[q]; ((float4*)SB)[q]=((const float4*)pb)[q]; }
  __syncthreads();
  int fa=(SA[FLGOFF]!=0.f), fb=(SB[FLGOFF]!=0.f);
  if(mode==1){
    for(int q=tid;q<537;q+=256) ((float4*)pb)[q]=((float4*)SA)[q];
    if(tid==0) pa[FLGOFF]=0.f;
    return;
  }
  if(mode==2){ for(int q=tid;q<537;q+=256) ((float4*)pa)[q]=((float4*)SB)[q]; }
  float* X = (mode==2)? SB : SA;  int fx=(mode==2)?fb:fa;
  float* Y = (mode==2)? SA : SB;  int fy=(mode==2)?fa:fb;
  if(!fx && !fy){ if(tid==0) pb[FLGOFF]=0.f; return; }
  if(!fx){ for(int q=tid;q<537;q+=256) ((float4*)pb)[q]=((float4*)Y)[q]; return; }
  if(!fy){ for(int q=tid;q<537;q+=256) ((float4*)pb)[q]=((float4*)X)[q]; return; }
  // result = Y ∘ X (X applied first): G=GY*GX, P=GY*PX*GY^T+PY, c=GY*cX+cY
  for(int q=tid;q<528;q+=256){
    int r,c; tri_rc(q,r,c);
    float v = X[BP+q]; PXF[r*33+c]=v; PXF[c*33+r]=v;
  }
  for(int q=tid;q<1024;q+=256){ int c=q>>5,m=q&31; GYT[c*33+m]=Y[BG+c*32+m]; }
  __syncthreads();
  for(int q=tid;q<1024;q+=256){
    int r=q>>5,c=q&31;
    float a=0.f;
    #pragma unroll
    for(int m=0;m<32;++m) a=fmaf(GYT[r*33+m],PXF[m*33+c],a);
    Tm[r*33+c]=a;
  }
  __syncthreads();
  for(int q=tid;q<528;q+=256){
    int r,c; tri_rc(q,r,c);
    float a=0.f;
    #pragma unroll
    for(int m=0;m<32;++m) a=fmaf(Tm[r*33+m],GYT[c*33+m],a);
    pb[BP+q]=a+Y[BP+q];
  }
  for(int q=tid;q<1024;q+=256){
    int r=q>>5,c=q&31;
    float a=0.f;
    #pragma unroll
    for(int m=0;m<32;++m) a=fmaf(GYT[r*33+m],X[BG+m*32+c],a);
    pb[BG+q]=a;
  }
  if(tid<32){
    float az=0.f,am=0.f;
    #pragma unroll
    for(int m=0;m<32;++m){ float g=GYT[tid*33+m]; az=fmaf(g,X[BCZ+m],az); am=fmaf(g,X[BCM+m],am); }
    pb[BCZ+tid]=az+Y[BCZ+tid];
    pb[BCM+tid]=am+Y[BCM+tid];
  }
  if(tid==0) pb[FLGOFF]=1.f;
}

// ---------------- apply composites: m_t, ExxT_t, z_t (composite for time t at slot t) ----------------
__global__ __launch_bounds__(256) void k_smz(float* wsf, float* out){
  __shared__ float CP[1620];
  __shared__ float CVF[1024], Tm[1024];
  __shared__ float mlv[32], xtv[32], mv[32], zv[32];
  int tid=threadIdx.x;
  int t = blockIdx.x;           // 0..NN-1
  const float* pe = wsf + F_SCAN + (size_t)t*SSTR;
  for(int p=0;p<2;p++){ int q=tid+(p<<8); if(q<405) ((float4*)CP)[q]=((const float4*)pe)[q]; }
  for(int q=tid;q<1024;q+=256) CVF[q]=wsf[F_COVT+q];
  if(tid<32){ mlv[tid]=wsf[F_MLAST+tid]; xtv[tid]=wsf[F_XT+tid]; }
  __syncthreads();
  if(tid<32){
    float am=0.f, az=0.f;
    #pragma unroll
    for(int m=0;m<32;++m){
      am=fmaf(CP[BG+tid*32+m], mlv[m], am);
      az=fmaf(CP[BG+tid*32+m], xtv[m], az);
    }
    mv[tid]=am+CP[BCM+tid];
    zv[tid]=az+CP[BCZ+tid];
    out[O_EX+(size_t)t*32+tid]=mv[tid];
    out[O_Z +(size_t)t*32+tid]=zv[tid];
  }
  for(int q=tid;q<1024;q+=256){
    int r=q>>5,c=q&31;
    float acc=0.f;
    #pragma unroll
    for(int m=0;m<32;++m) acc=fmaf(CP[BG+r*32+m], CVF[m*32+c], acc);
    Tm[q]=acc;
  }
  __syncthreads();
  for(int q=tid;q<528;q+=256){
    int r,c; tri_rc(q,r,c);
    float acc=0.f;
    #pragma unroll
    for(int m=0;m<32;++m) acc=fmaf(Tm[r*32+m], CP[BG+c*32+m], acc);
    float cov = acc + CP[BP+q];
    float e = cov + mv[r]*mv[c];
    out[O_EXXT+(size_t)t*1024 + r*32+c]=e;
    if(r!=c) out[O_EXXT+(size_t)t*1024 + c*32+r]=e;
  }
}

// ---------------- Cross_t ----------------
__global__ __launch_bounds__(256) void k_cross(float* wsf, float* out){
  __shared__ float PV[1089], GF[1024], E1[1024];
  __shared__ float gv[32], m1[32];
  int tid=threadIdx.x;
  int t = blockIdx.x;           // 0..NN-1
  float* outc = out + O_CROSS + (size_t)t*1024;
  for(int q=tid;q<528;q+=256){
    int r,c; tri_rc(q,r,c);
    float v=outc[q]; PV[r*33+c]=v; PV[c*33+r]=v;
  }
  if(tid<32) gv[tid]=outc[528+tid];
  for(int q=tid;q<1024;q+=256) E1[q]=out[O_EXXT+(size_t)(t+1)*1024+q];
  if(tid<32) m1[tid]=out[O_EX+(size_t)(t+1)*32+tid];
  __syncthreads();
  for(int q=tid;q<1024;q+=256){
    int r=q>>5,c=q&31;
    float acc=0.f;
    #pragma unroll
    for(int m=0;m<32;++m) acc=fmaf(PV[r*33+m], wsf[F_ATLAM+m*32+c], acc);
    GF[q]=acc;
  }
  __syncthreads();
  for(int q=tid;q<1024;q+=256){
    int i2=q>>5, j=q&31;
    float acc=0.f;
    #pragma unroll
    for(int m=0;m<32;++m) acc=fmaf(GF[j*32+m], E1[m*32+i2], acc);
    outc[q] = acc + gv[j]*m1[i2];
  }
}

// ---------------- big reduction over t ----------------
__global__ __launch_bounds__(256) void k_terms(const float* rJ, const float* rh,
    const float* plam, float* wsf, double* wsd, float* out){
  __shared__ float slam[1056], slamA[1056], sata[1056];
  __shared__ float slamb[32], satlb[32], cst[16], sw[16];
  __shared__ double sd[256];
  int tid=threadIdx.x; int i8=tid>>3, c4=(tid&7)*4;
  for(int p=0;p<4;p++){int cell=tid+(p<<8);int r=cell>>5,c=cell&31;
    slam[r*33+c]=wsf[F_LAM+cell]; slamA[r*33+c]=wsf[F_LAMA+cell]; sata[r*33+c]=wsf[F_ATLAMA+cell];}
  if(tid<32){slamb[tid]=wsf[F_LAMB+tid]; satlb[tid]=wsf[F_ATLAMB+tid];}
  if(tid<16) cst[tid] = -0.5f*wsf[F_BTLAMBK+tid] + 0.5f*wsf[F_LOGDETK+tid];
  __syncthreads();
  double dr=0.0, dt=0.0, dm=0.0;
  int t0=blockIdx.x*8;
  for(int tt=0;tt<8;++tt){
    int t=t0+tt;
    if(t<NN){ if(tid<16) sw[tid]=out[O_CAT+(size_t)t*16+tid]; }
    __syncthreads();
    size_t cb=(size_t)t*1024+((size_t)i8<<5)+c4;
    float4 exT=*(const float4*)(out+O_EXXT+cb);
    float4 rj =*(const float4*)(rJ+cb);
    dr += -0.5*(double)(rj.x*exT.x+rj.y*exT.y+rj.z*exT.z+rj.w*exT.w);
    if(tid<32) dr += (double)(rh[(size_t)t*32+tid]*out[O_EX+(size_t)t*32+tid]);
    if(t>=1){
      dt += -0.5*(double)(slam[i8*33+c4]*exT.x + slam[i8*33+c4+1]*exT.y
                        + slam[i8*33+c4+2]*exT.z + slam[i8*33+c4+3]*exT.w);
      if(tid<32) dt += (double)(slamb[tid]*out[O_EX+(size_t)t*32+tid]);
    }
    if(t<NN){
      float4 crT =*(const float4*)(out+O_CROSS+cb);
      float4 exT1=*(const float4*)(out+O_EXXT+cb+1024);
      dt += (double)(slamA[i8*33+c4]*crT.x + slamA[i8*33+c4+1]*crT.y
                   + slamA[i8*33+c4+2]*crT.z + slamA[i8*33+c4+3]*crT.w)
          -0.5*(double)(sata[i8*33+c4]*exT.x + sata[i8*33+c4+1]*exT.y
                      + sata[i8*33+c4+2]*exT.z + sata[i8*33+c4+3]*exT.w);
      if(tid<32) dt -= (double)(satlb[tid]*out[O_EX+(size_t)t*32+tid]);
      const float* pe1=(const float*)&exT1; const float* pcr=(const float*)&crT; const float* pe0=(const float*)&exT;
      #pragma unroll
      for(int q=0;q<4;q++){
        int cc=(i8<<5)+c4+q;
        float wl=0.f, wa=0.f, wt2=0.f;
        #pragma unroll
        for(int k2=0;k2<KK;k2++){ float wv=sw[k2];
          wl =fmaf(wv, plam[(size_t)k2*1024+cc], wl);
          wa =fmaf(wv, wsf[F_LAMAK+(size_t)k2*1024+cc], wa);
          wt2=fmaf(wv, wsf[F_ATLAMAK+(size_t)k2*1024+cc], wt2);}
        dm += (double)(-0.5f*wl*pe1[q] + wa*pcr[q] - 0.5f*wt2*pe0[q]);
      }
      if(tid<32){
        float wlb=0.f, wtb=0.f;
        #pragma unroll
        for(int k2=0;k2<KK;k2++){ wlb=fmaf(sw[k2], wsf[F_LAMBK+k2*32+tid], wlb);
                                  wtb=fmaf(sw[k2], wsf[F_ATLAMBK+k2*32+tid], wtb);}
        dm += (double)(wlb*out[O_EX+(size_t)(t+1)*32+tid] - wtb*out[O_EX+(size_t)t*32+tid]);
      }
      if(tid<16) dm += (double)(sw[tid]*cst[tid]);
    }
    __syncthreads();
  }
  double r1=blk_red(dr,sd,tid);
  double r2=blk_red(dt,sd,tid);
  double r3=blk_red(dm,sd,tid);
  if(tid==0){ wsd[WSD_PR+blockIdx.x]=r1; wsd[WSD_PT+blockIdx.x]=r2; wsd[WSD_PM+blockIdx.x]=r3; }
}

__global__ __launch_bounds__(256) void k_final(const float* il, const float* tl,
    const float* ilp, const float* tlp, const float* ptau, float* wsf, double* wsd, float* out){
  __shared__ double sd[256];
  int tid=threadIdx.x;
  double ez=0.0;
  for(int b=0;b<128;++b) ez += (double)wsf[F_EZ + b*256 + tid];
  double v = ez * (double)(tl[tid]-tlp[tid]);
  if(tid<16) v += (double)out[O_CAT+tid] * (double)(il[tid]-ilp[tid]);
  double hmmkl = blk_red(v, sd, tid) - (double)wsf[F_SC+0];
  double a=0,b2=0,c=0;
  for(int q=0;q<4;q++){int b3=tid+q*256; a+=wsd[WSD_PR+b3]; b2+=wsd[WSD_PT+b3]; c+=wsd[WSD_PM+b3];}
  double recog=blk_red(a,sd,tid), trns=blk_red(b2,sd,tid), mixt=blk_red(c,sd,tid);
  double ia=0, ib=0, va=0, vb=0;
  for(int p=0;p<4;p++){int cell=tid+(p<<8);
    float e0=out[O_EXXT+cell];
    ia += (double)(wsf[F_TAU+cell]*e0);
    ib += (double)(ptau[cell]*e0);
  }
  if(tid<32){ float ex0=out[O_EX+tid];
    va=(double)(ex0*wsf[F_TAUMU+tid]); vb=(double)(ex0*wsf[F_TPM+tid]); }
  double s_ia=blk_red(ia,sd,tid), s_ib=blk_red(ib,sd,tid);
  double s_va=blk_red(va,sd,tid), s_vb=blk_red(vb,sd,tid);
  if(tid==0){
    double init_term = -0.5*s_ia + s_va + wsd[WSD_LOGC0];
    double mix_init  = -0.5*s_ib + s_vb + wsd[WSD_MIXC];
    double trans_term = trns + (double)NN*(-0.5*wsd[WSD_BTLAMB] + 0.5*wsd[WSD_LDLAM] - 0.5*Dd*LOG2PI_);
    double mix_trans  = mixt - 0.5*(double)NN*(double)Dd*LOG2PI_;
    double lds_kl = (init_term+trans_term) + recog - wsd[WSD_LOGZQ] - (mix_init+mix_trans);
    out[O_KL] = (float)(lds_kl + hmmkl);
  }
}

// ---------------- launch ----------------
extern "C" void kernel_launch(void* const* d_in, const int* in_sizes, int n_in,
                              void* d_out, int out_size, void* d_ws, size_t ws_size,
                              hipStream_t stream){
  const float* rJ  =(const float*)d_in[0];
  const float* rh  =(const float*)d_in[1];
  const float* loc =(const float*)d_in[2];
  const float* Tp  =(const float*)d_in[3];
  const float* Lp  =(const float*)d_in[4];
  const float* X   =(const float*)d_in[5];
  const float* il  =(const float*)d_in[6];
  const float* tl  =(const float*)d_in[7];
  const float* plam=(const float*)d_in[8];
  const float* pX  =(const float*)d_in[9];
  const float* ptau=(const float*)d_in[10];
  const float* pmu =(const float*)d_in[11];
  const float* ilp =(const float*)d_in[12];
  const float* tlp =(const float*)d_in[13];
  const int*   seed=(const int*)d_in[14];
  float* out=(float*)d_out;
  double* wsd=(double*)d_ws;
  float* wsf=(float*)((char*)d_ws + 32768);

  k_setup<<<1,256,0,stream>>>(rJ,rh,loc,Tp,Lp,X,plam,pX,ptau,pmu,wsf,wsd);
  k_eps<<<1024,256,0,stream>>>(seed, out + O_Z);
  k_hmmpow<<<1,256,0,stream>>>(tl, wsf);
  k_hmmab<<<32,256,0,stream>>>(il, wsf);
  k_cat<<<128,256,0,stream>>>(tl, wsf, out);
  k_leaf<<<8192,256,0,stream>>>(rJ, rh, wsf, wsd);
  for(int d=0; d<13; ++d) k_cf<<<(8192>>(d+1)),256,0,stream>>>(wsf, out, d, 0);
  k_cf<<<1,256,0,stream>>>(wsf, out, 12, 1);
  for(int d=11; d>=0; --d) k_cf<<<(8192>>(d+1)),256,0,stream>>>(wsf, out, d, 2);
  k_point<<<8192,256,0,stream>>>(wsf, wsd, out);
  for(int d=0; d<13; ++d) k_ca<<<(8192>>(d+1)),256,0,stream>>>(wsf, d, 0);
  k_ca<<<1,256,0,stream>>>(wsf, 12, 1);
  for(int d=11; d>=0; --d) k_ca<<<(8192>>(d+1)),256,0,stream>>>(wsf, d, 2);
  k_smz<<<NN,256,0,stream>>>(wsf, out);
  k_cross<<<NN,256,0,stream>>>(wsf, out);
  k_terms<<<1024,256,0,stream>>>(rJ, rh, plam, wsf, wsd, out);
  k_final<<<1,256,0,stream>>>(il, tl, ilp, tlp, ptau, wsf, wsd, out);
}

// Round 5
// 2188.924 us; speedup vs baseline: 162.2437x; 1.1795x over previous
//
#include <hip/hip_runtime.h>
#include <math.h>
#include <stdint.h>

#define Dd 32
#define TT 8192
#define NN 8191
#define KK 16
#define LOG2PI_ 1.8378770664093453

// ---------------- ws doubles ----------------
#define WSD_LOGC0  0
#define WSD_LOGZQ  1
#define WSD_MIXC   3
#define WSD_LDLAM  4
#define WSD_BTLAMB 5
#define WSD_PR     8
#define WSD_PT     1032
#define WSD_PM     2056
// ---------------- ws floats (base = byte 32768) ----------------
#define F_TAU      0
#define F_TAUMU    1024
#define F_LAM      1056
#define F_A        2080
#define F_B        3104
#define F_ATLAM    3136
#define F_ATLAMA   4160
#define F_LAMA     5184
#define F_LAMB     6208
#define F_ATLAMB   6240
#define F_SC       6272
#define F_LAMAK    6304
#define F_ATLAMAK  22688
#define F_LAMBK    39072
#define F_ATLAMBK  39584
#define F_BTLAMBK  40096
#define F_LOGDETK  40112
#define F_TPM      40128
#define F_J0       40160
#define F_H0       41184
#define F_MLAST    41216
#define F_COVT     41248
#define F_XT       42272
#define F_TPOW     42304
#define F_ALPHA    45632
#define F_BETA     176704
#define F_EZ       307776
#define F_SCAN     340544

// scan slot layout (stride 2148 floats)
#define SSTR   2148
#define POFF   0
#define QOFF   528
#define ROFF   1056
#define PPOFF  2080
#define QQOFF  2112
#define GAMOFF 2144
#define FLGOFF 2146
// affine (B) slot layout (same slots, reused after k_point)
#define BG     0
#define BCZ    1024
#define BCM    1056
#define BP     1088

// out offsets (floats)
#define O_Z     ((size_t)0)
#define O_EX    ((size_t)262144)
#define O_EXXT  ((size_t)524288)
#define O_CROSS ((size_t)8912896)
#define O_CAT   ((size_t)17300480)
#define O_KL    ((size_t)17431536)

// ---------------- threefry ----------------
__device__ __forceinline__ uint32_t rotl32(uint32_t v, int d){ return (v<<d)|(v>>(32-d)); }
__device__ __forceinline__ void threefry2x32(uint32_t k0, uint32_t k1, uint32_t x0, uint32_t x1,
                                             uint32_t& o0, uint32_t& o1){
  uint32_t ks2 = k0 ^ k1 ^ 0x1BD11BDAu;
  x0 += k0; x1 += k1;
  x0+=x1; x1=rotl32(x1,13); x1^=x0;  x0+=x1; x1=rotl32(x1,15); x1^=x0;
  x0+=x1; x1=rotl32(x1,26); x1^=x0;  x0+=x1; x1=rotl32(x1, 6); x1^=x0;
  x0+=k1; x1+=ks2+1u;
  x0+=x1; x1=rotl32(x1,17); x1^=x0;  x0+=x1; x1=rotl32(x1,29); x1^=x0;
  x0+=x1; x1=rotl32(x1,16); x1^=x0;  x0+=x1; x1=rotl32(x1,24); x1^=x0;
  x0+=ks2; x1+=k0+2u;
  x0+=x1; x1=rotl32(x1,13); x1^=x0;  x0+=x1; x1=rotl32(x1,15); x1^=x0;
  x0+=x1; x1=rotl32(x1,26); x1^=x0;  x0+=x1; x1=rotl32(x1, 6); x1^=x0;
  x0+=k0; x1+=k1+3u;
  x0+=x1; x1=rotl32(x1,17); x1^=x0;  x0+=x1; x1=rotl32(x1,29); x1^=x0;
  x0+=x1; x1=rotl32(x1,16); x1^=x0;  x0+=x1; x1=rotl32(x1,24); x1^=x0;
  x0+=k1; x1+=ks2+4u;
  x0+=x1; x1=rotl32(x1,13); x1^=x0;  x0+=x1; x1=rotl32(x1,15); x1^=x0;
  x0+=x1; x1=rotl32(x1,26); x1^=x0;  x0+=x1; x1=rotl32(x1, 6); x1^=x0;
  x0+=ks2; x1+=k0+5u;
  o0=x0; o1=x1;
}
__device__ __forceinline__ float tf_normal(uint32_t bits){
  float fl = __uint_as_float((bits>>9) | 0x3F800000u) - 1.0f;
  const float lo = -0.99999994f;
  float u = fmaxf(lo, fl*2.0f + lo);
  float w = -log1pf(-u*u);
  float p;
  if (w < 5.0f){
    w -= 2.5f;
    p = 2.81022636e-08f;
    p = fmaf(p,w,3.43273939e-07f); p = fmaf(p,w,-3.5233877e-06f);
    p = fmaf(p,w,-4.39150654e-06f); p = fmaf(p,w,0.00021858087f);
    p = fmaf(p,w,-0.00125372503f); p = fmaf(p,w,-0.00417768164f);
    p = fmaf(p,w,0.246640727f); p = fmaf(p,w,1.50140941f);
  } else {
    w = sqrtf(w) - 3.0f;
    p = -0.000200214257f;
    p = fmaf(p,w,0.000100950558f); p = fmaf(p,w,0.00134934322f);
    p = fmaf(p,w,-0.00367342844f); p = fmaf(p,w,0.00573950773f);
    p = fmaf(p,w,-0.0076224613f); p = fmaf(p,w,0.00943887047f);
    p = fmaf(p,w,1.00167406f); p = fmaf(p,w,2.83297682f);
  }
  return 1.4142135381698608f * (p*u);
}

// ---------------- helpers ----------------
__device__ __forceinline__ void tri_rc(int i, int& r, int& c){
  int rr = (int)((sqrtf(8.f*(float)i+1.f)-1.f)*0.5f);
  while((rr+1)*(rr+2)/2 <= i) ++rr;
  while(rr*(rr+1)/2 > i) --rr;
  r = rr; c = i - rr*(rr+1)/2;
}

// Fused cholesky + L^-1 (33 barrier steps). W: full symmetric (stride 33);
// after: W subdiag cols hold scaled L, Li = L^-1 (lower), rdg[j]=1/L_jj.
// Returns sum log L_jj.
template<int NT>
__device__ double chol_linv(float* W, float* Li, float* rdg, int tid){
  #pragma unroll
  for(int p=0;p<1024/NT;++p){ int q=tid+p*NT; int r=q>>5,c=q&31; Li[r*33+c]=(r==c)?1.f:0.f; }
  double slog=0.0;
  for(int j=0;j<33;++j){
    if(j<32){
      float dd = W[j*33+j];
      float rd = 1.0f/sqrtf(dd);
      float invd = rd*rd;
      slog += (double)(0.5f*__logf(dd));
      if(tid==0) rdg[j]=rd;
      #pragma unroll
      for(int p=0;p<1024/NT;++p){
        int q=tid+p*NT; int r=q>>5, c=q&31;
        if(r>j){
          if(c>j)       W[r*33+c] -= W[j*33+r]*(W[j*33+c]*invd);
          else if(c==j) W[r*33+j] *= rd;
        }
      }
    }
    if(j>0){
      int ii=j-1;
      float rdi = rdg[ii];
      #pragma unroll
      for(int p=0;p<1024/NT;++p){
        int q=tid+p*NT; int r=q>>5,c=q&31;
        if(r>ii && c<=ii) Li[r*33+c] -= W[r*33+ii]*(Li[ii*33+c]*rdi);
      }
    }
    __syncthreads();
  }
  #pragma unroll
  for(int p=0;p<1024/NT;++p){ int q=tid+p*NT; int r=q>>5,c=q&31; if(c<=r) Li[r*33+c]*=rdg[r]; }
  __syncthreads();
  return slog;
}

__device__ __forceinline__ double blk_red(double v, double* sd, int tid){
  sd[tid]=v; __syncthreads();
  for(int s=128;s>0;s>>=1){ if(tid<s) sd[tid]+=sd[tid+s]; __syncthreads(); }
  double r=sd[0]; __syncthreads(); return r;
}
__device__ double blk_logdet(float* Ms, int tid){
  double sl = 0.0;
  for (int j=0;j<Dd;++j){
    float dd = Ms[j*33+j];
    sl += log((double)dd);
    float invd = 1.0f/dd;
    #pragma unroll
    for(int p=0;p<4;p++){
      int cell = tid + (p<<8); int r=cell>>5, c=cell&31;
      if(r>j && c>j && c<=r) Ms[r*33+c] -= Ms[r*33+j]*(Ms[c*33+j]*invd);
    }
    __syncthreads();
  }
  return sl;
}

// ---------------- setup: 19 independent blocks ----------------
__global__ __launch_bounds__(256) void k_setup(const float* rJ, const float* rh, const float* loc,
    const float* Tp, const float* Lp, const float* X, const float* plam, const float* pX,
    const float* ptau, const float* pmu, float* wsf, double* wsd){
  __shared__ float s1[1056], s2[1056], s3[1056];
  __shared__ float sv[32], sv2[32];
  int tid=threadIdx.x; int b=blockIdx.x;
  if(b==0){
    // ---- tau path ----
    for(int p=0;p<4;p++){int cell=tid+(p<<8);int r=cell>>5,c=cell&31; s1[r*33+c]=Tp[cell];}
    if(tid<32) sv[tid]=loc[tid];
    __syncthreads();
    for(int p=0;p<4;p++){int cell=tid+(p<<8);int r=cell>>5,c=cell&31;
      float a=0.f;
      #pragma unroll
      for(int m=0;m<Dd;++m) a=fmaf(s1[r*33+m], s1[c*33+m], a);
      if(r==c) a+=1e-8f;
      s2[r*33+c]=a; wsf[F_TAU+cell]=a; wsf[F_J0+cell]=a+rJ[cell];
    }
    __syncthreads();
    if(tid<32){ float tm=0.f;
      #pragma unroll
      for(int m=0;m<Dd;++m) tm=fmaf(s2[tid*33+m], sv[m], tm);
      sv2[tid]=tm; wsf[F_TAUMU+tid]=tm; wsf[F_H0+tid]=tm+rh[tid];
    }
    __syncthreads();
    double ldt = blk_logdet(s2, tid);
    if(tid==0){ double dd=0; for(int m=0;m<Dd;++m) dd += (double)sv[m]*(double)sv2[m];
      wsd[WSD_LOGC0] = -0.5*dd + 0.5*ldt - 0.5*Dd*LOG2PI_; }
  } else if(b==1){
    // ---- lam / A path ----
    for(int p=0;p<4;p++){int cell=tid+(p<<8);int r=cell>>5,c=cell&31; s1[r*33+c]=Lp[cell];}
    __syncthreads();
    for(int p=0;p<4;p++){int cell=tid+(p<<8);int r=cell>>5,c=cell&31;
      float a=0.f;
      #pragma unroll
      for(int m=0;m<Dd;++m) a=fmaf(s1[r*33+m], s1[c*33+m], a);
      if(r==c) a+=1e-8f;
      s2[r*33+c]=a; wsf[F_LAM+cell]=a;
    }
    __syncthreads();
    for(int p=0;p<4;p++){int cell=tid+(p<<8);int r=cell>>5,c=cell&31;
      float a=X[r*33+c]; s3[r*33+c]=a; wsf[F_A+cell]=a; }
    if(tid<32){ sv[tid]=X[tid*33+32]; wsf[F_B+tid]=sv[tid]; }
    __syncthreads();
    for(int p=0;p<4;p++){int cell=tid+(p<<8);int r=cell>>5,c=cell&31;
      float a=0.f,b2=0.f;
      #pragma unroll
      for(int m=0;m<Dd;++m){ a=fmaf(s2[r*33+m], s3[m*33+c], a); b2=fmaf(s3[m*33+r], s2[m*33+c], b2); }
      s1[r*33+c]=a; wsf[F_LAMA+cell]=a; wsf[F_ATLAM+cell]=b2;
    }
    if(tid<32){ float lb=0.f;
      #pragma unroll
      for(int m=0;m<Dd;++m) lb=fmaf(s2[tid*33+m], sv[m], lb);
      sv2[tid]=lb; wsf[F_LAMB+tid]=lb;
    }
    __syncthreads();
    for(int p=0;p<4;p++){int cell=tid+(p<<8);int r=cell>>5,c=cell&31;
      float a=0.f;
      #pragma unroll
      for(int m=0;m<Dd;++m) a=fmaf(s3[m*33+r], s1[m*33+c], a);
      wsf[F_ATLAMA+cell]=a;
    }
    if(tid<32){ float ab=0.f;
      #pragma unroll
      for(int m=0;m<Dd;++m) ab=fmaf(s3[m*33+tid], sv2[m], ab);
      wsf[F_ATLAMB+tid]=ab;
    }
    if(tid==0){ double bb=0; for(int m=0;m<Dd;++m) bb += (double)sv[m]*(double)sv2[m];
      wsd[WSD_BTLAMB]=bb; }
    __syncthreads();
    double ldl = blk_logdet(s2, tid);
    if(tid==0) wsd[WSD_LDLAM]=ldl;
  } else if(b==2){
    // ---- prior tau path ----
    for(int p=0;p<4;p++){int cell=tid+(p<<8);int r=cell>>5,c=cell&31; s1[r*33+c]=ptau[cell];}
    if(tid<32) sv[tid]=pmu[tid];
    __syncthreads();
    if(tid<32){ float tm=0.f;
      #pragma unroll
      for(int m=0;m<Dd;++m) tm=fmaf(s1[tid*33+m], sv[m], tm);
      sv2[tid]=tm; wsf[F_TPM+tid]=tm;
    }
    __syncthreads();
    double ldp = blk_logdet(s1, tid);
    if(tid==0){ double dd=0; for(int m=0;m<Dd;++m) dd += (double)sv[m]*(double)sv2[m];
      wsd[WSD_MIXC] = -0.5*dd + 0.5*ldp - 0.5*Dd*LOG2PI_; }
  } else {
    // ---- per-k mixture blocks ----
    int k2 = b-3;
    for(int p=0;p<4;p++){int cell=tid+(p<<8);int r=cell>>5,c=cell&31;
      s2[r*33+c]=plam[k2*1024+cell]; s3[r*33+c]=pX[k2*1056 + r*33 + c];}
    if(tid<32) sv[tid]=pX[k2*1056 + tid*33 + 32];
    __syncthreads();
    for(int p=0;p<4;p++){int cell=tid+(p<<8);int r=cell>>5,c=cell&31;
      float a=0.f;
      #pragma unroll
      for(int m=0;m<Dd;++m) a=fmaf(s2[r*33+m], s3[m*33+c], a);
      s1[r*33+c]=a; wsf[F_LAMAK + (size_t)k2*1024 + cell]=a;
    }
    if(tid<32){ float lb=0.f;
      #pragma unroll
      for(int m=0;m<Dd;++m) lb=fmaf(s2[tid*33+m], sv[m], lb);
      sv2[tid]=lb; wsf[F_LAMBK + k2*32 + tid]=lb;
    }
    __syncthreads();
    for(int p=0;p<4;p++){int cell=tid+(p<<8);int r=cell>>5,c=cell&31;
      float a=0.f;
      #pragma unroll
      for(int m=0;m<Dd;++m) a=fmaf(s3[m*33+r], s1[m*33+c], a);
      wsf[F_ATLAMAK + (size_t)k2*1024 + cell]=a;
    }
    if(tid<32){ float ab=0.f;
      #pragma unroll
      for(int m=0;m<Dd;++m) ab=fmaf(s3[m*33+tid], sv2[m], ab);
      wsf[F_ATLAMBK + k2*32 + tid]=ab;
    }
    if(tid==0){ float bb=0.f; for(int m=0;m<Dd;++m) bb=fmaf(sv[m],sv2[m],bb);
      wsf[F_BTLAMBK + k2]=bb; }
    __syncthreads();
    double dk = blk_logdet(s2, tid);
    if(tid==0) wsf[F_LOGDETK + k2]=(float)dk;
  }
}

// ---------------- eps -> out O_Z (staged; overwritten by sampler later) ----------------
__global__ __launch_bounds__(256) void k_eps(const int* seedp, float* outz){
  uint32_t seed = (uint32_t)seedp[0];
  uint32_t K0,K1;
  threefry2x32(0u, seed, 0u, 1u, K0, K1);
  uint32_t i = blockIdx.x*256u + threadIdx.x;
  uint32_t o0,o1;
  threefry2x32(K0, K1, 0u, i, o0, o1);
  outz[i] = tf_normal(o0 ^ o1);
}

// ---------------- HMM ----------------
__global__ __launch_bounds__(256) void k_hmmpow(const float* tl, float* wsf){
  __shared__ float A0[256], A1[256];
  int tid=threadIdx.x;
  A0[tid]=tl[tid];
  wsf[F_TPOW+tid]=A0[tid];
  __syncthreads();
  float* cur=A0; float* nxt=A1;
  for(int k=1;k<13;++k){
    int i=tid>>4, j=tid&15;
    float mx=-3.0e38f;
    #pragma unroll
    for(int m=0;m<16;++m) mx=fmaxf(mx, cur[i*16+m]+cur[m*16+j]);
    float s=0.f;
    #pragma unroll
    for(int m=0;m<16;++m) s+=__expf(cur[i*16+m]+cur[m*16+j]-mx);
    float v=mx+__logf(s);
    nxt[tid]=v; wsf[F_TPOW+k*256+tid]=v;
    __syncthreads();
    float* t2=cur; cur=nxt; nxt=t2;
  }
}

__global__ __launch_bounds__(256) void k_hmmab(const float* il, float* wsf){
  __shared__ float S[3328];
  int tid=threadIdx.x;
  for(int p=0;p<13;++p) S[p*256+tid]=wsf[F_TPOW+p*256+tid];
  __syncthreads();
  int n = blockIdx.x*256 + tid;
  if(n>NN-1) return;
  float v[16], w[16];
  #pragma unroll
  for(int j=0;j<16;++j) v[j]=il[j];
  for(int k=0;k<13;++k){
    if((n>>k)&1){
      #pragma unroll
      for(int j=0;j<16;++j){
        float mx=-3.0e38f;
        #pragma unroll
        for(int i2=0;i2<16;++i2) mx=fmaxf(mx, v[i2]+S[k*256+i2*16+j]);
        float s=0.f;
        #pragma unroll
        for(int i2=0;i2<16;++i2) s+=__expf(v[i2]+S[k*256+i2*16+j]-mx);
        w[j]=mx+__logf(s);
      }
      #pragma unroll
      for(int j=0;j<16;++j) v[j]=w[j];
    }
  }
  #pragma unroll
  for(int j=0;j<16;++j) wsf[F_ALPHA+(size_t)n*16+j]=v[j];
  if(n==NN-1){
    float mx=-3.0e38f;
    #pragma unroll
    for(int j=0;j<16;++j) mx=fmaxf(mx,v[j]);
    float s=0.f;
    #pragma unroll
    for(int j=0;j<16;++j) s+=__expf(v[j]-mx);
    wsf[F_SC+0]=mx+__logf(s);
  }
  int m = NN-1-n;
  float b[16];
  #pragma unroll
  for(int i2=0;i2<16;++i2) b[i2]=0.f;
  for(int k=0;k<13;++k){
    if((m>>k)&1){
      #pragma unroll
      for(int i2=0;i2<16;++i2){
        float mx=-3.0e38f;
        #pragma unroll
        for(int j=0;j<16;++j) mx=fmaxf(mx, S[k*256+i2*16+j]+b[j]);
        float s=0.f;
        #pragma unroll
        for(int j=0;j<16;++j) s+=__expf(S[k*256+i2*16+j]+b[j]-mx);
        w[i2]=mx+__logf(s);
      }
      #pragma unroll
      for(int i2=0;i2<16;++i2) b[i2]=w[i2];
    }
  }
  #pragma unroll
  for(int i2=0;i2<16;++i2) wsf[F_BETA+(size_t)n*16+i2]=b[i2];
}

// ---------------- cat_es + EZZNT partials (single barrier) ----------------
__global__ __launch_bounds__(256) void k_cat(const float* tl, float* wsf, float* out){
  __shared__ float Ts[256]; __shared__ float al[1024]; __shared__ float be[1040];
  int tid=threadIdx.x;
  Ts[tid]=tl[tid];
  float logZ = wsf[F_SC+0];
  int n0=blockIdx.x*64;
  for(int q=tid;q<1024;q+=256){ int n=n0+(q>>4); al[q] = (n<NN)? wsf[F_ALPHA+(size_t)n*16+(q&15)] : 0.f; }
  for(int q=tid;q<1040;q+=256){ int n=n0+(q>>4); be[q] = (n<NN)? wsf[F_BETA +(size_t)n*16+(q&15)] : 0.f; }
  __syncthreads();
  for(int q=tid;q<1024;q+=256){ int n=n0+(q>>4);
    if(n<NN) out[O_CAT+(size_t)n*16+(q&15)] = __expf(al[q]+be[q]-logZ); }
  int i=tid>>4, j=tid&15;
  float acc=0.f;
  #pragma unroll 4
  for(int nn=0;nn<64;++nn){
    int n=n0+nn;
    if(n<NN-1) acc += __expf(al[nn*16+i]+Ts[i*16+j]+be[(nn+1)*16+j]-logZ);
  }
  wsf[F_EZ + blockIdx.x*256 + tid]=acc;
}

// ---------------- leaves: slot 0 = unary(J0,h0,logc0), slots t=1..NN = pair_t ----------------
__global__ __launch_bounds__(256) void k_leaf(const float* rJ, const float* rh, float* wsf, double* wsd){
  int b = blockIdx.x; int tid=threadIdx.x;
  float* pe = wsf + F_SCAN + (size_t)b*SSTR;
  if(b==0){
    for(int q=tid;q<528;q+=256){
      int r,c; tri_rc(q,r,c);
      pe[POFF+q]=0.f;
      pe[QOFF+q]=wsf[F_J0 + r*32+c];
    }
    for(int q=tid;q<1024;q+=256) pe[ROFF+q]=0.f;
    if(tid<32){ pe[PPOFF+tid]=0.f; pe[QQOFF+tid]=wsf[F_H0+tid]; }
    if(tid==0){ *(double*)(pe+GAMOFF)=wsd[WSD_LOGC0]; pe[FLGOFF]=1.f; }
  } else {
    int t = b;
    for(int q=tid;q<528;q+=256){
      int r,c; tri_rc(q,r,c);
      pe[POFF+q] = wsf[F_ATLAMA + r*32+c] + ((r==c)?1e-6f:0.f);
      pe[QOFF+q] = wsf[F_LAM + r*32+c] + rJ[(size_t)t*1024 + r*32+c];
    }
    for(int q=tid;q<1024;q+=256) pe[ROFF+q] = -wsf[F_ATLAM+q];
    if(tid<32){
      pe[PPOFF+tid] = -wsf[F_ATLAMB+tid];
      pe[QQOFF+tid] = wsf[F_LAMB+tid] + rh[(size_t)t*32+tid];
    }
    if(tid==0){
      *(double*)(pe+GAMOFF) = -0.5*wsd[WSD_BTLAMB] + 0.5*wsd[WSD_LDLAM];
      pe[FLGOFF]=1.f;
    }
  }
}

// ---------------- filter-scan combine ----------------
__global__ __launch_bounds__(256) void k_cf(float* wsf, float* out, int d, int mode){
  __shared__ float SA[2148], SB[2148];
  __shared__ float W[1089], Li[1089], T1[1056], T2[1056];
  __shared__ float rdg[32], Ls[32];
  int tid = threadIdx.x;
  int i = blockIdx.x;
  int iA = (i<<(d+1)) + (1<<d) - 1;
  int iB = iA + (1<<d);
  float* base = wsf + F_SCAN;
  float* pa = base + (size_t)iA*SSTR;
  float* pb = base + (size_t)iB*SSTR;
  for(int q=tid;q<537;q+=256){ ((float4*)SA)[q]=((const float4*)pa)[q]; ((float4*)SB)[q]=((const float4*)pb)[q]; }
  __syncthreads();
  int fa=(SA[FLGOFF]!=0.f), fb=(SB[FLGOFF]!=0.f);
  if(mode==1){
    float* st = out + O_EXXT;    // stage up-sweep total (Jlast,hlast,lc); k_smz overwrites later
    for(int q=tid;q<537;q+=256){ ((float4*)st)[q]=((float4*)SB)[q]; ((float4*)pb)[q]=((float4*)SA)[q]; }
    if(tid==0) pa[FLGOFF]=0.f;
    return;
  }
  if(mode==2){ for(int q=tid;q<537;q+=256) ((float4*)pa)[q]=((float4*)SB)[q]; }
  float* X = (mode==2)? SB : SA;  int fx=(mode==2)?fb:fa;
  float* Y = (mode==2)? SA : SB;  int fy=(mode==2)?fa:fb;
  if(!fx && !fy){ if(tid==0) pb[FLGOFF]=0.f; return; }
  if(!fx){ for(int q=tid;q<537;q+=256) ((float4*)pb)[q]=((float4*)Y)[q]; return; }
  if(!fy){ for(int q=tid;q<537;q+=256) ((float4*)pb)[q]=((float4*)X)[q]; return; }
  // W = Q_x + P_y
  for(int q=tid;q<528;q+=256){
    int r,c; tri_rc(q,r,c);
    float w = X[QOFF+q] + Y[POFF+q];
    W[r*33+c]=w; W[c*33+r]=w;
  }
  __syncthreads();
  double slog = chol_linv<256>(W, Li, rdg, tid);
  // Ls = Li * s,  s = q_x + p_y
  if(tid<32){
    float acc=0.f;
    for(int m=0;m<=tid;++m) acc = fmaf(Li[tid*33+m], X[QQOFF+m]+Y[PPOFF+m], acc);
    Ls[tid]=acc;
  }
  // T1 = Li * R_x^T ; T2 = Li * R_y
  for(int q=tid;q<1024;q+=256){
    int i2=q&31, j=q>>5;
    float a1=0.f,a2=0.f;
    #pragma unroll
    for(int m=0;m<32;++m){
      float lv = Li[i2*33+m];
      a1 = fmaf(lv, X[ROFF + j*32 + m], a1);
      a2 = fmaf(lv, Y[ROFF + m*32 + j], a2);
    }
    T1[i2*33+j]=a1; T2[i2*33+j]=a2;
  }
  __syncthreads();
  for(int q=tid;q<528;q+=256){
    int r,c; tri_rc(q,r,c);
    float aP=0.f,aQ=0.f;
    #pragma unroll
    for(int m=0;m<32;++m){
      aP = fmaf(T1[m*33+r], T1[m*33+c], aP);
      aQ = fmaf(T2[m*33+r], T2[m*33+c], aQ);
    }
    pb[POFF+q] = X[POFF+q] - aP;
    pb[QOFF+q] = Y[QOFF+q] - aQ;
  }
  for(int q=tid;q<1024;q+=256){
    int r=q>>5, c=q&31;
    float a=0.f;
    #pragma unroll
    for(int m=0;m<32;++m) a = fmaf(T1[m*33+r], T2[m*33+c], a);
    pb[ROFF+q] = -a;
  }
  if(tid<32){
    float ap=0.f,aq=0.f;
    #pragma unroll
    for(int m=0;m<32;++m){ ap=fmaf(T1[m*33+tid],Ls[m],ap); aq=fmaf(T2[m*33+tid],Ls[m],aq); }
    pb[PPOFF+tid] = X[PPOFF+tid] - ap;
    pb[QQOFF+tid] = Y[QQOFF+tid] - aq;
  }
  if(tid==0){
    double g = *(double*)(X+GAMOFF) + *(double*)(Y+GAMOFF);
    double dot=0.0;
    for(int m=0;m<32;++m) dot += (double)Ls[m]*(double)Ls[m];
    *(double*)(pb+GAMOFF) = g + 0.5*dot - slog;
    pb[FLGOFF]=1.f;
  }
}

// ---------------- per-t pointwise ----------------
// block 0: final state (reads staged total). blocks b=1..NN: time t=b-1 -> affine leaf into slot b.
__global__ __launch_bounds__(256) void k_point(float* wsf, double* wsd, float* out){
  __shared__ float SE[2148];
  __shared__ float W[1089], Li[1089], T1[1056], SAT[1024];
  __shared__ float rdg[32], uv[32], Lu[32], ev[32], gv[32], yv[32];
  int tid=threadIdx.x; int b=blockIdx.x;
  float* base = wsf + F_SCAN;
  float* outz = out + O_Z;
  if(b>0){
    int t = b-1;
    float* pe = base + (size_t)b*SSTR;
    for(int q=tid;q<537;q+=256) ((float4*)SE)[q]=((const float4*)pe)[q];
    if(tid<32) ev[tid]=outz[(size_t)t*32+tid];
    for(int q=tid;q<1024;q+=256) SAT[q]=wsf[F_ATLAM+q];
    __syncthreads();
    // M = Jf_{t-1} + ATlamA + jitter ; prefix is unary: Q holds Jf
    for(int q=tid;q<528;q+=256){
      int r,c; tri_rc(q,r,c);
      float w = SE[QOFF+q] + wsf[F_ATLAMA + r*32+c] + ((r==c)?1e-6f:0.f);
      W[r*33+c]=w; W[c*33+r]=w;
    }
    if(tid<32) uv[tid]=SE[QQOFF+tid]-wsf[F_ATLAMB+tid];
    __syncthreads();
    chol_linv<256>(W, Li, rdg, tid);
    if(tid<32){
      float acc=0.f;
      for(int m=0;m<=tid;++m) acc=fmaf(Li[tid*33+m],uv[m],acc);
      Lu[tid]=acc;
    }
    for(int q=tid;q<1024;q+=256){
      int i2=q&31, j=q>>5;
      float a=0.f;
      #pragma unroll
      for(int m=0;m<32;++m) a=fmaf(Li[i2*33+m], SAT[m*32+j], a);
      T1[i2*33+j]=a;
    }
    __syncthreads();
    if(tid<32){
      float ag=0.f, ay=0.f;
      for(int m2=tid;m2<32;++m2){ float lv=Li[m2*33+tid]; ag=fmaf(lv,Lu[m2],ag); ay=fmaf(lv,ev[m2],ay); }
      gv[tid]=ag; yv[tid]=ay;
    }
    __syncthreads();
    // G = Li^T T1 = M^-1 ATlam
    for(int q=tid;q<1024;q+=256){
      int r=q>>5,c=q&31;
      float a=0.f;
      #pragma unroll
      for(int m=0;m<32;++m) a=fmaf(Li[m*33+r],T1[m*33+c],a);
      pe[BG+q]=a;
    }
    float* outc = out + O_CROSS + (size_t)t*1024;
    for(int q=tid;q<528;q+=256){
      int r,c; tri_rc(q,r,c);
      float a=0.f;
      #pragma unroll
      for(int m=0;m<32;++m) a=fmaf(Li[m*33+r],Li[m*33+c],a);
      pe[BP+q]=a; outc[q]=a;
    }
    if(tid<32){
      pe[BCM+tid]=gv[tid]; pe[BCZ+tid]=gv[tid]+yv[tid]; outc[528+tid]=gv[tid];
    }
    if(tid==0) pe[FLGOFF]=1.f;
  } else {
    const float* st = out + O_EXXT;
    for(int q=tid;q<537;q+=256) ((float4*)SE)[q]=((const float4*)st)[q];
    if(tid<32) ev[tid]=outz[(size_t)NN*32+tid];
    __syncthreads();
    for(int q=tid;q<528;q+=256){
      int r,c; tri_rc(q,r,c);
      float w = SE[QOFF+q] + ((r==c)?1e-6f:0.f);
      W[r*33+c]=w; W[c*33+r]=w;
    }
    if(tid<32) uv[tid]=SE[QQOFF+tid];
    __syncthreads();
    double slog2 = chol_linv<256>(W, Li, rdg, tid);
    if(tid<32){
      float acc=0.f;
      for(int m=0;m<=tid;++m) acc=fmaf(Li[tid*33+m],uv[m],acc);
      Lu[tid]=acc;
    }
    __syncthreads();
    if(tid<32){
      float am=0.f, ay=0.f;
      for(int m2=tid;m2<32;++m2){ float lv=Li[m2*33+tid]; am=fmaf(lv,Lu[m2],am); ay=fmaf(lv,ev[m2],ay); }
      gv[tid]=am; yv[tid]=ay;
      wsf[F_MLAST+tid]=am; out[O_EX+(size_t)NN*32+tid]=am;
      float xt=am+ay;
      wsf[F_XT+tid]=xt; out[O_Z+(size_t)NN*32+tid]=xt;
    }
    __syncthreads();
    for(int q=tid;q<1024;q+=256){
      int r=q>>5,c=q&31;
      float a=0.f;
      #pragma unroll
      for(int m=0;m<32;++m) a=fmaf(Li[m*33+r],Li[m*33+c],a);
      wsf[F_COVT+q]=a;
      out[O_EXXT+(size_t)NN*1024+q]=a+gv[r]*gv[c];
    }
    if(tid==0){
      double gam=*(const double*)(SE+GAMOFF);
      double hm=0.0;
      for(int m=0;m<32;++m) hm += (double)uv[m]*(double)gv[m];
      wsd[WSD_LOGZQ] = gam + 0.5*hm + 0.5*Dd*LOG2PI_ - slog2;
    }
  }
}

// ---------------- affine-scan combine (leaf for time t at slot t+1; pad -> slot 0) ----------------
__device__ __forceinline__ int amap(int j){ return (j<NN)? (NN-j) : 0; }

__global__ __launch_bounds__(256) void k_ca(float* wsf, int d, int mode){
  __shared__ float SA[2148], SB[2148];
  __shared__ float PXF[1089], Tm[1056], GYT[1056];
  int tid = threadIdx.x;
  int i = blockIdx.x;
  int iA = (i<<(d+1)) + (1<<d) - 1;
  int iB = iA + (1<<d);
  float* base = wsf + F_SCAN;
  float* pa = base + (size_t)amap(iA)*SSTR;
  float* pb = base + (size_t)amap(iB)*SSTR;
  for(int q=tid;q<537;q+=256){ ((float4*)SA)[q]=((const float4*)pa)[q]; ((float4*)SB)[q]=((const float4*)pb)[q]; }
  __syncthreads();
  int fa=(SA[FLGOFF]!=0.f), fb=(SB[FLGOFF]!=0.f);
  if(mode==1){
    for(int q=tid;q<537;q+=256) ((float4*)pb)[q]=((float4*)SA)[q];
    if(tid==0) pa[FLGOFF]=0.f;
    return;
  }
  if(mode==2){ for(int q=tid;q<537;q+=256) ((float4*)pa)[q]=((float4*)SB)[q]; }
  float* X = (mode==2)? SB : SA;  int fx=(mode==2)?fb:fa;
  float* Y = (mode==2)? SA : SB;  int fy=(mode==2)?fa:fb;
  if(!fx && !fy){ if(tid==0) pb[FLGOFF]=0.f; return; }
  if(!fx){ for(int q=tid;q<537;q+=256) ((float4*)pb)[q]=((float4*)Y)[q]; return; }
  if(!fy){ for(int q=tid;q<537;q+=256) ((float4*)pb)[q]=((float4*)X)[q]; return; }
  // result = Y ∘ X (X applied first): G=GY*GX, P=GY*PX*GY^T+PY, c=GY*cX+cY
  for(int q=tid;q<528;q+=256){
    int r,c; tri_rc(q,r,c);
    float v = X[BP+q]; PXF[r*33+c]=v; PXF[c*33+r]=v;
  }
  for(int q=tid;q<1024;q+=256){ int c=q>>5,m=q&31; GYT[c*33+m]=Y[BG+c*32+m]; }
  __syncthreads();
  for(int q=tid;q<1024;q+=256){
    int r=q>>5,c=q&31;
    float a=0.f;
    #pragma unroll
    for(int m=0;m<32;++m) a=fmaf(GYT[r*33+m],PXF[m*33+c],a);
    Tm[r*33+c]=a;
  }
  __syncthreads();
  for(int q=tid;q<528;q+=256){
    int r,c; tri_rc(q,r,c);
    float a=0.f;
    #pragma unroll
    for(int m=0;m<32;++m) a=fmaf(Tm[r*33+m],GYT[c*33+m],a);
    pb[BP+q]=a+Y[BP+q];
  }
  for(int q=tid;q<1024;q+=256){
    int r=q>>5,c=q&31;
    float a=0.f;
    #pragma unroll
    for(int m=0;m<32;++m) a=fmaf(GYT[r*33+m],X[BG+m*32+c],a);
    pb[BG+q]=a;
  }
  if(tid<32){
    float az=0.f,am=0.f;
    #pragma unroll
    for(int m=0;m<32;++m){ float g=GYT[tid*33+m]; az=fmaf(g,X[BCZ+m],az); am=fmaf(g,X[BCM+m],am); }
    pb[BCZ+tid]=az+Y[BCZ+tid];
    pb[BCM+tid]=am+Y[BCM+tid];
  }
  if(tid==0) pb[FLGOFF]=1.f;
}

// ---------------- apply composites: m_t, ExxT_t, z_t (composite for time t at slot t) ----------------
__global__ __launch_bounds__(256) void k_smz(float* wsf, float* out){
  __shared__ float CP[1620];
  __shared__ float CVF[1024], Tm[1024];
  __shared__ float mlv[32], xtv[32], mv[32], zv[32];
  int tid=threadIdx.x;
  int t = blockIdx.x;           // 0..NN-1
  const float* pe = wsf + F_SCAN + (size_t)t*SSTR;
  for(int p=0;p<2;p++){ int q=tid+(p<<8); if(q<405) ((float4*)CP)[q]=((const float4*)pe)[q]; }
  for(int q=tid;q<1024;q+=256) CVF[q]=wsf[F_COVT+q];
  if(tid<32){ mlv[tid]=wsf[F_MLAST+tid]; xtv[tid]=wsf[F_XT+tid]; }
  __syncthreads();
  if(tid<32){
    float am=0.f, az=0.f;
    #pragma unroll
    for(int m=0;m<32;++m){
      am=fmaf(CP[BG+tid*32+m], mlv[m], am);
      az=fmaf(CP[BG+tid*32+m], xtv[m], az);
    }
    mv[tid]=am+CP[BCM+tid];
    zv[tid]=az+CP[BCZ+tid];
    out[O_EX+(size_t)t*32+tid]=mv[tid];
    out[O_Z +(size_t)t*32+tid]=zv[tid];
  }
  for(int q=tid;q<1024;q+=256){
    int r=q>>5,c=q&31;
    float acc=0.f;
    #pragma unroll
    for(int m=0;m<32;++m) acc=fmaf(CP[BG+r*32+m], CVF[m*32+c], acc);
    Tm[q]=acc;
  }
  __syncthreads();
  for(int q=tid;q<528;q+=256){
    int r,c; tri_rc(q,r,c);
    float acc=0.f;
    #pragma unroll
    for(int m=0;m<32;++m) acc=fmaf(Tm[r*32+m], CP[BG+c*32+m], acc);
    float cov = acc + CP[BP+q];
    float e = cov + mv[r]*mv[c];
    out[O_EXXT+(size_t)t*1024 + r*32+c]=e;
    if(r!=c) out[O_EXXT+(size_t)t*1024 + c*32+r]=e;
  }
}

// ---------------- Cross_t ----------------
__global__ __launch_bounds__(256) void k_cross(float* wsf, float* out){
  __shared__ float PV[1089], GF[1024], E1[1024];
  __shared__ float gv[32], m1[32];
  int tid=threadIdx.x;
  int t = blockIdx.x;           // 0..NN-1
  float* outc = out + O_CROSS + (size_t)t*1024;
  for(int q=tid;q<528;q+=256){
    int r,c; tri_rc(q,r,c);
    float v=outc[q]; PV[r*33+c]=v; PV[c*33+r]=v;
  }
  if(tid<32) gv[tid]=outc[528+tid];
  for(int q=tid;q<1024;q+=256) E1[q]=out[O_EXXT+(size_t)(t+1)*1024+q];
  if(tid<32) m1[tid]=out[O_EX+(size_t)(t+1)*32+tid];
  __syncthreads();
  for(int q=tid;q<1024;q+=256){
    int r=q>>5,c=q&31;
    float acc=0.f;
    #pragma unroll
    for(int m=0;m<32;++m) acc=fmaf(PV[r*33+m], wsf[F_ATLAM+m*32+c], acc);
    GF[q]=acc;
  }
  __syncthreads();
  for(int q=tid;q<1024;q+=256){
    int i2=q>>5, j=q&31;
    float acc=0.f;
    #pragma unroll
    for(int m=0;m<32;++m) acc=fmaf(GF[j*32+m], E1[m*32+i2], acc);
    outc[q] = acc + gv[j]*m1[i2];
  }
}

// ---------------- big reduction over t ----------------
__global__ __launch_bounds__(256) void k_terms(const float* rJ, const float* rh,
    const float* plam, float* wsf, double* wsd, float* out){
  __shared__ float slam[1056], slamA[1056], sata[1056];
  __shared__ float slamb[32], satlb[32], cst[16], sw[16];
  __shared__ double sd[256];
  int tid=threadIdx.x; int i8=tid>>3, c4=(tid&7)*4;
  for(int p=0;p<4;p++){int cell=tid+(p<<8);int r=cell>>5,c=cell&31;
    slam[r*33+c]=wsf[F_LAM+cell]; slamA[r*33+c]=wsf[F_LAMA+cell]; sata[r*33+c]=wsf[F_ATLAMA+cell];}
  if(tid<32){slamb[tid]=wsf[F_LAMB+tid]; satlb[tid]=wsf[F_ATLAMB+tid];}
  if(tid<16) cst[tid] = -0.5f*wsf[F_BTLAMBK+tid] + 0.5f*wsf[F_LOGDETK+tid];
  __syncthreads();
  double dr=0.0, dt=0.0, dm=0.0;
  int t0=blockIdx.x*8;
  for(int tt=0;tt<8;++tt){
    int t=t0+tt;
    if(t<NN){ if(tid<16) sw[tid]=out[O_CAT+(size_t)t*16+tid]; }
    __syncthreads();
    size_t cb=(size_t)t*1024+((size_t)i8<<5)+c4;
    float4 exT=*(const float4*)(out+O_EXXT+cb);
    float4 rj =*(const float4*)(rJ+cb);
    dr += -0.5*(double)(rj.x*exT.x+rj.y*exT.y+rj.z*exT.z+rj.w*exT.w);
    if(tid<32) dr += (double)(rh[(size_t)t*32+tid]*out[O_EX+(size_t)t*32+tid]);
    if(t>=1){
      dt += -0.5*(double)(slam[i8*33+c4]*exT.x + slam[i8*33+c4+1]*exT.y
                        + slam[i8*33+c4+2]*exT.z + slam[i8*33+c4+3]*exT.w);
      if(tid<32) dt += (double)(slamb[tid]*out[O_EX+(size_t)t*32+tid]);
    }
    if(t<NN){
      float4 crT =*(const float4*)(out+O_CROSS+cb);
      float4 exT1=*(const float4*)(out+O_EXXT+cb+1024);
      dt += (double)(slamA[i8*33+c4]*crT.x + slamA[i8*33+c4+1]*crT.y
                   + slamA[i8*33+c4+2]*crT.z + slamA[i8*33+c4+3]*crT.w)
          -0.5*(double)(sata[i8*33+c4]*exT.x + sata[i8*33+c4+1]*exT.y
                      + sata[i8*33+c4+2]*exT.z + sata[i8*33+c4+3]*exT.w);
      if(tid<32) dt -= (double)(satlb[tid]*out[O_EX+(size_t)t*32+tid]);
      const float* pe1=(const float*)&exT1; const float* pcr=(const float*)&crT; const float* pe0=(const float*)&exT;
      #pragma unroll
      for(int q=0;q<4;q++){
        int cc=(i8<<5)+c4+q;
        float wl=0.f, wa=0.f, wt2=0.f;
        #pragma unroll
        for(int k2=0;k2<KK;k2++){ float wv=sw[k2];
          wl =fmaf(wv, plam[(size_t)k2*1024+cc], wl);
          wa =fmaf(wv, wsf[F_LAMAK+(size_t)k2*1024+cc], wa);
          wt2=fmaf(wv, wsf[F_ATLAMAK+(size_t)k2*1024+cc], wt2);}
        dm += (double)(-0.5f*wl*pe1[q] + wa*pcr[q] - 0.5f*wt2*pe0[q]);
      }
      if(tid<32){
        float wlb=0.f, wtb=0.f;
        #pragma unroll
        for(int k2=0;k2<KK;k2++){ wlb=fmaf(sw[k2], wsf[F_LAMBK+k2*32+tid], wlb);
                                  wtb=fmaf(sw[k2], wsf[F_ATLAMBK+k2*32+tid], wtb);}
        dm += (double)(wlb*out[O_EX+(size_t)(t+1)*32+tid] - wtb*out[O_EX+(size_t)t*32+tid]);
      }
      if(tid<16) dm += (double)(sw[tid]*cst[tid]);
    }
    __syncthreads();
  }
  double r1=blk_red(dr,sd,tid);
  double r2=blk_red(dt,sd,tid);
  double r3=blk_red(dm,sd,tid);
  if(tid==0){ wsd[WSD_PR+blockIdx.x]=r1; wsd[WSD_PT+blockIdx.x]=r2; wsd[WSD_PM+blockIdx.x]=r3; }
}

__global__ __launch_bounds__(256) void k_final(const float* il, const float* tl,
    const float* ilp, const float* tlp, const float* ptau, float* wsf, double* wsd, float* out){
  __shared__ double sd[256];
  int tid=threadIdx.x;
  double ez=0.0;
  for(int b=0;b<128;++b) ez += (double)wsf[F_EZ + b*256 + tid];
  double v = ez * (double)(tl[tid]-tlp[tid]);
  if(tid<16) v += (double)out[O_CAT+tid] * (double)(il[tid]-ilp[tid]);
  double hmmkl = blk_red(v, sd, tid) - (double)wsf[F_SC+0];
  double a=0,b2=0,c=0;
  for(int q=0;q<4;q++){int b3=tid+q*256; a+=wsd[WSD_PR+b3]; b2+=wsd[WSD_PT+b3]; c+=wsd[WSD_PM+b3];}
  double recog=blk_red(a,sd,tid), trns=blk_red(b2,sd,tid), mixt=blk_red(c,sd,tid);
  double ia=0, ib=0, va=0, vb=0;
  for(int p=0;p<4;p++){int cell=tid+(p<<8);
    float e0=out[O_EXXT+cell];
    ia += (double)(wsf[F_TAU+cell]*e0);
    ib += (double)(ptau[cell]*e0);
  }
  if(tid<32){ float ex0=out[O_EX+tid];
    va=(double)(ex0*wsf[F_TAUMU+tid]); vb=(double)(ex0*wsf[F_TPM+tid]); }
  double s_ia=blk_red(ia,sd,tid), s_ib=blk_red(ib,sd,tid);
  double s_va=blk_red(va,sd,tid), s_vb=blk_red(vb,sd,tid);
  if(tid==0){
    double init_term = -0.5*s_ia + s_va + wsd[WSD_LOGC0];
    double mix_init  = -0.5*s_ib + s_vb + wsd[WSD_MIXC];
    double trans_term = trns + (double)NN*(-0.5*wsd[WSD_BTLAMB] + 0.5*wsd[WSD_LDLAM] - 0.5*Dd*LOG2PI_);
    double mix_trans  = mixt - 0.5*(double)NN*(double)Dd*LOG2PI_;
    double lds_kl = (init_term+trans_term) + recog - wsd[WSD_LOGZQ] - (mix_init+mix_trans);
    out[O_KL] = (float)(lds_kl + hmmkl);
  }
}

// ---------------- launch ----------------
extern "C" void kernel_launch(void* const* d_in, const int* in_sizes, int n_in,
                              void* d_out, int out_size, void* d_ws, size_t ws_size,
                              hipStream_t stream){
  const float* rJ  =(const float*)d_in[0];
  const float* rh  =(const float*)d_in[1];
  const float* loc =(const float*)d_in[2];
  const float* Tp  =(const float*)d_in[3];
  const float* Lp  =(const float*)d_in[4];
  const float* X   =(const float*)d_in[5];
  const float* il  =(const float*)d_in[6];
  const float* tl  =(const float*)d_in[7];
  const float* plam=(const float*)d_in[8];
  const float* pX  =(const float*)d_in[9];
  const float* ptau=(const float*)d_in[10];
  const float* pmu =(const float*)d_in[11];
  const float* ilp =(const float*)d_in[12];
  const float* tlp =(const float*)d_in[13];
  const int*   seed=(const int*)d_in[14];
  float* out=(float*)d_out;
  double* wsd=(double*)d_ws;
  float* wsf=(float*)((char*)d_ws + 32768);

  k_setup<<<19,256,0,stream>>>(rJ,rh,loc,Tp,Lp,X,plam,pX,ptau,pmu,wsf,wsd);
  k_eps<<<1024,256,0,stream>>>(seed, out + O_Z);
  k_hmmpow<<<1,256,0,stream>>>(tl, wsf);
  k_hmmab<<<32,256,0,stream>>>(il, wsf);
  k_cat<<<128,256,0,stream>>>(tl, wsf, out);
  k_leaf<<<8192,256,0,stream>>>(rJ, rh, wsf, wsd);
  for(int d=0; d<13; ++d) k_cf<<<(8192>>(d+1)),256,0,stream>>>(wsf, out, d, 0);
  k_cf<<<1,256,0,stream>>>(wsf, out, 12, 1);
  for(int d=11; d>=0; --d) k_cf<<<(8192>>(d+1)),256,0,stream>>>(wsf, out, d, 2);
  k_point<<<8192,256,0,stream>>>(wsf, wsd, out);
  for(int d=0; d<13; ++d) k_ca<<<(8192>>(d+1)),256,0,stream>>>(wsf, d, 0);
  k_ca<<<1,256,0,stream>>>(wsf, 12, 1);
  for(int d=11; d>=0; --d) k_ca<<<(8192>>(d+1)),256,0,stream>>>(wsf, d, 2);
  k_smz<<<NN,256,0,stream>>>(wsf, out);
  k_cross<<<NN,256,0,stream>>>(wsf, out);
  k_terms<<<1024,256,0,stream>>>(rJ, rh, plam, wsf, wsd, out);
  k_final<<<1,256,0,stream>>>(il, tl, ilp, tlp, ptau, wsf, wsd, out);
}

// Round 6
// 2043.194 us; speedup vs baseline: 173.8157x; 1.0713x over previous
//
#include <hip/hip_runtime.h>
#include <math.h>
#include <stdint.h>

#define Dd 32
#define TT 8192
#define NN 8191
#define KK 16
#define LOG2PI_ 1.8378770664093453

// ---------------- ws doubles ----------------
#define WSD_LOGC0  0
#define WSD_LOGZQ  1
#define WSD_MIXC   3
#define WSD_LDLAM  4
#define WSD_BTLAMB 5
#define WSD_PR     8
#define WSD_PT     1032
#define WSD_PM     2056
// ---------------- ws floats (base = byte 32768) ----------------
#define F_TAU      0
#define F_TAUMU    1024
#define F_LAM      1056
#define F_A        2080
#define F_B        3104
#define F_ATLAM    3136
#define F_ATLAMA   4160
#define F_LAMA     5184
#define F_LAMB     6208
#define F_ATLAMB   6240
#define F_SC       6272
#define F_LAMAK    6304
#define F_ATLAMAK  22688
#define F_LAMBK    39072
#define F_ATLAMBK  39584
#define F_BTLAMBK  40096
#define F_LOGDETK  40112
#define F_TPM      40128
#define F_J0       40160
#define F_H0       41184
#define F_MLAST    41216
#define F_COVT     41248
#define F_XT       42272
#define F_TPOW     42304
#define F_ALPHA    45632
#define F_BETA     176704
#define F_EZ       307776
#define F_SCAN     340544

// scan slot layout (stride 2148 floats)
#define SSTR   2148
#define POFF   0
#define QOFF   528
#define ROFF   1056
#define PPOFF  2080
#define QQOFF  2112
#define GAMOFF 2144
#define FLGOFF 2146
// affine (B) slot layout (same slots, reused after k_point)
#define BG     0
#define BCZ    1024
#define BCM    1056
#define BP     1088

// out offsets (floats)
#define O_Z     ((size_t)0)
#define O_EX    ((size_t)262144)
#define O_EXXT  ((size_t)524288)
#define O_CROSS ((size_t)8912896)
#define O_CAT   ((size_t)17300480)
#define O_KL    ((size_t)17431536)

// ---------------- threefry ----------------
__device__ __forceinline__ uint32_t rotl32(uint32_t v, int d){ return (v<<d)|(v>>(32-d)); }
__device__ __forceinline__ void threefry2x32(uint32_t k0, uint32_t k1, uint32_t x0, uint32_t x1,
                                             uint32_t& o0, uint32_t& o1){
  uint32_t ks2 = k0 ^ k1 ^ 0x1BD11BDAu;
  x0 += k0; x1 += k1;
  x0+=x1; x1=rotl32(x1,13); x1^=x0;  x0+=x1; x1=rotl32(x1,15); x1^=x0;
  x0+=x1; x1=rotl32(x1,26); x1^=x0;  x0+=x1; x1=rotl32(x1, 6); x1^=x0;
  x0+=k1; x1+=ks2+1u;
  x0+=x1; x1=rotl32(x1,17); x1^=x0;  x0+=x1; x1=rotl32(x1,29); x1^=x0;
  x0+=x1; x1=rotl32(x1,16); x1^=x0;  x0+=x1; x1=rotl32(x1,24); x1^=x0;
  x0+=ks2; x1+=k0+2u;
  x0+=x1; x1=rotl32(x1,13); x1^=x0;  x0+=x1; x1=rotl32(x1,15); x1^=x0;
  x0+=x1; x1=rotl32(x1,26); x1^=x0;  x0+=x1; x1=rotl32(x1, 6); x1^=x0;
  x0+=k0; x1+=k1+3u;
  x0+=x1; x1=rotl32(x1,17); x1^=x0;  x0+=x1; x1=rotl32(x1,29); x1^=x0;
  x0+=x1; x1=rotl32(x1,16); x1^=x0;  x0+=x1; x1=rotl32(x1,24); x1^=x0;
  x0+=k1; x1+=ks2+4u;
  x0+=x1; x1=rotl32(x1,13); x1^=x0;  x0+=x1; x1=rotl32(x1,15); x1^=x0;
  x0+=x1; x1=rotl32(x1,26); x1^=x0;  x0+=x1; x1=rotl32(x1, 6); x1^=x0;
  x0+=ks2; x1+=k0+5u;
  o0=x0; o1=x1;
}
__device__ __forceinline__ float tf_normal(uint32_t bits){
  float fl = __uint_as_float((bits>>9) | 0x3F800000u) - 1.0f;
  const float lo = -0.99999994f;
  float u = fmaxf(lo, fl*2.0f + lo);
  float w = -log1pf(-u*u);
  float p;
  if (w < 5.0f){
    w -= 2.5f;
    p = 2.81022636e-08f;
    p = fmaf(p,w,3.43273939e-07f); p = fmaf(p,w,-3.5233877e-06f);
    p = fmaf(p,w,-4.39150654e-06f); p = fmaf(p,w,0.00021858087f);
    p = fmaf(p,w,-0.00125372503f); p = fmaf(p,w,-0.00417768164f);
    p = fmaf(p,w,0.246640727f); p = fmaf(p,w,1.50140941f);
  } else {
    w = sqrtf(w) - 3.0f;
    p = -0.000200214257f;
    p = fmaf(p,w,0.000100950558f); p = fmaf(p,w,0.00134934322f);
    p = fmaf(p,w,-0.00367342844f); p = fmaf(p,w,0.00573950773f);
    p = fmaf(p,w,-0.0076224613f); p = fmaf(p,w,0.00943887047f);
    p = fmaf(p,w,1.00167406f); p = fmaf(p,w,2.83297682f);
  }
  return 1.4142135381698608f * (p*u);
}

// ---------------- helpers ----------------
__device__ __forceinline__ void tri_rc(int i, int& r, int& c){
  int rr = (int)((sqrtf(8.f*(float)i+1.f)-1.f)*0.5f);
  while((rr+1)*(rr+2)/2 <= i) ++rr;
  while(rr*(rr+1)/2 > i) --rr;
  r = rr; c = i - rr*(rr+1)/2;
}

// dot of stride-36 rows: sum_m A[r][m]*B[c][m]
__device__ __forceinline__ float dot36(const float* A, int r, const float* B, int c){
  const float4* a4 = (const float4*)(A + r*36);
  const float4* b4 = (const float4*)(B + c*36);
  float sx=0.f, sy=0.f, sz=0.f, sw=0.f;
  #pragma unroll
  for(int m=0;m<8;++m){
    float4 a=a4[m], b=b4[m];
    sx=fmaf(a.x,b.x,sx); sy=fmaf(a.y,b.y,sy);
    sz=fmaf(a.z,b.z,sz); sw=fmaf(a.w,b.w,sw);
  }
  return (sx+sy)+(sz+sw);
}
// stride-32 rows (src in LDS/global, f4-aligned) -> stride-36 LDS rows
__device__ __forceinline__ void t36_rows(float* dst, const float* src, int tid){
  int r=tid>>3, c0=(tid&7)<<2;
  *(float4*)(dst + r*36 + c0) = *(const float4*)(src + r*32 + c0);
}
// dst[j][m] = src[m*32+j]  (transpose stage)
__device__ __forceinline__ void t36_tr(float* dst, const float* src, int tid){
  int m=tid>>3, j0=(tid&7)<<2;
  float4 v = *(const float4*)(src + m*32 + j0);
  dst[(j0+0)*36+m]=v.x; dst[(j0+1)*36+m]=v.y;
  dst[(j0+2)*36+m]=v.z; dst[(j0+3)*36+m]=v.w;
}
// dst[j][m] = src36[m][j]  (transpose of stride-36 LDS matrix)
__device__ __forceinline__ void t36_tr36(float* dst, const float* src, int tid){
  int m=tid>>3, j0=(tid&7)<<2;
  float4 v = *(const float4*)(src + m*36 + j0);
  dst[(j0+0)*36+m]=v.x; dst[(j0+1)*36+m]=v.y;
  dst[(j0+2)*36+m]=v.z; dst[(j0+3)*36+m]=v.w;
}
// packed 528 tri -> full symmetric stride-36
__device__ __forceinline__ void t36_sym(float* dst, const float* packed, int tid){
  for(int q=tid;q<528;q+=256){
    int r,c; tri_rc(q,r,c);
    float v=packed[q];
    dst[r*36+c]=v; dst[c*36+r]=v;
  }
}

// Fused cholesky + L^-1, quad-vectorized, stride 36.
// W: full symmetric in/out (subdiag cols end scaled-L); Li out = L^-1 (lower, upper zero).
// rdg[j]=1/L_jj. slog valid on tid==0 only.
__device__ double chol_linv36(float* W, float* Li, float* rdg, int tid){
  int r = tid>>3, c0 = (tid&7)<<2;
  {
    float4 z = make_float4(0.f,0.f,0.f,0.f);
    if(r>=c0 && r<c0+4) ((float*)&z)[r-c0]=1.f;
    *(float4*)(Li + r*36 + c0) = z;
  }
  double slog=0.0;
  for(int j=0;j<33;++j){
    if(j<32){
      float dd = W[j*36+j];
      float rd = 1.0f/sqrtf(dd);
      float invd = rd*rd;
      if(tid==0){ rdg[j]=rd; slog += (double)(0.5f*__logf(dd)); }
      if(r>j && c0+3>=j){
        float t0 = W[j*36+r]*invd;
        float4 wj  = *(const float4*)(W+j*36+c0);
        float4 cur = *(float4*)(W+r*36+c0);
        float rdl = rd;
        int c;
        c=c0;   cur.x = (c>j)? fmaf(-t0, wj.x, cur.x) : ((c==j)? cur.x*rdl : cur.x);
        c=c0+1; cur.y = (c>j)? fmaf(-t0, wj.y, cur.y) : ((c==j)? cur.y*rdl : cur.y);
        c=c0+2; cur.z = (c>j)? fmaf(-t0, wj.z, cur.z) : ((c==j)? cur.z*rdl : cur.z);
        c=c0+3; cur.w = (c>j)? fmaf(-t0, wj.w, cur.w) : ((c==j)? cur.w*rdl : cur.w);
        *(float4*)(W+r*36+c0) = cur;
      }
    }
    if(j>0){
      int ii=j-1;
      if(r>ii && c0<=ii){
        float wri = W[r*36+ii]*rdg[ii];
        float4 lrow = *(const float4*)(Li+ii*36+c0);
        float4 cur  = *(float4*)(Li+r*36+c0);
        if(c0+0<=ii) cur.x = fmaf(-wri, lrow.x, cur.x);
        if(c0+1<=ii) cur.y = fmaf(-wri, lrow.y, cur.y);
        if(c0+2<=ii) cur.z = fmaf(-wri, lrow.z, cur.z);
        if(c0+3<=ii) cur.w = fmaf(-wri, lrow.w, cur.w);
        *(float4*)(Li+r*36+c0) = cur;
      }
    }
    __syncthreads();
  }
  {
    float rr = rdg[r];
    float4 cur = *(float4*)(Li+r*36+c0);
    cur.x*=rr; cur.y*=rr; cur.z*=rr; cur.w*=rr;
    *(float4*)(Li+r*36+c0) = cur;
  }
  __syncthreads();
  return slog;
}

__device__ __forceinline__ double blk_red(double v, double* sd, int tid){
  sd[tid]=v; __syncthreads();
  for(int s=128;s>0;s>>=1){ if(tid<s) sd[tid]+=sd[tid+s]; __syncthreads(); }
  double r=sd[0]; __syncthreads(); return r;
}
__device__ double blk_logdet(float* Ms, int tid){
  double sl = 0.0;
  for (int j=0;j<Dd;++j){
    float dd = Ms[j*33+j];
    sl += log((double)dd);
    float invd = 1.0f/dd;
    #pragma unroll
    for(int p=0;p<4;p++){
      int cell = tid + (p<<8); int r=cell>>5, c=cell&31;
      if(r>j && c>j && c<=r) Ms[r*33+c] -= Ms[r*33+j]*(Ms[c*33+j]*invd);
    }
    __syncthreads();
  }
  return sl;
}

// ---------------- setup: 19 independent blocks ----------------
__global__ __launch_bounds__(256) void k_setup(const float* rJ, const float* rh, const float* loc,
    const float* Tp, const float* Lp, const float* X, const float* plam, const float* pX,
    const float* ptau, const float* pmu, float* wsf, double* wsd){
  __shared__ float s1[1056], s2[1056], s3[1056];
  __shared__ float sv[32], sv2[32];
  int tid=threadIdx.x; int b=blockIdx.x;
  if(b==0){
    for(int p=0;p<4;p++){int cell=tid+(p<<8);int r=cell>>5,c=cell&31; s1[r*33+c]=Tp[cell];}
    if(tid<32) sv[tid]=loc[tid];
    __syncthreads();
    for(int p=0;p<4;p++){int cell=tid+(p<<8);int r=cell>>5,c=cell&31;
      float a=0.f;
      #pragma unroll
      for(int m=0;m<Dd;++m) a=fmaf(s1[r*33+m], s1[c*33+m], a);
      if(r==c) a+=1e-8f;
      s2[r*33+c]=a; wsf[F_TAU+cell]=a; wsf[F_J0+cell]=a+rJ[cell];
    }
    __syncthreads();
    if(tid<32){ float tm=0.f;
      #pragma unroll
      for(int m=0;m<Dd;++m) tm=fmaf(s2[tid*33+m], sv[m], tm);
      sv2[tid]=tm; wsf[F_TAUMU+tid]=tm; wsf[F_H0+tid]=tm+rh[tid];
    }
    __syncthreads();
    double ldt = blk_logdet(s2, tid);
    if(tid==0){ double dd=0; for(int m=0;m<Dd;++m) dd += (double)sv[m]*(double)sv2[m];
      wsd[WSD_LOGC0] = -0.5*dd + 0.5*ldt - 0.5*Dd*LOG2PI_; }
  } else if(b==1){
    for(int p=0;p<4;p++){int cell=tid+(p<<8);int r=cell>>5,c=cell&31; s1[r*33+c]=Lp[cell];}
    __syncthreads();
    for(int p=0;p<4;p++){int cell=tid+(p<<8);int r=cell>>5,c=cell&31;
      float a=0.f;
      #pragma unroll
      for(int m=0;m<Dd;++m) a=fmaf(s1[r*33+m], s1[c*33+m], a);
      if(r==c) a+=1e-8f;
      s2[r*33+c]=a; wsf[F_LAM+cell]=a;
    }
    __syncthreads();
    for(int p=0;p<4;p++){int cell=tid+(p<<8);int r=cell>>5,c=cell&31;
      float a=X[r*33+c]; s3[r*33+c]=a; wsf[F_A+cell]=a; }
    if(tid<32){ sv[tid]=X[tid*33+32]; wsf[F_B+tid]=sv[tid]; }
    __syncthreads();
    for(int p=0;p<4;p++){int cell=tid+(p<<8);int r=cell>>5,c=cell&31;
      float a=0.f,b2=0.f;
      #pragma unroll
      for(int m=0;m<Dd;++m){ a=fmaf(s2[r*33+m], s3[m*33+c], a); b2=fmaf(s3[m*33+r], s2[m*33+c], b2); }
      s1[r*33+c]=a; wsf[F_LAMA+cell]=a; wsf[F_ATLAM+cell]=b2;
    }
    if(tid<32){ float lb=0.f;
      #pragma unroll
      for(int m=0;m<Dd;++m) lb=fmaf(s2[tid*33+m], sv[m], lb);
      sv2[tid]=lb; wsf[F_LAMB+tid]=lb;
    }
    __syncthreads();
    for(int p=0;p<4;p++){int cell=tid+(p<<8);int r=cell>>5,c=cell&31;
      float a=0.f;
      #pragma unroll
      for(int m=0;m<Dd;++m) a=fmaf(s3[m*33+r], s1[m*33+c], a);
      wsf[F_ATLAMA+cell]=a;
    }
    if(tid<32){ float ab=0.f;
      #pragma unroll
      for(int m=0;m<Dd;++m) ab=fmaf(s3[m*33+tid], sv2[m], ab);
      wsf[F_ATLAMB+tid]=ab;
    }
    if(tid==0){ double bb=0; for(int m=0;m<Dd;++m) bb += (double)sv[m]*(double)sv2[m];
      wsd[WSD_BTLAMB]=bb; }
    __syncthreads();
    double ldl = blk_logdet(s2, tid);
    if(tid==0) wsd[WSD_LDLAM]=ldl;
  } else if(b==2){
    for(int p=0;p<4;p++){int cell=tid+(p<<8);int r=cell>>5,c=cell&31; s1[r*33+c]=ptau[cell];}
    if(tid<32) sv[tid]=pmu[tid];
    __syncthreads();
    if(tid<32){ float tm=0.f;
      #pragma unroll
      for(int m=0;m<Dd;++m) tm=fmaf(s1[tid*33+m], sv[m], tm);
      sv2[tid]=tm; wsf[F_TPM+tid]=tm;
    }
    __syncthreads();
    double ldp = blk_logdet(s1, tid);
    if(tid==0){ double dd=0; for(int m=0;m<Dd;++m) dd += (double)sv[m]*(double)sv2[m];
      wsd[WSD_MIXC] = -0.5*dd + 0.5*ldp - 0.5*Dd*LOG2PI_; }
  } else {
    int k2 = b-3;
    for(int p=0;p<4;p++){int cell=tid+(p<<8);int r=cell>>5,c=cell&31;
      s2[r*33+c]=plam[k2*1024+cell]; s3[r*33+c]=pX[k2*1056 + r*33 + c];}
    if(tid<32) sv[tid]=pX[k2*1056 + tid*33 + 32];
    __syncthreads();
    for(int p=0;p<4;p++){int cell=tid+(p<<8);int r=cell>>5,c=cell&31;
      float a=0.f;
      #pragma unroll
      for(int m=0;m<Dd;++m) a=fmaf(s2[r*33+m], s3[m*33+c], a);
      s1[r*33+c]=a; wsf[F_LAMAK + (size_t)k2*1024 + cell]=a;
    }
    if(tid<32){ float lb=0.f;
      #pragma unroll
      for(int m=0;m<Dd;++m) lb=fmaf(s2[tid*33+m], sv[m], lb);
      sv2[tid]=lb; wsf[F_LAMBK + k2*32 + tid]=lb;
    }
    __syncthreads();
    for(int p=0;p<4;p++){int cell=tid+(p<<8);int r=cell>>5,c=cell&31;
      float a=0.f;
      #pragma unroll
      for(int m=0;m<Dd;++m) a=fmaf(s3[m*33+r], s1[m*33+c], a);
      wsf[F_ATLAMAK + (size_t)k2*1024 + cell]=a;
    }
    if(tid<32){ float ab=0.f;
      #pragma unroll
      for(int m=0;m<Dd;++m) ab=fmaf(s3[m*33+tid], sv2[m], ab);
      wsf[F_ATLAMBK + k2*32 + tid]=ab;
    }
    if(tid==0){ float bb=0.f; for(int m=0;m<Dd;++m) bb=fmaf(sv[m],sv2[m],bb);
      wsf[F_BTLAMBK + k2]=bb; }
    __syncthreads();
    double dk = blk_logdet(s2, tid);
    if(tid==0) wsf[F_LOGDETK + k2]=(float)dk;
  }
}

// ---------------- eps -> out O_Z (staged; overwritten by sampler later) ----------------
__global__ __launch_bounds__(256) void k_eps(const int* seedp, float* outz){
  uint32_t seed = (uint32_t)seedp[0];
  uint32_t K0,K1;
  threefry2x32(0u, seed, 0u, 1u, K0, K1);
  uint32_t i = blockIdx.x*256u + threadIdx.x;
  uint32_t o0,o1;
  threefry2x32(K0, K1, 0u, i, o0, o1);
  outz[i] = tf_normal(o0 ^ o1);
}

// ---------------- HMM ----------------
__global__ __launch_bounds__(256) void k_hmmpow(const float* tl, float* wsf){
  __shared__ float A0[256], A1[256];
  int tid=threadIdx.x;
  A0[tid]=tl[tid];
  wsf[F_TPOW+tid]=A0[tid];
  __syncthreads();
  float* cur=A0; float* nxt=A1;
  for(int k=1;k<13;++k){
    int i=tid>>4, j=tid&15;
    float mx=-3.0e38f;
    #pragma unroll
    for(int m=0;m<16;++m) mx=fmaxf(mx, cur[i*16+m]+cur[m*16+j]);
    float s=0.f;
    #pragma unroll
    for(int m=0;m<16;++m) s+=__expf(cur[i*16+m]+cur[m*16+j]-mx);
    float v=mx+__logf(s);
    nxt[tid]=v; wsf[F_TPOW+k*256+tid]=v;
    __syncthreads();
    float* t2=cur; cur=nxt; nxt=t2;
  }
}

__global__ __launch_bounds__(256) void k_hmmab(const float* il, float* wsf){
  __shared__ float S[3328];
  int tid=threadIdx.x;
  for(int p=0;p<13;++p) S[p*256+tid]=wsf[F_TPOW+p*256+tid];
  __syncthreads();
  int n = blockIdx.x*256 + tid;
  if(n>NN-1) return;
  float v[16], w[16];
  #pragma unroll
  for(int j=0;j<16;++j) v[j]=il[j];
  for(int k=0;k<13;++k){
    if((n>>k)&1){
      #pragma unroll
      for(int j=0;j<16;++j){
        float mx=-3.0e38f;
        #pragma unroll
        for(int i2=0;i2<16;++i2) mx=fmaxf(mx, v[i2]+S[k*256+i2*16+j]);
        float s=0.f;
        #pragma unroll
        for(int i2=0;i2<16;++i2) s+=__expf(v[i2]+S[k*256+i2*16+j]-mx);
        w[j]=mx+__logf(s);
      }
      #pragma unroll
      for(int j=0;j<16;++j) v[j]=w[j];
    }
  }
  #pragma unroll
  for(int j=0;j<16;++j) wsf[F_ALPHA+(size_t)n*16+j]=v[j];
  if(n==NN-1){
    float mx=-3.0e38f;
    #pragma unroll
    for(int j=0;j<16;++j) mx=fmaxf(mx,v[j]);
    float s=0.f;
    #pragma unroll
    for(int j=0;j<16;++j) s+=__expf(v[j]-mx);
    wsf[F_SC+0]=mx+__logf(s);
  }
  int m = NN-1-n;
  float b[16];
  #pragma unroll
  for(int i2=0;i2<16;++i2) b[i2]=0.f;
  for(int k=0;k<13;++k){
    if((m>>k)&1){
      #pragma unroll
      for(int i2=0;i2<16;++i2){
        float mx=-3.0e38f;
        #pragma unroll
        for(int j=0;j<16;++j) mx=fmaxf(mx, S[k*256+i2*16+j]+b[j]);
        float s=0.f;
        #pragma unroll
        for(int j=0;j<16;++j) s+=__expf(S[k*256+i2*16+j]+b[j]-mx);
        w[i2]=mx+__logf(s);
      }
      #pragma unroll
      for(int i2=0;i2<16;++i2) b[i2]=w[i2];
    }
  }
  #pragma unroll
  for(int i2=0;i2<16;++i2) wsf[F_BETA+(size_t)n*16+i2]=b[i2];
}

// ---------------- cat_es + EZZNT partials ----------------
__global__ __launch_bounds__(256) void k_cat(const float* tl, float* wsf, float* out){
  __shared__ float Ts[256]; __shared__ float al[1024]; __shared__ float be[1040];
  int tid=threadIdx.x;
  Ts[tid]=tl[tid];
  float logZ = wsf[F_SC+0];
  int n0=blockIdx.x*64;
  for(int q=tid;q<1024;q+=256){ int n=n0+(q>>4); al[q] = (n<NN)? wsf[F_ALPHA+(size_t)n*16+(q&15)] : 0.f; }
  for(int q=tid;q<1040;q+=256){ int n=n0+(q>>4); be[q] = (n<NN)? wsf[F_BETA +(size_t)n*16+(q&15)] : 0.f; }
  __syncthreads();
  for(int q=tid;q<1024;q+=256){ int n=n0+(q>>4);
    if(n<NN) out[O_CAT+(size_t)n*16+(q&15)] = __expf(al[q]+be[q]-logZ); }
  int i=tid>>4, j=tid&15;
  float acc=0.f;
  #pragma unroll 4
  for(int nn=0;nn<64;++nn){
    int n=n0+nn;
    if(n<NN-1) acc += __expf(al[nn*16+i]+Ts[i*16+j]+be[(nn+1)*16+j]-logZ);
  }
  wsf[F_EZ + blockIdx.x*256 + tid]=acc;
}

// ---------------- leaves ----------------
__global__ __launch_bounds__(256) void k_leaf(const float* rJ, const float* rh, float* wsf, double* wsd){
  int b = blockIdx.x; int tid=threadIdx.x;
  float* pe = wsf + F_SCAN + (size_t)b*SSTR;
  if(b==0){
    for(int q=tid;q<528;q+=256){
      int r,c; tri_rc(q,r,c);
      pe[POFF+q]=0.f;
      pe[QOFF+q]=wsf[F_J0 + r*32+c];
    }
    for(int q=tid;q<1024;q+=256) pe[ROFF+q]=0.f;
    if(tid<32){ pe[PPOFF+tid]=0.f; pe[QQOFF+tid]=wsf[F_H0+tid]; }
    if(tid==0){ *(double*)(pe+GAMOFF)=wsd[WSD_LOGC0]; pe[FLGOFF]=1.f; }
  } else {
    int t = b;
    for(int q=tid;q<528;q+=256){
      int r,c; tri_rc(q,r,c);
      pe[POFF+q] = wsf[F_ATLAMA + r*32+c] + ((r==c)?1e-6f:0.f);
      pe[QOFF+q] = wsf[F_LAM + r*32+c] + rJ[(size_t)t*1024 + r*32+c];
    }
    for(int q=tid;q<1024;q+=256) pe[ROFF+q] = -wsf[F_ATLAM+q];
    if(tid<32){
      pe[PPOFF+tid] = -wsf[F_ATLAMB+tid];
      pe[QQOFF+tid] = wsf[F_LAMB+tid] + rh[(size_t)t*32+tid];
    }
    if(tid==0){
      *(double*)(pe+GAMOFF) = -0.5*wsd[WSD_BTLAMB] + 0.5*wsd[WSD_LDLAM];
      pe[FLGOFF]=1.f;
    }
  }
}

// ---------------- filter-scan combine ----------------
__global__ __launch_bounds__(256) void k_cf(float* wsf, float* out, int d, int mode){
  __shared__ __align__(16) float SA[2148], SB[2148];
  __shared__ __align__(16) float W[1152], Li[1152], BA[1152], BB[1152];
  __shared__ float rdg[32], Ls[32];
  int tid = threadIdx.x;
  int i = blockIdx.x;
  int iA = (i<<(d+1)) + (1<<d) - 1;
  int iB = iA + (1<<d);
  float* base = wsf + F_SCAN;
  float* pa = base + (size_t)iA*SSTR;
  float* pb = base + (size_t)iB*SSTR;
  for(int q=tid;q<537;q+=256){ ((float4*)SA)[q]=((const float4*)pa)[q]; ((float4*)SB)[q]=((const float4*)pb)[q]; }
  __syncthreads();
  int fa=(SA[FLGOFF]!=0.f), fb=(SB[FLGOFF]!=0.f);
  if(mode==1){
    float* st = out + O_EXXT;
    for(int q=tid;q<537;q+=256){ ((float4*)st)[q]=((float4*)SB)[q]; ((float4*)pb)[q]=((float4*)SA)[q]; }
    if(tid==0) pa[FLGOFF]=0.f;
    return;
  }
  if(mode==2){ for(int q=tid;q<537;q+=256) ((float4*)pa)[q]=((float4*)SB)[q]; }
  float* X = (mode==2)? SB : SA;  int fx=(mode==2)?fb:fa;
  float* Y = (mode==2)? SA : SB;  int fy=(mode==2)?fa:fb;
  if(!fx && !fy){ if(tid==0) pb[FLGOFF]=0.f; return; }
  if(!fx){ for(int q=tid;q<537;q+=256) ((float4*)pb)[q]=((float4*)Y)[q]; return; }
  if(!fy){ for(int q=tid;q<537;q+=256) ((float4*)pb)[q]=((float4*)X)[q]; return; }
  // W = Q_x + P_y (sym expand) ; stage Rx rows, Ry^T
  for(int q=tid;q<528;q+=256){
    int r,c; tri_rc(q,r,c);
    float w = X[QOFF+q] + Y[POFF+q];
    W[r*36+c]=w; W[c*36+r]=w;
  }
  t36_rows(BA, X+ROFF, tid);   // BA[j][m] = Rx[j][m]
  t36_tr  (BB, Y+ROFF, tid);   // BB[j][m] = Ry[m][j]
  __syncthreads();
  double slog = chol_linv36(W, Li, rdg, tid);
  if(tid<32){
    float acc=0.f;
    for(int m=0;m<=tid;++m) acc = fmaf(Li[tid*36+m], X[QQOFF+m]+Y[PPOFF+m], acc);
    Ls[tid]=acc;
  }
  // T1t[j][i] = sum_m Li[i][m]*Rx[j][m]  -> into W
  for(int q=tid;q<1024;q+=256){
    int i2=q>>5, j=q&31;
    W[j*36+i2] = dot36(Li, i2, BA, j);
  }
  __syncthreads();
  // T2t[j][i] = sum_m Li[i][m]*RyT[j][m] -> into BA
  for(int q=tid;q<1024;q+=256){
    int i2=q>>5, j=q&31;
    BA[j*36+i2] = dot36(Li, i2, BB, j);
  }
  __syncthreads();
  for(int q=tid;q<528;q+=256){
    int r,c; tri_rc(q,r,c);
    pb[POFF+q] = X[POFF+q] - dot36(W, r, W, c);
    pb[QOFF+q] = Y[QOFF+q] - dot36(BA, r, BA, c);
  }
  for(int q=tid;q<1024;q+=256){
    int r=q>>5, c=q&31;
    pb[ROFF+q] = -dot36(W, r, BA, c);
  }
  if(tid<32){
    float ap=0.f,aq=0.f;
    #pragma unroll
    for(int m=0;m<32;++m){ ap=fmaf(W[tid*36+m],Ls[m],ap); aq=fmaf(BA[tid*36+m],Ls[m],aq); }
    pb[PPOFF+tid] = X[PPOFF+tid] - ap;
    pb[QQOFF+tid] = Y[QQOFF+tid] - aq;
  }
  if(tid==0){
    double g = *(double*)(X+GAMOFF) + *(double*)(Y+GAMOFF);
    double dot=0.0;
    for(int m=0;m<32;++m) dot += (double)Ls[m]*(double)Ls[m];
    *(double*)(pb+GAMOFF) = g + 0.5*dot - slog;
    pb[FLGOFF]=1.f;
  }
}

// ---------------- per-t pointwise ----------------
__global__ __launch_bounds__(256) void k_point(float* wsf, double* wsd, float* out){
  __shared__ __align__(16) float SE[2148];
  __shared__ __align__(16) float W[1152], Li[1152], AUX[1152];
  __shared__ float rdg[32], uv[32], Lu[32], ev[32], gv[32], yv[32];
  int tid=threadIdx.x; int b=blockIdx.x;
  float* base = wsf + F_SCAN;
  float* outz = out + O_Z;
  if(b>0){
    int t = b-1;
    float* pe = base + (size_t)b*SSTR;
    for(int q=tid;q<537;q+=256) ((float4*)SE)[q]=((const float4*)pe)[q];
    if(tid<32) ev[tid]=outz[(size_t)t*32+tid];
    t36_rows(AUX, wsf+F_LAMA, tid);    // AUX[j][m] = LAMA[j][m] = ATlam^T
    __syncthreads();
    for(int q=tid;q<528;q+=256){
      int r,c; tri_rc(q,r,c);
      float w = SE[QOFF+q] + wsf[F_ATLAMA + r*32+c] + ((r==c)?1e-6f:0.f);
      W[r*36+c]=w; W[c*36+r]=w;
    }
    if(tid<32) uv[tid]=SE[QQOFF+tid]-wsf[F_ATLAMB+tid];
    __syncthreads();
    chol_linv36(W, Li, rdg, tid);
    if(tid<32){
      float acc=0.f;
      for(int m=0;m<=tid;++m) acc=fmaf(Li[tid*36+m],uv[m],acc);
      Lu[tid]=acc;
    }
    // T1t[j][i] = sum_m Li[i][m]*LAMA[j][m] -> into W
    for(int q=tid;q<1024;q+=256){
      int i2=q>>5, j=q&31;
      W[j*36+i2] = dot36(Li, i2, AUX, j);
    }
    __syncthreads();
    // LiT into AUX ; gv/yv
    t36_tr36(AUX, Li, tid);
    if(tid<32){
      float ag=0.f, ay=0.f;
      for(int m2=tid;m2<32;++m2){ float lv=Li[m2*36+tid]; ag=fmaf(lv,Lu[m2],ag); ay=fmaf(lv,ev[m2],ay); }
      gv[tid]=ag; yv[tid]=ay;
    }
    __syncthreads();
    // G[r][c] = sum_m LiT[r][m]*T1t[c][m]
    for(int q=tid;q<1024;q+=256){
      int r=q>>5,c=q&31;
      pe[BG+q] = dot36(AUX, r, W, c);
    }
    float* outc = out + O_CROSS + (size_t)t*1024;
    for(int q=tid;q<528;q+=256){
      int r,c; tri_rc(q,r,c);
      float a = dot36(AUX, r, AUX, c);
      pe[BP+q]=a; outc[q]=a;
    }
    if(tid<32){
      pe[BCM+tid]=gv[tid]; pe[BCZ+tid]=gv[tid]+yv[tid]; outc[528+tid]=gv[tid];
    }
    if(tid==0) pe[FLGOFF]=1.f;
  } else {
    const float* st = out + O_EXXT;
    for(int q=tid;q<537;q+=256) ((float4*)SE)[q]=((const float4*)st)[q];
    if(tid<32) ev[tid]=outz[(size_t)NN*32+tid];
    __syncthreads();
    for(int q=tid;q<528;q+=256){
      int r,c; tri_rc(q,r,c);
      float w = SE[QOFF+q] + ((r==c)?1e-6f:0.f);
      W[r*36+c]=w; W[c*36+r]=w;
    }
    if(tid<32) uv[tid]=SE[QQOFF+tid];
    __syncthreads();
    double slog2 = chol_linv36(W, Li, rdg, tid);
    if(tid<32){
      float acc=0.f;
      for(int m=0;m<=tid;++m) acc=fmaf(Li[tid*36+m],uv[m],acc);
      Lu[tid]=acc;
    }
    t36_tr36(AUX, Li, tid);
    __syncthreads();
    if(tid<32){
      float am=0.f, ay=0.f;
      for(int m2=tid;m2<32;++m2){ float lv=Li[m2*36+tid]; am=fmaf(lv,Lu[m2],am); ay=fmaf(lv,ev[m2],ay); }
      gv[tid]=am; yv[tid]=ay;
      wsf[F_MLAST+tid]=am; out[O_EX+(size_t)NN*32+tid]=am;
      float xt=am+ay;
      wsf[F_XT+tid]=xt; out[O_Z+(size_t)NN*32+tid]=xt;
    }
    __syncthreads();
    for(int q=tid;q<1024;q+=256){
      int r=q>>5,c=q&31;
      float a = dot36(AUX, r, AUX, c);
      wsf[F_COVT+q]=a;
      out[O_EXXT+(size_t)NN*1024+q]=a+gv[r]*gv[c];
    }
    if(tid==0){
      double gam=*(const double*)(SE+GAMOFF);
      double hm=0.0;
      for(int m=0;m<32;++m) hm += (double)uv[m]*(double)gv[m];
      wsd[WSD_LOGZQ] = gam + 0.5*hm + 0.5*Dd*LOG2PI_ - slog2;
    }
  }
}

// ---------------- affine-scan combine ----------------
__device__ __forceinline__ int amap(int j){ return (j<NN)? (NN-j) : 0; }

__global__ __launch_bounds__(256) void k_ca(float* wsf, int d, int mode){
  __shared__ __align__(16) float SA[2148], SB[2148];
  __shared__ __align__(16) float GY36[1152], GB[1152], PX36[1152];
  int tid = threadIdx.x;
  int i = blockIdx.x;
  int iA = (i<<(d+1)) + (1<<d) - 1;
  int iB = iA + (1<<d);
  float* base = wsf + F_SCAN;
  float* pa = base + (size_t)amap(iA)*SSTR;
  float* pb = base + (size_t)amap(iB)*SSTR;
  for(int q=tid;q<537;q+=256){ ((float4*)SA)[q]=((const float4*)pa)[q]; ((float4*)SB)[q]=((const float4*)pb)[q]; }
  __syncthreads();
  int fa=(SA[FLGOFF]!=0.f), fb=(SB[FLGOFF]!=0.f);
  if(mode==1){
    for(int q=tid;q<537;q+=256) ((float4*)pb)[q]=((float4*)SA)[q];
    if(tid==0) pa[FLGOFF]=0.f;
    return;
  }
  if(mode==2){ for(int q=tid;q<537;q+=256) ((float4*)pa)[q]=((float4*)SB)[q]; }
  float* X = (mode==2)? SB : SA;  int fx=(mode==2)?fb:fa;
  float* Y = (mode==2)? SA : SB;  int fy=(mode==2)?fa:fb;
  if(!fx && !fy){ if(tid==0) pb[FLGOFF]=0.f; return; }
  if(!fx){ for(int q=tid;q<537;q+=256) ((float4*)pb)[q]=((float4*)Y)[q]; return; }
  if(!fy){ for(int q=tid;q<537;q+=256) ((float4*)pb)[q]=((float4*)X)[q]; return; }
  // stage: GY rows ; GX^T ; PX sym
  t36_rows(GY36, Y+BG, tid);
  t36_tr  (GB,   X+BG, tid);
  t36_sym (PX36, X+BP, tid);
  __syncthreads();
  // G_out[r][c] = sum_m GY[r][m]*GX[m][c]
  for(int q=tid;q<1024;q+=256){
    int r=q>>5,c=q&31;
    pb[BG+q] = dot36(GY36, r, GB, c);
  }
  __syncthreads();
  // S[r][c] = sum_m GY[r][m]*PX[c][m] -> GB
  for(int q=tid;q<1024;q+=256){
    int r=q>>5,c=q&31;
    GB[r*36+c] = dot36(GY36, r, PX36, c);
  }
  __syncthreads();
  for(int q=tid;q<528;q+=256){
    int r,c; tri_rc(q,r,c);
    pb[BP+q] = dot36(GB, r, GY36, c) + Y[BP+q];
  }
  if(tid<32){
    float az=0.f,am=0.f;
    #pragma unroll
    for(int m=0;m<32;++m){ float g=GY36[tid*36+m]; az=fmaf(g,X[BCZ+m],az); am=fmaf(g,X[BCM+m],am); }
    pb[BCZ+tid]=az+Y[BCZ+tid];
    pb[BCM+tid]=am+Y[BCM+tid];
  }
  if(tid==0) pb[FLGOFF]=1.f;
}

// ---------------- apply composites: m_t, ExxT_t, z_t ----------------
__global__ __launch_bounds__(256) void k_smz(float* wsf, float* out){
  __shared__ __align__(16) float G36[1152], CV36[1152], Tm36[1152];
  __shared__ float mlv[32], xtv[32], mv[32], zv[32];
  int tid=threadIdx.x;
  int t = blockIdx.x;           // 0..NN-1
  const float* pe = wsf + F_SCAN + (size_t)t*SSTR;
  t36_rows(G36,  pe+BG,       tid);
  t36_rows(CV36, wsf+F_COVT,  tid);
  if(tid<32){ mlv[tid]=wsf[F_MLAST+tid]; xtv[tid]=wsf[F_XT+tid]; }
  __syncthreads();
  if(tid<32){
    float am=0.f, az=0.f;
    #pragma unroll
    for(int m=0;m<32;++m){
      float g=G36[tid*36+m];
      am=fmaf(g, mlv[m], am);
      az=fmaf(g, xtv[m], az);
    }
    mv[tid]=am+pe[BCM+tid];
    zv[tid]=az+pe[BCZ+tid];
    out[O_EX+(size_t)t*32+tid]=mv[tid];
    out[O_Z +(size_t)t*32+tid]=zv[tid];
  }
  // Tm[r][c] = sum_m G[r][m]*CV[c][m]  (CV symmetric)
  for(int q=tid;q<1024;q+=256){
    int r=q>>5,c=q&31;
    Tm36[r*36+c] = dot36(G36, r, CV36, c);
  }
  __syncthreads();
  for(int q=tid;q<528;q+=256){
    int r,c; tri_rc(q,r,c);
    float cov = dot36(Tm36, r, G36, c) + pe[BP+q];
    float e = cov + mv[r]*mv[c];
    out[O_EXXT+(size_t)t*1024 + r*32+c]=e;
    if(r!=c) out[O_EXXT+(size_t)t*1024 + c*32+r]=e;
  }
}

// ---------------- Cross_t ----------------
__global__ __launch_bounds__(256) void k_cross(float* wsf, float* out){
  __shared__ __align__(16) float PV36[1152], LA36[1152], E136[1152], GF36[1152];
  __shared__ float gv[32], m1[32];
  int tid=threadIdx.x;
  int t = blockIdx.x;           // 0..NN-1
  float* outc = out + O_CROSS + (size_t)t*1024;
  t36_sym (PV36, outc, tid);
  t36_rows(LA36, wsf+F_LAMA, tid);
  t36_rows(E136, out+O_EXXT+(size_t)(t+1)*1024, tid);
  if(tid<32){ gv[tid]=outc[528+tid]; m1[tid]=out[O_EX+(size_t)(t+1)*32+tid]; }
  __syncthreads();
  // GF[r][c] = sum_m PV[r][m]*ATlam[m][c] = sum_m PV36[r][m]*LA36[c][m]
  for(int q=tid;q<1024;q+=256){
    int r=q>>5,c=q&31;
    GF36[r*36+c] = dot36(PV36, r, LA36, c);
  }
  __syncthreads();
  for(int q=tid;q<1024;q+=256){
    int i2=q>>5, j=q&31;
    float acc = dot36(GF36, j, E136, i2);   // E1 symmetric
    outc[q] = acc + gv[j]*m1[i2];
  }
}

// ---------------- big reduction over t ----------------
__global__ __launch_bounds__(256) void k_terms(const float* rJ, const float* rh,
    const float* plam, float* wsf, double* wsd, float* out){
  __shared__ float slam[1056], slamA[1056], sata[1056];
  __shared__ float slamb[32], satlb[32], cst[16], sw[16];
  __shared__ double sd[256];
  int tid=threadIdx.x; int i8=tid>>3, c4=(tid&7)*4;
  for(int p=0;p<4;p++){int cell=tid+(p<<8);int r=cell>>5,c=cell&31;
    slam[r*33+c]=wsf[F_LAM+cell]; slamA[r*33+c]=wsf[F_LAMA+cell]; sata[r*33+c]=wsf[F_ATLAMA+cell];}
  if(tid<32){slamb[tid]=wsf[F_LAMB+tid]; satlb[tid]=wsf[F_ATLAMB+tid];}
  if(tid<16) cst[tid] = -0.5f*wsf[F_BTLAMBK+tid] + 0.5f*wsf[F_LOGDETK+tid];
  __syncthreads();
  double dr=0.0, dt=0.0, dm=0.0;
  int t0=blockIdx.x*8;
  for(int tt=0;tt<8;++tt){
    int t=t0+tt;
    if(t<NN){ if(tid<16) sw[tid]=out[O_CAT+(size_t)t*16+tid]; }
    __syncthreads();
    size_t cb=(size_t)t*1024+((size_t)i8<<5)+c4;
    float4 exT=*(const float4*)(out+O_EXXT+cb);
    float4 rj =*(const float4*)(rJ+cb);
    dr += -0.5*(double)(rj.x*exT.x+rj.y*exT.y+rj.z*exT.z+rj.w*exT.w);
    if(tid<32) dr += (double)(rh[(size_t)t*32+tid]*out[O_EX+(size_t)t*32+tid]);
    if(t>=1){
      dt += -0.5*(double)(slam[i8*33+c4]*exT.x + slam[i8*33+c4+1]*exT.y
                        + slam[i8*33+c4+2]*exT.z + slam[i8*33+c4+3]*exT.w);
      if(tid<32) dt += (double)(slamb[tid]*out[O_EX+(size_t)t*32+tid]);
    }
    if(t<NN){
      float4 crT =*(const float4*)(out+O_CROSS+cb);
      float4 exT1=*(const float4*)(out+O_EXXT+cb+1024);
      dt += (double)(slamA[i8*33+c4]*crT.x + slamA[i8*33+c4+1]*crT.y
                   + slamA[i8*33+c4+2]*crT.z + slamA[i8*33+c4+3]*crT.w)
          -0.5*(double)(sata[i8*33+c4]*exT.x + sata[i8*33+c4+1]*exT.y
                      + sata[i8*33+c4+2]*exT.z + sata[i8*33+c4+3]*exT.w);
      if(tid<32) dt -= (double)(satlb[tid]*out[O_EX+(size_t)t*32+tid]);
      const float* pe1=(const float*)&exT1; const float* pcr=(const float*)&crT; const float* pe0=(const float*)&exT;
      #pragma unroll
      for(int q=0;q<4;q++){
        int cc=(i8<<5)+c4+q;
        float wl=0.f, wa=0.f, wt2=0.f;
        #pragma unroll
        for(int k2=0;k2<KK;k2++){ float wv=sw[k2];
          wl =fmaf(wv, plam[(size_t)k2*1024+cc], wl);
          wa =fmaf(wv, wsf[F_LAMAK+(size_t)k2*1024+cc], wa);
          wt2=fmaf(wv, wsf[F_ATLAMAK+(size_t)k2*1024+cc], wt2);}
        dm += (double)(-0.5f*wl*pe1[q] + wa*pcr[q] - 0.5f*wt2*pe0[q]);
      }
      if(tid<32){
        float wlb=0.f, wtb=0.f;
        #pragma unroll
        for(int k2=0;k2<KK;k2++){ wlb=fmaf(sw[k2], wsf[F_LAMBK+k2*32+tid], wlb);
                                  wtb=fmaf(sw[k2], wsf[F_ATLAMBK+k2*32+tid], wtb);}
        dm += (double)(wlb*out[O_EX+(size_t)(t+1)*32+tid] - wtb*out[O_EX+(size_t)t*32+tid]);
      }
      if(tid<16) dm += (double)(sw[tid]*cst[tid]);
    }
    __syncthreads();
  }
  double r1=blk_red(dr,sd,tid);
  double r2=blk_red(dt,sd,tid);
  double r3=blk_red(dm,sd,tid);
  if(tid==0){ wsd[WSD_PR+blockIdx.x]=r1; wsd[WSD_PT+blockIdx.x]=r2; wsd[WSD_PM+blockIdx.x]=r3; }
}

__global__ __launch_bounds__(256) void k_final(const float* il, const float* tl,
    const float* ilp, const float* tlp, const float* ptau, float* wsf, double* wsd, float* out){
  __shared__ double sd[256];
  int tid=threadIdx.x;
  double ez=0.0;
  for(int b=0;b<128;++b) ez += (double)wsf[F_EZ + b*256 + tid];
  double v = ez * (double)(tl[tid]-tlp[tid]);
  if(tid<16) v += (double)out[O_CAT+tid] * (double)(il[tid]-ilp[tid]);
  double hmmkl = blk_red(v, sd, tid) - (double)wsf[F_SC+0];
  double a=0,b2=0,c=0;
  for(int q=0;q<4;q++){int b3=tid+q*256; a+=wsd[WSD_PR+b3]; b2+=wsd[WSD_PT+b3]; c+=wsd[WSD_PM+b3];}
  double recog=blk_red(a,sd,tid), trns=blk_red(b2,sd,tid), mixt=blk_red(c,sd,tid);
  double ia=0, ib=0, va=0, vb=0;
  for(int p=0;p<4;p++){int cell=tid+(p<<8);
    float e0=out[O_EXXT+cell];
    ia += (double)(wsf[F_TAU+cell]*e0);
    ib += (double)(ptau[cell]*e0);
  }
  if(tid<32){ float ex0=out[O_EX+tid];
    va=(double)(ex0*wsf[F_TAUMU+tid]); vb=(double)(ex0*wsf[F_TPM+tid]); }
  double s_ia=blk_red(ia,sd,tid), s_ib=blk_red(ib,sd,tid);
  double s_va=blk_red(va,sd,tid), s_vb=blk_red(vb,sd,tid);
  if(tid==0){
    double init_term = -0.5*s_ia + s_va + wsd[WSD_LOGC0];
    double mix_init  = -0.5*s_ib + s_vb + wsd[WSD_MIXC];
    double trans_term = trns + (double)NN*(-0.5*wsd[WSD_BTLAMB] + 0.5*wsd[WSD_LDLAM] - 0.5*Dd*LOG2PI_);
    double mix_trans  = mixt - 0.5*(double)NN*(double)Dd*LOG2PI_;
    double lds_kl = (init_term+trans_term) + recog - wsd[WSD_LOGZQ] - (mix_init+mix_trans);
    out[O_KL] = (float)(lds_kl + hmmkl);
  }
}

// ---------------- launch ----------------
extern "C" void kernel_launch(void* const* d_in, const int* in_sizes, int n_in,
                              void* d_out, int out_size, void* d_ws, size_t ws_size,
                              hipStream_t stream){
  const float* rJ  =(const float*)d_in[0];
  const float* rh  =(const float*)d_in[1];
  const float* loc =(const float*)d_in[2];
  const float* Tp  =(const float*)d_in[3];
  const float* Lp  =(const float*)d_in[4];
  const float* X   =(const float*)d_in[5];
  const float* il  =(const float*)d_in[6];
  const float* tl  =(const float*)d_in[7];
  const float* plam=(const float*)d_in[8];
  const float* pX  =(const float*)d_in[9];
  const float* ptau=(const float*)d_in[10];
  const float* pmu =(const float*)d_in[11];
  const float* ilp =(const float*)d_in[12];
  const float* tlp =(const float*)d_in[13];
  const int*   seed=(const int*)d_in[14];
  float* out=(float*)d_out;
  double* wsd=(double*)d_ws;
  float* wsf=(float*)((char*)d_ws + 32768);

  k_setup<<<19,256,0,stream>>>(rJ,rh,loc,Tp,Lp,X,plam,pX,ptau,pmu,wsf,wsd);
  k_eps<<<1024,256,0,stream>>>(seed, out + O_Z);
  k_hmmpow<<<1,256,0,stream>>>(tl, wsf);
  k_hmmab<<<32,256,0,stream>>>(il, wsf);
  k_cat<<<128,256,0,stream>>>(tl, wsf, out);
  k_leaf<<<8192,256,0,stream>>>(rJ, rh, wsf, wsd);
  for(int d=0; d<13; ++d) k_cf<<<(8192>>(d+1)),256,0,stream>>>(wsf, out, d, 0);
  k_cf<<<1,256,0,stream>>>(wsf, out, 12, 1);
  for(int d=11; d>=0; --d) k_cf<<<(8192>>(d+1)),256,0,stream>>>(wsf, out, d, 2);
  k_point<<<8192,256,0,stream>>>(wsf, wsd, out);
  for(int d=0; d<13; ++d) k_ca<<<(8192>>(d+1)),256,0,stream>>>(wsf, d, 0);
  k_ca<<<1,256,0,stream>>>(wsf, 12, 1);
  for(int d=11; d>=0; --d) k_ca<<<(8192>>(d+1)),256,0,stream>>>(wsf, d, 2);
  k_smz<<<NN,256,0,stream>>>(wsf, out);
  k_cross<<<NN,256,0,stream>>>(wsf, out);
  k_terms<<<1024,256,0,stream>>>(rJ, rh, plam, wsf, wsd, out);
  k_final<<<1,256,0,stream>>>(il, tl, ilp, tlp, ptau, wsf, wsd, out);
}